// Round 1
// baseline (1570.029 us; speedup 1.0000x reference)
//
#include <hip/hip_runtime.h>
#include <hip/hip_bf16.h>

#define B 4
#define L 2048
#define D 1024
#define NH 4
#define DK 256
#define CHUNK 32
#define NCH 64
#define BH (B*NH)

typedef __attribute__((ext_vector_type(8))) __bf16 bf16x8;
typedef __attribute__((ext_vector_type(4))) float f32x4;

__device__ inline unsigned short f2bf(float f) {
    union { float f; unsigned u; } v; v.f = f;
    unsigned r = v.u + 0x7fffu + ((v.u >> 16) & 1u);
    return (unsigned short)(r >> 16);
}
__device__ inline float bf2f(unsigned short h) {
    union { unsigned u; float f; } v; v.u = ((unsigned)h) << 16; return v.f;
}
__device__ inline float sigmoidf_(float x) { return 1.0f / (1.0f + __expf(-x)); }
__device__ inline float siluf_(float x) { return x / (1.0f + __expf(-x)); }

#define MFMA16(a, b, c) __builtin_amdgcn_mfma_f32_16x16x32_bf16((a), (b), (c), 0, 0, 0)

// ---------------- K1: transpose+convert weights: W (K,N) f32 -> WT (N,K) bf16 ----------------
__global__ __launch_bounds__(256) void k_wT(const float* Wq, const float* Wk, const float* Wv,
                                            const float* Wo, unsigned short* wT)
{
    __shared__ float tile[32][33];
    int z = blockIdx.z;
    const float* W = (z == 0) ? Wq : (z == 1) ? Wk : (z == 2) ? Wv : Wo;
    unsigned short* out = wT + (size_t)z * D * D;
    int kt = blockIdx.x * 32, nt = blockIdx.y * 32;
    int tx = threadIdx.x & 31, ty = threadIdx.x >> 5;
#pragma unroll
    for (int i = 0; i < 4; i++)
        tile[ty + 8 * i][tx] = W[(size_t)(kt + ty + 8 * i) * D + nt + tx];
    __syncthreads();
#pragma unroll
    for (int i = 0; i < 4; i++)
        out[(size_t)(nt + ty + 8 * i) * D + kt + tx] = f2bf(tile[tx][ty + 8 * i]);
}

// ---------------- K2: hidden f32 -> bf16 ----------------
__global__ __launch_bounds__(256) void k_cvt(const float* h, unsigned short* hb, int n4)
{
    int i = blockIdx.x * blockDim.x + threadIdx.x;
    int stride = gridDim.x * blockDim.x;
    const float4* h4 = (const float4*)h;
    for (; i < n4; i += stride) {
        float4 v = h4[i];
        ushort4 o;
        o.x = f2bf(v.x); o.y = f2bf(v.y); o.z = f2bf(v.z); o.w = f2bf(v.w);
        *(ushort4*)(hb + 4 * (size_t)i) = o;
    }
}

// ---------------- K3: QKV GEMM (bf16 MFMA, cache-based) ----------------
__global__ __launch_bounds__(256) void k_gemm_qkv(const unsigned short* A, const unsigned short* wT,
                                                  unsigned short* xq, unsigned short* xk, unsigned short* xv)
{
    int z = blockIdx.z;
    const unsigned short* BT = wT + (size_t)z * D * D;
    unsigned short* out = (z == 0) ? xq : (z == 1) ? xk : xv;
    int wave = threadIdx.x >> 6, lane = threadIdx.x & 63;
    int wm = wave & 1, wn = wave >> 1;
    int m0 = blockIdx.x * 64 + wm * 32;
    int n0 = blockIdx.y * 64 + wn * 32;
    int r16 = lane & 15, quad = lane >> 4;
    f32x4 z4 = {0.f, 0.f, 0.f, 0.f};
    f32x4 acc[2][2];
    acc[0][0] = z4; acc[0][1] = z4; acc[1][0] = z4; acc[1][1] = z4;
    for (int kt = 0; kt < D; kt += 32) {
        bf16x8 a0 = *(const bf16x8*)(A + (size_t)(m0 + r16) * D + kt + quad * 8);
        bf16x8 a1 = *(const bf16x8*)(A + (size_t)(m0 + 16 + r16) * D + kt + quad * 8);
        bf16x8 b0 = *(const bf16x8*)(BT + (size_t)(n0 + r16) * D + kt + quad * 8);
        bf16x8 b1 = *(const bf16x8*)(BT + (size_t)(n0 + 16 + r16) * D + kt + quad * 8);
        acc[0][0] = MFMA16(a0, b0, acc[0][0]);
        acc[0][1] = MFMA16(a0, b1, acc[0][1]);
        acc[1][0] = MFMA16(a1, b0, acc[1][0]);
        acc[1][1] = MFMA16(a1, b1, acc[1][1]);
    }
#pragma unroll
    for (int ms = 0; ms < 2; ms++)
#pragma unroll
        for (int ns = 0; ns < 2; ns++)
#pragma unroll
            for (int r = 0; r < 4; r++) {
                int m = m0 + ms * 16 + quad * 4 + r;
                int n = n0 + ns * 16 + r16;
                out[(size_t)m * D + n] = f2bf(acc[ms][ns][r]);
            }
}

// ---------------- K4: small projections: beta/gamma (sigmoid), xmix raw ----------------
__global__ __launch_bounds__(256) void k_smallproj(const float* hid, const float* Wb, const float* Wd,
                                                   const float* Wm, float* beta, float* gamma, float* xmix)
{
    int wave = threadIdx.x >> 6, lane = threadIdx.x & 63;
    int row = blockIdx.x * 4 + wave;
    const float* hrow = hid + (size_t)row * D;
    float acc[12];
#pragma unroll
    for (int j = 0; j < 12; j++) acc[j] = 0.f;
    for (int i = 0; i < 16; i++) {
        int k = lane + 64 * i;
        float h = hrow[k];
        float4 wb = ((const float4*)Wb)[k];
        float4 wd = ((const float4*)Wd)[k];
        float4 wm = ((const float4*)Wm)[k];
        acc[0] += h * wb.x; acc[1] += h * wb.y; acc[2] += h * wb.z; acc[3] += h * wb.w;
        acc[4] += h * wd.x; acc[5] += h * wd.y; acc[6] += h * wd.z; acc[7] += h * wd.w;
        acc[8] += h * wm.x; acc[9] += h * wm.y; acc[10] += h * wm.z; acc[11] += h * wm.w;
    }
#pragma unroll
    for (int j = 0; j < 12; j++)
        for (int off = 32; off; off >>= 1) acc[j] += __shfl_xor(acc[j], off, 64);
    if (lane < 4) {
        beta[(size_t)row * 4 + lane] = sigmoidf_(acc[lane]);
        gamma[(size_t)row * 4 + lane] = sigmoidf_(acc[4 + lane]);
        xmix[(size_t)row * 4 + lane] = acc[8 + lane];
    }
}

// ---------------- K5: short conv + silu (q,k double-silu; v single) ----------------
__global__ __launch_bounds__(256) void k_conv(const unsigned short* xq, const unsigned short* xk,
                                              const unsigned short* xv,
                                              const float* cq, const float* ck, const float* cv,
                                              float* q, float* k, float* v)
{
    int z = blockIdx.z;
    const unsigned short* src = (z == 0) ? xq : (z == 1) ? xk : xv;
    const float* cw = (z == 0) ? cq : (z == 1) ? ck : cv;
    float* dst = (z == 0) ? q : (z == 1) ? k : v;
    int idx = blockIdx.x * 256 + threadIdx.x;
    int c = idx & (D - 1);
    int t = (idx >> 10) & (L - 1);
    int b = idx >> 21;
    float4 w4 = *(const float4*)(cw + (size_t)c * 4);
    float wv[4] = {w4.x, w4.y, w4.z, w4.w};
    size_t base = (size_t)(b * L) * D + c;
    float acc = 0.f;
#pragma unroll
    for (int kk = 0; kk < 4; kk++) {
        int tt = t - 3 + kk;
        if (tt >= 0) acc += wv[kk] * bf2f(src[base + (size_t)tt * D]);
    }
    float r = siluf_(acc);
    if (z < 2) r = siluf_(r);
    dst[idx] = r;
}

// ---------------- K6: mix conv + silu (H channels) ----------------
__global__ __launch_bounds__(256) void k_convmix(const float* xmix, const float* cmix, float* mixinp)
{
    int idx = blockIdx.x * 256 + threadIdx.x;   // < B*L*NH
    int h = idx & 3;
    int t = (idx >> 2) & (L - 1);
    int b = idx >> 13;
    float acc = 0.f;
#pragma unroll
    for (int kk = 0; kk < 4; kk++) {
        int tt = t - 3 + kk;
        if (tt >= 0) acc += cmix[h * 4 + kk] * xmix[((size_t)(b * L + tt) << 2) + h];
    }
    mixinp[idx] = siluf_(acc);
}

// ---------------- K7a: l2norm q,k -> bf16 (bh, L, DK) ----------------
__global__ __launch_bounds__(256) void k_l2norm(const float* qbuf, const float* kbuf,
                                                unsigned short* qn, unsigned short* kn)
{
    int wave = threadIdx.x >> 6, lane = threadIdx.x & 63;
    int rid = blockIdx.x * 4 + wave;      // 0..BH*L-1
    int bh = rid >> 11, t = rid & (L - 1);
    int b = bh >> 2, h = bh & 3;
    size_t src = (size_t)(b * L + t) * D + h * DK + lane * 4;
    float4 q4 = *(const float4*)(qbuf + src);
    float4 k4 = *(const float4*)(kbuf + src);
    float sq = q4.x * q4.x + q4.y * q4.y + q4.z * q4.z + q4.w * q4.w;
    float sk = k4.x * k4.x + k4.y * k4.y + k4.z * k4.z + k4.w * k4.w;
    for (int off = 32; off; off >>= 1) { sq += __shfl_xor(sq, off, 64); sk += __shfl_xor(sk, off, 64); }
    float qsc = rsqrtf(sq + 1e-6f);
    float ksc = rsqrtf(sk + 1e-6f);
    uint2 pq, pk;
    pq.x = f2bf(q4.x * qsc) | ((unsigned)f2bf(q4.y * qsc) << 16);
    pq.y = f2bf(q4.z * qsc) | ((unsigned)f2bf(q4.w * qsc) << 16);
    pk.x = f2bf(k4.x * ksc) | ((unsigned)f2bf(k4.y * ksc) << 16);
    pk.y = f2bf(k4.z * ksc) | ((unsigned)f2bf(k4.w * ksc) << 16);
    *(uint2*)(qn + (size_t)rid * DK + lane * 4) = pq;
    *(uint2*)(kn + (size_t)rid * DK + lane * 4) = pk;
}

// ---------------- K7b: per-(bh,chunk) delta-rule precompute ----------------
__global__ __launch_bounds__(256) void k_delta_pre(const unsigned short* qn, const unsigned short* kn,
                                                   const float* vbuf, const float* beta,
                                                   unsigned short* wneg, unsigned short* knT,
                                                   unsigned short* attnb, float* u)
{
    __shared__ __align__(16) float ks[32 * 260];
    __shared__ float Tm[32 * 33];
    __shared__ float betav[32];
    int bx = blockIdx.x;
    int bh = bx >> 6, ch = bx & 63;
    int b = bh >> 2, h = bh & 3;
    int t0 = ch * 32;
    int tid = threadIdx.x;
    int r = tid >> 3, part = tid & 7;

    // stage normalized k (bf16 -> f32) into LDS
    const unsigned short* knrow = kn + (size_t)(bh * L + t0 + r) * DK;
#pragma unroll
    for (int i = 0; i < 8; i++) {
        int c = (part + 8 * i) * 4;
        ushort4 kv = *(const ushort4*)(knrow + c);
        ks[r * 260 + c + 0] = bf2f(kv.x);
        ks[r * 260 + c + 1] = bf2f(kv.y);
        ks[r * 260 + c + 2] = bf2f(kv.z);
        ks[r * 260 + c + 3] = bf2f(kv.w);
    }
    if (tid < 32) betav[tid] = beta[(size_t)(b * L + t0 + tid) * NH + h];
    __syncthreads();

    // G = k.kT, QK = q.kT; init Tm strict-lower = -beta_i*G; write attnb (tril incl) bf16
    {
        int i = tid >> 3, j0 = (tid & 7) * 4;
        const unsigned short* qrow = qn + (size_t)(bh * L + t0 + i) * DK;
        float g[4] = {0.f, 0.f, 0.f, 0.f};
        float a[4] = {0.f, 0.f, 0.f, 0.f};
        for (int c = 0; c < DK; c += 4) {
            ushort4 qv = *(const ushort4*)(qrow + c);
            float q0 = bf2f(qv.x), q1 = bf2f(qv.y), q2 = bf2f(qv.z), q3 = bf2f(qv.w);
            float4 ki = *(const float4*)&ks[i * 260 + c];
#pragma unroll
            for (int jj = 0; jj < 4; jj++) {
                float4 kj = *(const float4*)&ks[(j0 + jj) * 260 + c];
                g[jj] += ki.x * kj.x + ki.y * kj.y + ki.z * kj.z + ki.w * kj.w;
                a[jj] += q0 * kj.x + q1 * kj.y + q2 * kj.z + q3 * kj.w;
            }
        }
#pragma unroll
        for (int jj = 0; jj < 4; jj++) {
            int j = j0 + jj;
            Tm[i * 33 + j] = (j < i) ? (-betav[i] * g[jj]) : 0.0f;
            if (j > i) a[jj] = 0.f;
        }
        uint2 p;
        p.x = f2bf(a[0]) | ((unsigned)f2bf(a[1]) << 16);
        p.y = f2bf(a[2]) | ((unsigned)f2bf(a[3]) << 16);
        *(uint2*)(attnb + (size_t)(bh * 64 + ch) * 1024 + i * 32 + j0) = p;
    }
    __syncthreads();

    // forward substitution
    for (int i = 1; i < 32; i++) {
        float s = 0.f;
        bool act = (tid < i);
        if (act) {
            s = Tm[i * 33 + tid];
            for (int j = tid + 1; j < i; j++) s += Tm[i * 33 + j] * Tm[j * 33 + tid];
        }
        __syncthreads();
        if (act) Tm[i * 33 + tid] = s;
        __syncthreads();
    }
    // T2 = (T + I) * diag(beta)
    for (int idx = tid; idx < 1024; idx += 256) {
        int i = idx >> 5, j = idx & 31;
        float val = (j == i) ? 1.0f : Tm[i * 33 + j]; // j>i slots already 0
        Tm[i * 33 + j] = val * betav[j];
    }
    __syncthreads();

    // u = T2 @ v (raw v), wneg = -(T2 @ k_hat)
    {
        const float* vrow0 = vbuf + (size_t)(b * L + t0) * D + h * DK;
        float* ug = u + (size_t)(bh * L + t0 + r) * DK;
        unsigned short* wg = wneg + (size_t)(bh * L + t0 + r) * DK;
        for (int ccb = 0; ccb < 8; ccb++) {
            int c = part * 4 + 32 * ccb;
            float au0 = 0, au1 = 0, au2 = 0, au3 = 0;
            float aw0 = 0, aw1 = 0, aw2 = 0, aw3 = 0;
            for (int j = 0; j < 32; j++) {
                float t2 = Tm[r * 33 + j];
                float4 vj = *(const float4*)(vrow0 + (size_t)j * D + c);
                float4 kj = *(const float4*)&ks[j * 260 + c];
                au0 += t2 * vj.x; au1 += t2 * vj.y; au2 += t2 * vj.z; au3 += t2 * vj.w;
                aw0 += t2 * kj.x; aw1 += t2 * kj.y; aw2 += t2 * kj.z; aw3 += t2 * kj.w;
            }
            float4 uo; uo.x = au0; uo.y = au1; uo.z = au2; uo.w = au3;
            *(float4*)(ug + c) = uo;
            uint2 p;
            p.x = f2bf(-aw0) | ((unsigned)f2bf(-aw1) << 16);
            p.y = f2bf(-aw2) | ((unsigned)f2bf(-aw3) << 16);
            *(uint2*)(wg + c) = p;
        }
    }
    // knT (bh,ch,DK,32) bf16
    {
        int kk = tid;
        unsigned short* kT = knT + ((size_t)(bh * 64 + ch) * DK + kk) * 32;
#pragma unroll
        for (int r2 = 0; r2 < 32; r2 += 2) {
            unsigned pv = f2bf(ks[r2 * 260 + kk]) | ((unsigned)f2bf(ks[(r2 + 1) * 260 + kk]) << 16);
            *(unsigned*)(kT + r2) = pv;
        }
    }
}

// ---------------- K8: EMA over time ----------------
__global__ __launch_bounds__(256) void k_ema(const float* v, const float* gamma, float* ema)
{
    int bh = blockIdx.x;
    int b = bh >> 2, h = bh & 3;
    int c = threadIdx.x;
    __shared__ float gsh[64];
    float s = 0.f;
    const float* vg = v + (size_t)(b * L) * D + h * DK + c;
    float* eg = ema + (size_t)(b * L) * D + h * DK + c;
    const float* gg = gamma + (size_t)(b * L) * NH + h;
    for (int tb = 0; tb < L; tb += 64) {
        __syncthreads();
        if (threadIdx.x < 64) gsh[threadIdx.x] = gg[(size_t)(tb + threadIdx.x) * NH];
        __syncthreads();
#pragma unroll 8
        for (int i = 0; i < 64; i++) {
            int t = tb + i;
            float g = gsh[i];
            float vv = vg[(size_t)t * D];
            s = g * s + (1.f - g) * vv;
            eg[(size_t)t * D] = s;
        }
    }
}

// ---------------- K9: sequential inter-chunk scan (MFMA, S in AGPRs) ----------------
__global__ __launch_bounds__(256) void k_scan(const unsigned short* qn, const unsigned short* wneg,
                                              const unsigned short* knT, const unsigned short* attnb,
                                              const float* u, float* od)
{
    __shared__ __align__(16) unsigned short st[32 * 264];   // S^T bf16: [c][kk]
    __shared__ __align__(16) unsigned short uat[32 * 40];   // u_adj^T bf16: [c][r]
    int tile = blockIdx.x;      // dv tile (0..7), 32 cols
    int bh = blockIdx.y;
    int b = bh >> 2, h = bh & 3;
    int wave = threadIdx.x >> 6, lane = threadIdx.x & 63;
    int r16 = lane & 15, quad = lane >> 4;
    int mo = wave & 1, no = wave >> 1;
    int cbase = tile * 32;
    f32x4 z4 = {0.f, 0.f, 0.f, 0.f};
    f32x4 sacc[4][2];
#pragma unroll
    for (int a = 0; a < 4; a++) { sacc[a][0] = z4; sacc[a][1] = z4; }
    const unsigned short* qb = qn + (size_t)bh * L * DK;
    const unsigned short* wb = wneg + (size_t)bh * L * DK;
    const float* ub = u + (size_t)bh * L * DK;

    for (int ch = 0; ch < NCH; ch++) {
        int t0 = ch * 32;
        // (A) refresh S^T bf16 in LDS from fp32 accumulators
#pragma unroll
        for (int a = 0; a < 4; a++) {
            int kkb = (wave * 4 + a) * 16 + quad * 4;
#pragma unroll
            for (int ni = 0; ni < 2; ni++) {
                int c = ni * 16 + r16;
                unsigned p0 = f2bf(sacc[a][ni][0]) | ((unsigned)f2bf(sacc[a][ni][1]) << 16);
                unsigned p1 = f2bf(sacc[a][ni][2]) | ((unsigned)f2bf(sacc[a][ni][3]) << 16);
                *(unsigned*)&st[c * 264 + kkb] = p0;
                *(unsigned*)&st[c * 264 + kkb + 2] = p1;
            }
        }
        __syncthreads();

        // (C) u_adj = u - w@S  and o_partial = q@S   (this wave's 16x16 tile: rows 16*mo, cols 16*no)
        f32x4 au, ao = z4;
        {
            const float* up = ub + (size_t)(t0 + 16 * mo + quad * 4) * DK + cbase + no * 16 + r16;
            au[0] = up[0]; au[1] = up[DK]; au[2] = up[2 * DK]; au[3] = up[3 * DK];
        }
        const unsigned short* wrow = wb + (size_t)(t0 + 16 * mo + r16) * DK;
        const unsigned short* qrow = qb + (size_t)(t0 + 16 * mo + r16) * DK;
#pragma unroll
        for (int kt = 0; kt < 8; kt++) {
            bf16x8 bf = *(const bf16x8*)&st[(no * 16 + r16) * 264 + kt * 32 + quad * 8];
            bf16x8 wf = *(const bf16x8*)(wrow + kt * 32 + quad * 8);
            bf16x8 qf = *(const bf16x8*)(qrow + kt * 32 + quad * 8);
            au = MFMA16(wf, bf, au);
            ao = MFMA16(qf, bf, ao);
        }
        // (D) write u_adj^T bf16
        {
            int c = no * 16 + r16;
            int rb = 16 * mo + quad * 4;
            *(unsigned*)&uat[c * 40 + rb] = f2bf(au[0]) | ((unsigned)f2bf(au[1]) << 16);
            *(unsigned*)&uat[c * 40 + rb + 2] = f2bf(au[2]) | ((unsigned)f2bf(au[3]) << 16);
        }
        __syncthreads();

        // (F) o = q@S + attn@u_adj ; store ; S += kT @ u_adj
        {
            bf16x8 af = *(const bf16x8*)(attnb + (size_t)(bh * 64 + ch) * 1024 + (16 * mo + r16) * 32 + quad * 8);
            bf16x8 uf = *(const bf16x8*)&uat[(no * 16 + r16) * 40 + quad * 8];
            ao = MFMA16(af, uf, ao);
            float* op = od + (size_t)(b * L + t0 + 16 * mo + quad * 4) * D + h * DK + cbase + no * 16 + r16;
            op[0] = ao[0]; op[D] = ao[1]; op[2 * D] = ao[2]; op[3 * D] = ao[3];

            bf16x8 u0 = *(const bf16x8*)&uat[(r16) * 40 + quad * 8];
            bf16x8 u1 = *(const bf16x8*)&uat[(16 + r16) * 40 + quad * 8];
            const unsigned short* kTb = knT + (size_t)(bh * 64 + ch) * DK * 32;
#pragma unroll
            for (int a = 0; a < 4; a++) {
                bf16x8 kf = *(const bf16x8*)(kTb + (size_t)((wave * 4 + a) * 16 + r16) * 32 + quad * 8);
                sacc[a][0] = MFMA16(kf, u0, sacc[a][0]);
                sacc[a][1] = MFMA16(kf, u1, sacc[a][1]);
            }
        }
        // next iteration's first barrier protects uat/st reuse
    }
}

// ---------------- K10: mix + per-head RMS norm -> bf16 ----------------
__global__ __launch_bounds__(256) void k_mixrms(const float* od, const float* ema, const float* mixinp,
                                                const float* mix_bias, const float* rms_w,
                                                unsigned short* onorm)
{
    int row = blockIdx.x;       // b*L + t
    int t = threadIdx.x;
    int h = t >> 6, lane = t & 63;
    float m = sigmoidf_(mixinp[(size_t)row * NH + h] + mix_bias[h]);
    int c = t * 4;
    float4 o = *(const float4*)(od + (size_t)row * D + c);
    float4 e = *(const float4*)(ema + (size_t)row * D + c);
    float x0 = o.x + m * (e.x - o.x);
    float x1 = o.y + m * (e.y - o.y);
    float x2 = o.z + m * (e.z - o.z);
    float x3 = o.w + m * (e.w - o.w);
    float ss = x0 * x0 + x1 * x1 + x2 * x2 + x3 * x3;
    for (int off = 32; off; off >>= 1) ss += __shfl_xor(ss, off, 64);
    float scale = rsqrtf(ss * (1.0f / 256.0f) + 1e-5f);
    float4 w = *(const float4*)(rms_w + lane * 4);
    uint2 p;
    p.x = f2bf(x0 * scale * w.x) | ((unsigned)f2bf(x1 * scale * w.y) << 16);
    p.y = f2bf(x2 * scale * w.z) | ((unsigned)f2bf(x3 * scale * w.w) << 16);
    *(uint2*)(onorm + (size_t)row * D + c) = p;
}

// ---------------- K11: output GEMM ----------------
__global__ __launch_bounds__(256) void k_gemm_out(const unsigned short* A, const unsigned short* BT, float* out)
{
    int wave = threadIdx.x >> 6, lane = threadIdx.x & 63;
    int wm = wave & 1, wn = wave >> 1;
    int m0 = blockIdx.x * 64 + wm * 32;
    int n0 = blockIdx.y * 64 + wn * 32;
    int r16 = lane & 15, quad = lane >> 4;
    f32x4 z4 = {0.f, 0.f, 0.f, 0.f};
    f32x4 acc[2][2];
    acc[0][0] = z4; acc[0][1] = z4; acc[1][0] = z4; acc[1][1] = z4;
    for (int kt = 0; kt < D; kt += 32) {
        bf16x8 a0 = *(const bf16x8*)(A + (size_t)(m0 + r16) * D + kt + quad * 8);
        bf16x8 a1 = *(const bf16x8*)(A + (size_t)(m0 + 16 + r16) * D + kt + quad * 8);
        bf16x8 b0 = *(const bf16x8*)(BT + (size_t)(n0 + r16) * D + kt + quad * 8);
        bf16x8 b1 = *(const bf16x8*)(BT + (size_t)(n0 + 16 + r16) * D + kt + quad * 8);
        acc[0][0] = MFMA16(a0, b0, acc[0][0]);
        acc[0][1] = MFMA16(a0, b1, acc[0][1]);
        acc[1][0] = MFMA16(a1, b0, acc[1][0]);
        acc[1][1] = MFMA16(a1, b1, acc[1][1]);
    }
#pragma unroll
    for (int ms = 0; ms < 2; ms++)
#pragma unroll
        for (int ns = 0; ns < 2; ns++)
#pragma unroll
            for (int r = 0; r < 4; r++) {
                int m = m0 + ms * 16 + quad * 4 + r;
                int n = n0 + ns * 16 + r16;
                out[(size_t)m * D + n] = acc[ms][ns][r];
            }
}

extern "C" void kernel_launch(void* const* d_in, const int* in_sizes, int n_in,
                              void* d_out, int out_size, void* d_ws, size_t ws_size,
                              hipStream_t stream)
{
    (void)in_sizes; (void)n_in; (void)out_size; (void)ws_size;
    const float* hidden   = (const float*)d_in[0];
    const float* Wq       = (const float*)d_in[1];
    const float* Wk       = (const float*)d_in[2];
    const float* Wv       = (const float*)d_in[3];
    const float* conv_q   = (const float*)d_in[4];
    const float* conv_k   = (const float*)d_in[5];
    const float* conv_v   = (const float*)d_in[6];
    const float* Wb       = (const float*)d_in[7];
    const float* Wdec     = (const float*)d_in[8];
    const float* Wmix     = (const float*)d_in[9];
    const float* conv_mix = (const float*)d_in[10];
    const float* mix_bias = (const float*)d_in[11];
    const float* rms_w    = (const float*)d_in[12];
    const float* Wo       = (const float*)d_in[13];
    float* out = (float*)d_out;

    char* ws = (char*)d_ws;
    size_t off = 0;
    auto alloc = [&](size_t bytes) -> char* {
        char* p = ws + off;
        off += (bytes + 255) & ~(size_t)255;
        return p;
    };
    unsigned short* wT    = (unsigned short*)alloc((size_t)4 * D * D * 2);
    unsigned short* hidB  = (unsigned short*)alloc((size_t)B * L * D * 2);
    unsigned short* xq    = (unsigned short*)alloc((size_t)B * L * D * 2);   // later qn
    unsigned short* xk    = (unsigned short*)alloc((size_t)B * L * D * 2);   // later wneg
    unsigned short* xv    = (unsigned short*)alloc((size_t)B * L * D * 2);   // later knT
    float* beta   = (float*)alloc((size_t)B * L * NH * 4);
    float* gamma  = (float*)alloc((size_t)B * L * NH * 4);
    float* xmix   = (float*)alloc((size_t)B * L * NH * 4);
    float* mixinp = (float*)alloc((size_t)B * L * NH * 4);
    float* qbuf   = (float*)alloc((size_t)B * L * D * 4);   // later ema
    float* kbuf   = (float*)alloc((size_t)B * L * D * 4);   // later od
    float* vbuf   = (float*)alloc((size_t)B * L * D * 4);
    float* u      = (float*)alloc((size_t)B * L * D * 4);
    unsigned short* attnb = (unsigned short*)alloc((size_t)BH * NCH * CHUNK * CHUNK * 2);
    unsigned short* onorm = (unsigned short*)alloc((size_t)B * L * D * 2);
    unsigned short* kn    = (unsigned short*)alloc((size_t)B * L * D * 2);

    unsigned short* qn   = xq;
    unsigned short* wneg = xk;
    unsigned short* knT  = xv;
    float* ema = qbuf;
    float* od  = kbuf;

    k_wT<<<dim3(32, 32, 4), 256, 0, stream>>>(Wq, Wk, Wv, Wo, wT);
    k_cvt<<<dim3(2048), 256, 0, stream>>>(hidden, hidB, B * L * D / 4);
    k_gemm_qkv<<<dim3(128, 16, 3), 256, 0, stream>>>(hidB, wT, xq, xk, xv);
    k_smallproj<<<dim3(B * L / 4), 256, 0, stream>>>(hidden, Wb, Wdec, Wmix, beta, gamma, xmix);
    k_conv<<<dim3(B * L * D / 256, 1, 3), 256, 0, stream>>>(xq, xk, xv, conv_q, conv_k, conv_v,
                                                            qbuf, kbuf, vbuf);
    k_convmix<<<dim3(B * L * NH / 256), 256, 0, stream>>>(xmix, conv_mix, mixinp);
    k_l2norm<<<dim3(BH * L / 4), 256, 0, stream>>>(qbuf, kbuf, qn, kn);
    k_delta_pre<<<dim3(BH * NCH), 256, 0, stream>>>(qn, kn, vbuf, beta, wneg, knT, attnb, u);
    k_ema<<<dim3(BH), 256, 0, stream>>>(vbuf, gamma, ema);
    k_scan<<<dim3(8, 16), 256, 0, stream>>>(qn, wneg, knT, attnb, u, od);
    k_mixrms<<<dim3(B * L), 256, 0, stream>>>(od, ema, mixinp, mix_bias, rms_w, onorm);
    k_gemm_out<<<dim3(128, 16), 256, 0, stream>>>(onorm, wT + (size_t)3 * D * D, out);
}

// Round 2
// 1111.566 us; speedup vs baseline: 1.4124x; 1.4124x over previous
//
#include <hip/hip_runtime.h>
#include <hip/hip_bf16.h>

#define B 4
#define L 2048
#define D 1024
#define NH 4
#define DK 256
#define CHUNK 32
#define NCH 64
#define BH (B*NH)
// EMA chunking
#define ET 64
#define ENCH (L/ET)

typedef __attribute__((ext_vector_type(8))) __bf16 bf16x8;
typedef __attribute__((ext_vector_type(4))) float f32x4;

__device__ inline unsigned short f2bf(float f) {
    union { float f; unsigned u; } v; v.f = f;
    unsigned r = v.u + 0x7fffu + ((v.u >> 16) & 1u);
    return (unsigned short)(r >> 16);
}
__device__ inline float bf2f(unsigned short h) {
    union { unsigned u; float f; } v; v.u = ((unsigned)h) << 16; return v.f;
}
__device__ inline float sigmoidf_(float x) { return 1.0f / (1.0f + __expf(-x)); }
__device__ inline float siluf_(float x) { return x / (1.0f + __expf(-x)); }

#define MFMA16(a, b, c) __builtin_amdgcn_mfma_f32_16x16x32_bf16((a), (b), (c), 0, 0, 0)

// ---------------- K1: transpose+convert weights: W (K,N) f32 -> WT (N,K) bf16 ----------------
__global__ __launch_bounds__(256) void k_wT(const float* Wq, const float* Wk, const float* Wv,
                                            const float* Wo, unsigned short* wT)
{
    __shared__ float tile[32][33];
    int z = blockIdx.z;
    const float* W = (z == 0) ? Wq : (z == 1) ? Wk : (z == 2) ? Wv : Wo;
    unsigned short* out = wT + (size_t)z * D * D;
    int kt = blockIdx.x * 32, nt = blockIdx.y * 32;
    int tx = threadIdx.x & 31, ty = threadIdx.x >> 5;
#pragma unroll
    for (int i = 0; i < 4; i++)
        tile[ty + 8 * i][tx] = W[(size_t)(kt + ty + 8 * i) * D + nt + tx];
    __syncthreads();
#pragma unroll
    for (int i = 0; i < 4; i++)
        out[(size_t)(nt + ty + 8 * i) * D + kt + tx] = f2bf(tile[tx][ty + 8 * i]);
}

// ---------------- K2: hidden f32 -> bf16 ----------------
__global__ __launch_bounds__(256) void k_cvt(const float* h, unsigned short* hb, int n4)
{
    int i = blockIdx.x * blockDim.x + threadIdx.x;
    int stride = gridDim.x * blockDim.x;
    const float4* h4 = (const float4*)h;
    for (; i < n4; i += stride) {
        float4 v = h4[i];
        ushort4 o;
        o.x = f2bf(v.x); o.y = f2bf(v.y); o.z = f2bf(v.z); o.w = f2bf(v.w);
        *(ushort4*)(hb + 4 * (size_t)i) = o;
    }
}

// ---------------- K3: QKV GEMM (bf16 MFMA, cache-based) ----------------
__global__ __launch_bounds__(256) void k_gemm_qkv(const unsigned short* A, const unsigned short* wT,
                                                  unsigned short* xq, unsigned short* xk, unsigned short* xv)
{
    int z = blockIdx.z;
    const unsigned short* BT = wT + (size_t)z * D * D;
    unsigned short* out = (z == 0) ? xq : (z == 1) ? xk : xv;
    int wave = threadIdx.x >> 6, lane = threadIdx.x & 63;
    int wm = wave & 1, wn = wave >> 1;
    int m0 = blockIdx.x * 64 + wm * 32;
    int n0 = blockIdx.y * 64 + wn * 32;
    int r16 = lane & 15, quad = lane >> 4;
    f32x4 z4 = {0.f, 0.f, 0.f, 0.f};
    f32x4 acc[2][2];
    acc[0][0] = z4; acc[0][1] = z4; acc[1][0] = z4; acc[1][1] = z4;
    for (int kt = 0; kt < D; kt += 32) {
        bf16x8 a0 = *(const bf16x8*)(A + (size_t)(m0 + r16) * D + kt + quad * 8);
        bf16x8 a1 = *(const bf16x8*)(A + (size_t)(m0 + 16 + r16) * D + kt + quad * 8);
        bf16x8 b0 = *(const bf16x8*)(BT + (size_t)(n0 + r16) * D + kt + quad * 8);
        bf16x8 b1 = *(const bf16x8*)(BT + (size_t)(n0 + 16 + r16) * D + kt + quad * 8);
        acc[0][0] = MFMA16(a0, b0, acc[0][0]);
        acc[0][1] = MFMA16(a0, b1, acc[0][1]);
        acc[1][0] = MFMA16(a1, b0, acc[1][0]);
        acc[1][1] = MFMA16(a1, b1, acc[1][1]);
    }
#pragma unroll
    for (int ms = 0; ms < 2; ms++)
#pragma unroll
        for (int ns = 0; ns < 2; ns++)
#pragma unroll
            for (int r = 0; r < 4; r++) {
                int m = m0 + ms * 16 + quad * 4 + r;
                int n = n0 + ns * 16 + r16;
                out[(size_t)m * D + n] = f2bf(acc[ms][ns][r]);
            }
}

// ---------------- K4: small projections: beta/gamma (sigmoid), xmix raw ----------------
__global__ __launch_bounds__(256) void k_smallproj(const float* hid, const float* Wb, const float* Wd,
                                                   const float* Wm, float* beta, float* gamma, float* xmix)
{
    int wave = threadIdx.x >> 6, lane = threadIdx.x & 63;
    int row = blockIdx.x * 4 + wave;
    const float* hrow = hid + (size_t)row * D;
    float acc[12];
#pragma unroll
    for (int j = 0; j < 12; j++) acc[j] = 0.f;
    for (int i = 0; i < 16; i++) {
        int k = lane + 64 * i;
        float h = hrow[k];
        float4 wb = ((const float4*)Wb)[k];
        float4 wd = ((const float4*)Wd)[k];
        float4 wm = ((const float4*)Wm)[k];
        acc[0] += h * wb.x; acc[1] += h * wb.y; acc[2] += h * wb.z; acc[3] += h * wb.w;
        acc[4] += h * wd.x; acc[5] += h * wd.y; acc[6] += h * wd.z; acc[7] += h * wd.w;
        acc[8] += h * wm.x; acc[9] += h * wm.y; acc[10] += h * wm.z; acc[11] += h * wm.w;
    }
#pragma unroll
    for (int j = 0; j < 12; j++)
        for (int off = 32; off; off >>= 1) acc[j] += __shfl_xor(acc[j], off, 64);
    if (lane < 4) {
        beta[(size_t)row * 4 + lane] = sigmoidf_(acc[lane]);
        gamma[(size_t)row * 4 + lane] = sigmoidf_(acc[4 + lane]);
        xmix[(size_t)row * 4 + lane] = acc[8 + lane];
    }
}

// ---------------- K5: short conv + silu (q,k double-silu; v single) ----------------
__global__ __launch_bounds__(256) void k_conv(const unsigned short* xq, const unsigned short* xk,
                                              const unsigned short* xv,
                                              const float* cq, const float* ck, const float* cv,
                                              float* q, float* k, float* v)
{
    int z = blockIdx.z;
    const unsigned short* src = (z == 0) ? xq : (z == 1) ? xk : xv;
    const float* cw = (z == 0) ? cq : (z == 1) ? ck : cv;
    float* dst = (z == 0) ? q : (z == 1) ? k : v;
    int idx = blockIdx.x * 256 + threadIdx.x;
    int c = idx & (D - 1);
    int t = (idx >> 10) & (L - 1);
    int b = idx >> 21;
    float4 w4 = *(const float4*)(cw + (size_t)c * 4);
    float wv[4] = {w4.x, w4.y, w4.z, w4.w};
    size_t base = (size_t)(b * L) * D + c;
    float acc = 0.f;
#pragma unroll
    for (int kk = 0; kk < 4; kk++) {
        int tt = t - 3 + kk;
        if (tt >= 0) acc += wv[kk] * bf2f(src[base + (size_t)tt * D]);
    }
    float r = siluf_(acc);
    if (z < 2) r = siluf_(r);
    dst[idx] = r;
}

// ---------------- K6: mix conv + silu (H channels) ----------------
__global__ __launch_bounds__(256) void k_convmix(const float* xmix, const float* cmix, float* mixinp)
{
    int idx = blockIdx.x * 256 + threadIdx.x;   // < B*L*NH
    int h = idx & 3;
    int t = (idx >> 2) & (L - 1);
    int b = idx >> 13;
    float acc = 0.f;
#pragma unroll
    for (int kk = 0; kk < 4; kk++) {
        int tt = t - 3 + kk;
        if (tt >= 0) acc += cmix[h * 4 + kk] * xmix[((size_t)(b * L + tt) << 2) + h];
    }
    mixinp[idx] = siluf_(acc);
}

// ---------------- K7a: l2norm q,k -> bf16 (bh, L, DK) ----------------
__global__ __launch_bounds__(256) void k_l2norm(const float* qbuf, const float* kbuf,
                                                unsigned short* qn, unsigned short* kn)
{
    int wave = threadIdx.x >> 6, lane = threadIdx.x & 63;
    int rid = blockIdx.x * 4 + wave;      // 0..BH*L-1
    int bh = rid >> 11, t = rid & (L - 1);
    int b = bh >> 2, h = bh & 3;
    size_t src = (size_t)(b * L + t) * D + h * DK + lane * 4;
    float4 q4 = *(const float4*)(qbuf + src);
    float4 k4 = *(const float4*)(kbuf + src);
    float sq = q4.x * q4.x + q4.y * q4.y + q4.z * q4.z + q4.w * q4.w;
    float sk = k4.x * k4.x + k4.y * k4.y + k4.z * k4.z + k4.w * k4.w;
    for (int off = 32; off; off >>= 1) { sq += __shfl_xor(sq, off, 64); sk += __shfl_xor(sk, off, 64); }
    float qsc = rsqrtf(sq + 1e-6f);
    float ksc = rsqrtf(sk + 1e-6f);
    uint2 pq, pk;
    pq.x = f2bf(q4.x * qsc) | ((unsigned)f2bf(q4.y * qsc) << 16);
    pq.y = f2bf(q4.z * qsc) | ((unsigned)f2bf(q4.w * qsc) << 16);
    pk.x = f2bf(k4.x * ksc) | ((unsigned)f2bf(k4.y * ksc) << 16);
    pk.y = f2bf(k4.z * ksc) | ((unsigned)f2bf(k4.w * ksc) << 16);
    *(uint2*)(qn + (size_t)rid * DK + lane * 4) = pq;
    *(uint2*)(kn + (size_t)rid * DK + lane * 4) = pk;
}

// ---------------- K7b: per-(bh,chunk) delta-rule precompute ----------------
__global__ __launch_bounds__(256) void k_delta_pre(const unsigned short* qn, const unsigned short* kn,
                                                   const float* vbuf, const float* beta,
                                                   unsigned short* wneg, unsigned short* knT,
                                                   unsigned short* attnb, float* u)
{
    __shared__ __align__(16) float ks[32 * 260];
    __shared__ float Tm[32 * 33];
    __shared__ float betav[32];
    int bx = blockIdx.x;
    int bh = bx >> 6, ch = bx & 63;
    int b = bh >> 2, h = bh & 3;
    int t0 = ch * 32;
    int tid = threadIdx.x;
    int r = tid >> 3, part = tid & 7;

    // stage normalized k (bf16 -> f32) into LDS
    const unsigned short* knrow = kn + (size_t)(bh * L + t0 + r) * DK;
#pragma unroll
    for (int i = 0; i < 8; i++) {
        int c = (part + 8 * i) * 4;
        ushort4 kv = *(const ushort4*)(knrow + c);
        ks[r * 260 + c + 0] = bf2f(kv.x);
        ks[r * 260 + c + 1] = bf2f(kv.y);
        ks[r * 260 + c + 2] = bf2f(kv.z);
        ks[r * 260 + c + 3] = bf2f(kv.w);
    }
    if (tid < 32) betav[tid] = beta[(size_t)(b * L + t0 + tid) * NH + h];
    __syncthreads();

    // G = k.kT, QK = q.kT; init Tm strict-lower = -beta_i*G; write attnb (tril incl) bf16
    {
        int i = tid >> 3, j0 = (tid & 7) * 4;
        const unsigned short* qrow = qn + (size_t)(bh * L + t0 + i) * DK;
        float g[4] = {0.f, 0.f, 0.f, 0.f};
        float a[4] = {0.f, 0.f, 0.f, 0.f};
        for (int c = 0; c < DK; c += 4) {
            ushort4 qv = *(const ushort4*)(qrow + c);
            float q0 = bf2f(qv.x), q1 = bf2f(qv.y), q2 = bf2f(qv.z), q3 = bf2f(qv.w);
            float4 ki = *(const float4*)&ks[i * 260 + c];
#pragma unroll
            for (int jj = 0; jj < 4; jj++) {
                float4 kj = *(const float4*)&ks[(j0 + jj) * 260 + c];
                g[jj] += ki.x * kj.x + ki.y * kj.y + ki.z * kj.z + ki.w * kj.w;
                a[jj] += q0 * kj.x + q1 * kj.y + q2 * kj.z + q3 * kj.w;
            }
        }
#pragma unroll
        for (int jj = 0; jj < 4; jj++) {
            int j = j0 + jj;
            Tm[i * 33 + j] = (j < i) ? (-betav[i] * g[jj]) : 0.0f;
            if (j > i) a[jj] = 0.f;
        }
        uint2 p;
        p.x = f2bf(a[0]) | ((unsigned)f2bf(a[1]) << 16);
        p.y = f2bf(a[2]) | ((unsigned)f2bf(a[3]) << 16);
        *(uint2*)(attnb + (size_t)(bh * 64 + ch) * 1024 + i * 32 + j0) = p;
    }
    __syncthreads();

    // forward substitution
    for (int i = 1; i < 32; i++) {
        float s = 0.f;
        bool act = (tid < i);
        if (act) {
            s = Tm[i * 33 + tid];
            for (int j = tid + 1; j < i; j++) s += Tm[i * 33 + j] * Tm[j * 33 + tid];
        }
        __syncthreads();
        if (act) Tm[i * 33 + tid] = s;
        __syncthreads();
    }
    // T2 = (T + I) * diag(beta)
    for (int idx = tid; idx < 1024; idx += 256) {
        int i = idx >> 5, j = idx & 31;
        float val = (j == i) ? 1.0f : Tm[i * 33 + j]; // j>i slots already 0
        Tm[i * 33 + j] = val * betav[j];
    }
    __syncthreads();

    // u = T2 @ v (raw v), wneg = -(T2 @ k_hat)
    {
        const float* vrow0 = vbuf + (size_t)(b * L + t0) * D + h * DK;
        float* ug = u + (size_t)(bh * L + t0 + r) * DK;
        unsigned short* wg = wneg + (size_t)(bh * L + t0 + r) * DK;
        for (int ccb = 0; ccb < 8; ccb++) {
            int c = part * 4 + 32 * ccb;
            float au0 = 0, au1 = 0, au2 = 0, au3 = 0;
            float aw0 = 0, aw1 = 0, aw2 = 0, aw3 = 0;
            for (int j = 0; j < 32; j++) {
                float t2 = Tm[r * 33 + j];
                float4 vj = *(const float4*)(vrow0 + (size_t)j * D + c);
                float4 kj = *(const float4*)&ks[j * 260 + c];
                au0 += t2 * vj.x; au1 += t2 * vj.y; au2 += t2 * vj.z; au3 += t2 * vj.w;
                aw0 += t2 * kj.x; aw1 += t2 * kj.y; aw2 += t2 * kj.z; aw3 += t2 * kj.w;
            }
            float4 uo; uo.x = au0; uo.y = au1; uo.z = au2; uo.w = au3;
            *(float4*)(ug + c) = uo;
            uint2 p;
            p.x = f2bf(-aw0) | ((unsigned)f2bf(-aw1) << 16);
            p.y = f2bf(-aw2) | ((unsigned)f2bf(-aw3) << 16);
            *(uint2*)(wg + c) = p;
        }
    }
    // knT (bh,ch,DK,32) bf16
    {
        int kk = tid;
        unsigned short* kT = knT + ((size_t)(bh * 64 + ch) * DK + kk) * 32;
#pragma unroll
        for (int r2 = 0; r2 < 32; r2 += 2) {
            unsigned pv = f2bf(ks[r2 * 260 + kk]) | ((unsigned)f2bf(ks[(r2 + 1) * 260 + kk]) << 16);
            *(unsigned*)(kT + r2) = pv;
        }
    }
}

// ---------------- K8a: EMA local scan per (bh, time-chunk of ET) ----------------
__global__ __launch_bounds__(256) void k_ema_local(const float* v, const float* gamma,
                                                   float* ema_local, float* Acum,
                                                   float* s_end, float* Pchunk)
{
    __shared__ float gsh[ET];
    int blk = blockIdx.x;             // bh * ENCH + ch
    int bh = blk >> 5;                // ENCH = 32
    int ch = blk & (ENCH - 1);
    int b = bh >> 2, h = bh & 3;
    int c = threadIdx.x;              // channel within head (0..255)
    int t0 = ch * ET;
    if (c < ET) gsh[c] = gamma[(size_t)(b * L + t0 + c) * NH + h];
    __syncthreads();
    const float* vg = v + (size_t)(b * L + t0) * D + h * DK + c;
    float* eg = ema_local + (size_t)(b * L + t0) * D + h * DK + c;
    float* Ag = Acum + (size_t)bh * L + t0;
    float s = 0.f;
    float A = 1.f;
#pragma unroll 8
    for (int i = 0; i < ET; i++) {
        float g = gsh[i];
        s = g * s + (1.f - g) * vg[(size_t)i * D];
        A *= g;
        eg[(size_t)i * D] = s;
        if (c == 0) Ag[i] = A;
    }
    s_end[((size_t)bh * ENCH + ch) * DK + c] = s;
    if (c == 0) Pchunk[(size_t)bh * ENCH + ch] = A;
}

// ---------------- K8b: EMA carry scan over chunks ----------------
__global__ __launch_bounds__(256) void k_ema_carry(const float* s_end, const float* Pchunk, float* S_in)
{
    int bh = blockIdx.x;
    int c = threadIdx.x;
    float S = 0.f;
    for (int ch = 0; ch < ENCH; ch++) {
        S_in[((size_t)bh * ENCH + ch) * DK + c] = S;
        float P = Pchunk[(size_t)bh * ENCH + ch];
        S = P * S + s_end[((size_t)bh * ENCH + ch) * DK + c];
    }
}

// ---------------- K9: sequential inter-chunk scan (MFMA, S in AGPRs) ----------------
__global__ __launch_bounds__(256) void k_scan(const unsigned short* qn, const unsigned short* wneg,
                                              const unsigned short* knT, const unsigned short* attnb,
                                              const float* u, float* od)
{
    __shared__ __align__(16) unsigned short st[32 * 264];   // S^T bf16: [c][kk]
    __shared__ __align__(16) unsigned short uat[32 * 40];   // u_adj^T bf16: [c][r]
    int tile = blockIdx.x;      // dv tile (0..7), 32 cols
    int bh = blockIdx.y;
    int b = bh >> 2, h = bh & 3;
    int wave = threadIdx.x >> 6, lane = threadIdx.x & 63;
    int r16 = lane & 15, quad = lane >> 4;
    int mo = wave & 1, no = wave >> 1;
    int cbase = tile * 32;
    f32x4 z4 = {0.f, 0.f, 0.f, 0.f};
    f32x4 sacc[4][2];
#pragma unroll
    for (int a = 0; a < 4; a++) { sacc[a][0] = z4; sacc[a][1] = z4; }
    const unsigned short* qb = qn + (size_t)bh * L * DK;
    const unsigned short* wb = wneg + (size_t)bh * L * DK;
    const float* ub = u + (size_t)bh * L * DK;

    for (int ch = 0; ch < NCH; ch++) {
        int t0 = ch * 32;
        // (A) refresh S^T bf16 in LDS from fp32 accumulators
#pragma unroll
        for (int a = 0; a < 4; a++) {
            int kkb = (wave * 4 + a) * 16 + quad * 4;
#pragma unroll
            for (int ni = 0; ni < 2; ni++) {
                int c = ni * 16 + r16;
                unsigned p0 = f2bf(sacc[a][ni][0]) | ((unsigned)f2bf(sacc[a][ni][1]) << 16);
                unsigned p1 = f2bf(sacc[a][ni][2]) | ((unsigned)f2bf(sacc[a][ni][3]) << 16);
                *(unsigned*)&st[c * 264 + kkb] = p0;
                *(unsigned*)&st[c * 264 + kkb + 2] = p1;
            }
        }
        __syncthreads();

        // (C) u_adj = u - w@S  and o_partial = q@S
        f32x4 au, ao = z4;
        {
            const float* up = ub + (size_t)(t0 + 16 * mo + quad * 4) * DK + cbase + no * 16 + r16;
            au[0] = up[0]; au[1] = up[DK]; au[2] = up[2 * DK]; au[3] = up[3 * DK];
        }
        const unsigned short* wrow = wb + (size_t)(t0 + 16 * mo + r16) * DK;
        const unsigned short* qrow = qb + (size_t)(t0 + 16 * mo + r16) * DK;
#pragma unroll
        for (int kt = 0; kt < 8; kt++) {
            bf16x8 bf = *(const bf16x8*)&st[(no * 16 + r16) * 264 + kt * 32 + quad * 8];
            bf16x8 wf = *(const bf16x8*)(wrow + kt * 32 + quad * 8);
            bf16x8 qf = *(const bf16x8*)(qrow + kt * 32 + quad * 8);
            au = MFMA16(wf, bf, au);
            ao = MFMA16(qf, bf, ao);
        }
        // (D) write u_adj^T bf16
        {
            int c = no * 16 + r16;
            int rb = 16 * mo + quad * 4;
            *(unsigned*)&uat[c * 40 + rb] = f2bf(au[0]) | ((unsigned)f2bf(au[1]) << 16);
            *(unsigned*)&uat[c * 40 + rb + 2] = f2bf(au[2]) | ((unsigned)f2bf(au[3]) << 16);
        }
        __syncthreads();

        // (F) o = q@S + attn@u_adj ; store ; S += kT @ u_adj
        {
            bf16x8 af = *(const bf16x8*)(attnb + (size_t)(bh * 64 + ch) * 1024 + (16 * mo + r16) * 32 + quad * 8);
            bf16x8 uf = *(const bf16x8*)&uat[(no * 16 + r16) * 40 + quad * 8];
            ao = MFMA16(af, uf, ao);
            float* op = od + (size_t)(b * L + t0 + 16 * mo + quad * 4) * D + h * DK + cbase + no * 16 + r16;
            op[0] = ao[0]; op[D] = ao[1]; op[2 * D] = ao[2]; op[3 * D] = ao[3];

            bf16x8 u0 = *(const bf16x8*)&uat[(r16) * 40 + quad * 8];
            bf16x8 u1 = *(const bf16x8*)&uat[(16 + r16) * 40 + quad * 8];
            const unsigned short* kTb = knT + (size_t)(bh * 64 + ch) * DK * 32;
#pragma unroll
            for (int a = 0; a < 4; a++) {
                bf16x8 kf = *(const bf16x8*)(kTb + (size_t)((wave * 4 + a) * 16 + r16) * 32 + quad * 8);
                sacc[a][0] = MFMA16(kf, u0, sacc[a][0]);
                sacc[a][1] = MFMA16(kf, u1, sacc[a][1]);
            }
        }
    }
}

// ---------------- K10: mix + EMA fix-up + per-head RMS norm -> bf16 ----------------
__global__ __launch_bounds__(256) void k_mixrms(const float* od, const float* ema_local,
                                                const float* Acum, const float* S_in,
                                                const float* mixinp,
                                                const float* mix_bias, const float* rms_w,
                                                unsigned short* onorm)
{
    int row = blockIdx.x;       // b*L + t
    int tid = threadIdx.x;
    int h = tid >> 6, lane = tid & 63;
    int b = row >> 11, t = row & (L - 1);
    int bh = b * NH + h;
    int ch = t >> 6;            // ET = 64
    float m = sigmoidf_(mixinp[(size_t)row * NH + h] + mix_bias[h]);
    int c = tid * 4;
    float A = Acum[(size_t)bh * L + t];
    float4 sin4 = *(const float4*)(S_in + ((size_t)bh * ENCH + ch) * DK + (c & (DK - 1)));
    float4 o = *(const float4*)(od + (size_t)row * D + c);
    float4 e = *(const float4*)(ema_local + (size_t)row * D + c);
    e.x += A * sin4.x; e.y += A * sin4.y; e.z += A * sin4.z; e.w += A * sin4.w;
    float x0 = o.x + m * (e.x - o.x);
    float x1 = o.y + m * (e.y - o.y);
    float x2 = o.z + m * (e.z - o.z);
    float x3 = o.w + m * (e.w - o.w);
    float ss = x0 * x0 + x1 * x1 + x2 * x2 + x3 * x3;
    for (int off = 32; off; off >>= 1) ss += __shfl_xor(ss, off, 64);
    float scale = rsqrtf(ss * (1.0f / 256.0f) + 1e-5f);
    float4 w = *(const float4*)(rms_w + lane * 4);
    uint2 p;
    p.x = f2bf(x0 * scale * w.x) | ((unsigned)f2bf(x1 * scale * w.y) << 16);
    p.y = f2bf(x2 * scale * w.z) | ((unsigned)f2bf(x3 * scale * w.w) << 16);
    *(uint2*)(onorm + (size_t)row * D + c) = p;
}

// ---------------- K11: output GEMM ----------------
__global__ __launch_bounds__(256) void k_gemm_out(const unsigned short* A, const unsigned short* BT, float* out)
{
    int wave = threadIdx.x >> 6, lane = threadIdx.x & 63;
    int wm = wave & 1, wn = wave >> 1;
    int m0 = blockIdx.x * 64 + wm * 32;
    int n0 = blockIdx.y * 64 + wn * 32;
    int r16 = lane & 15, quad = lane >> 4;
    f32x4 z4 = {0.f, 0.f, 0.f, 0.f};
    f32x4 acc[2][2];
    acc[0][0] = z4; acc[0][1] = z4; acc[1][0] = z4; acc[1][1] = z4;
    for (int kt = 0; kt < D; kt += 32) {
        bf16x8 a0 = *(const bf16x8*)(A + (size_t)(m0 + r16) * D + kt + quad * 8);
        bf16x8 a1 = *(const bf16x8*)(A + (size_t)(m0 + 16 + r16) * D + kt + quad * 8);
        bf16x8 b0 = *(const bf16x8*)(BT + (size_t)(n0 + r16) * D + kt + quad * 8);
        bf16x8 b1 = *(const bf16x8*)(BT + (size_t)(n0 + 16 + r16) * D + kt + quad * 8);
        acc[0][0] = MFMA16(a0, b0, acc[0][0]);
        acc[0][1] = MFMA16(a0, b1, acc[0][1]);
        acc[1][0] = MFMA16(a1, b0, acc[1][0]);
        acc[1][1] = MFMA16(a1, b1, acc[1][1]);
    }
#pragma unroll
    for (int ms = 0; ms < 2; ms++)
#pragma unroll
        for (int ns = 0; ns < 2; ns++)
#pragma unroll
            for (int r = 0; r < 4; r++) {
                int m = m0 + ms * 16 + quad * 4 + r;
                int n = n0 + ns * 16 + r16;
                out[(size_t)m * D + n] = acc[ms][ns][r];
            }
}

extern "C" void kernel_launch(void* const* d_in, const int* in_sizes, int n_in,
                              void* d_out, int out_size, void* d_ws, size_t ws_size,
                              hipStream_t stream)
{
    (void)in_sizes; (void)n_in; (void)out_size; (void)ws_size;
    const float* hidden   = (const float*)d_in[0];
    const float* Wq       = (const float*)d_in[1];
    const float* Wk       = (const float*)d_in[2];
    const float* Wv       = (const float*)d_in[3];
    const float* conv_q   = (const float*)d_in[4];
    const float* conv_k   = (const float*)d_in[5];
    const float* conv_v   = (const float*)d_in[6];
    const float* Wb       = (const float*)d_in[7];
    const float* Wdec     = (const float*)d_in[8];
    const float* Wmix     = (const float*)d_in[9];
    const float* conv_mix = (const float*)d_in[10];
    const float* mix_bias = (const float*)d_in[11];
    const float* rms_w    = (const float*)d_in[12];
    const float* Wo       = (const float*)d_in[13];
    float* out = (float*)d_out;

    char* ws = (char*)d_ws;
    size_t off = 0;
    auto alloc = [&](size_t bytes) -> char* {
        char* p = ws + off;
        off += (bytes + 255) & ~(size_t)255;
        return p;
    };
    unsigned short* wT    = (unsigned short*)alloc((size_t)4 * D * D * 2);
    unsigned short* hidB  = (unsigned short*)alloc((size_t)B * L * D * 2);
    unsigned short* xq    = (unsigned short*)alloc((size_t)B * L * D * 2);   // later qn
    unsigned short* xk    = (unsigned short*)alloc((size_t)B * L * D * 2);   // later wneg
    unsigned short* xv    = (unsigned short*)alloc((size_t)B * L * D * 2);   // later knT
    float* beta   = (float*)alloc((size_t)B * L * NH * 4);
    float* gamma  = (float*)alloc((size_t)B * L * NH * 4);
    float* xmix   = (float*)alloc((size_t)B * L * NH * 4);
    float* mixinp = (float*)alloc((size_t)B * L * NH * 4);
    float* qbuf   = (float*)alloc((size_t)B * L * D * 4);   // later ema_local
    float* kbuf   = (float*)alloc((size_t)B * L * D * 4);   // later od
    float* vbuf   = (float*)alloc((size_t)B * L * D * 4);
    float* u      = (float*)alloc((size_t)B * L * D * 4);
    unsigned short* attnb = (unsigned short*)alloc((size_t)BH * NCH * CHUNK * CHUNK * 2);
    unsigned short* onorm = (unsigned short*)alloc((size_t)B * L * D * 2);
    unsigned short* kn    = (unsigned short*)alloc((size_t)B * L * D * 2);
    float* Acum   = (float*)alloc((size_t)BH * L * 4);
    float* s_end  = (float*)alloc((size_t)BH * ENCH * DK * 4);
    float* Pchunk = (float*)alloc((size_t)BH * ENCH * 4);
    float* S_in   = (float*)alloc((size_t)BH * ENCH * DK * 4);

    unsigned short* qn   = xq;
    unsigned short* wneg = xk;
    unsigned short* knT  = xv;
    float* ema_local = qbuf;
    float* od  = kbuf;

    k_wT<<<dim3(32, 32, 4), 256, 0, stream>>>(Wq, Wk, Wv, Wo, wT);
    k_cvt<<<dim3(2048), 256, 0, stream>>>(hidden, hidB, B * L * D / 4);
    k_gemm_qkv<<<dim3(128, 16, 3), 256, 0, stream>>>(hidB, wT, xq, xk, xv);
    k_smallproj<<<dim3(B * L / 4), 256, 0, stream>>>(hidden, Wb, Wdec, Wmix, beta, gamma, xmix);
    k_conv<<<dim3(B * L * D / 256, 1, 3), 256, 0, stream>>>(xq, xk, xv, conv_q, conv_k, conv_v,
                                                            qbuf, kbuf, vbuf);
    k_convmix<<<dim3(B * L * NH / 256), 256, 0, stream>>>(xmix, conv_mix, mixinp);
    k_l2norm<<<dim3(BH * L / 4), 256, 0, stream>>>(qbuf, kbuf, qn, kn);
    k_delta_pre<<<dim3(BH * NCH), 256, 0, stream>>>(qn, kn, vbuf, beta, wneg, knT, attnb, u);
    k_ema_local<<<dim3(BH * ENCH), 256, 0, stream>>>(vbuf, gamma, ema_local, Acum, s_end, Pchunk);
    k_ema_carry<<<dim3(BH), 256, 0, stream>>>(s_end, Pchunk, S_in);
    k_scan<<<dim3(8, 16), 256, 0, stream>>>(qn, wneg, knT, attnb, u, od);
    k_mixrms<<<dim3(B * L), 256, 0, stream>>>(od, ema_local, Acum, S_in, mixinp, mix_bias, rms_w, onorm);
    k_gemm_out<<<dim3(128, 16), 256, 0, stream>>>(onorm, wT + (size_t)3 * D * D, out);
}

// Round 3
// 748.380 us; speedup vs baseline: 2.0979x; 1.4853x over previous
//
#include <hip/hip_runtime.h>
#include <hip/hip_bf16.h>

#define B 4
#define L 2048
#define D 1024
#define NH 4
#define DK 256
#define CHUNK 32
#define NCH 64
#define BH (B*NH)
// EMA chunking
#define ET 64
#define ENCH (L/ET)

typedef __attribute__((ext_vector_type(8))) __bf16 bf16x8;
typedef __attribute__((ext_vector_type(4))) float f32x4;

__device__ inline unsigned short f2bf(float f) {
    union { float f; unsigned u; } v; v.f = f;
    unsigned r = v.u + 0x7fffu + ((v.u >> 16) & 1u);
    return (unsigned short)(r >> 16);
}
__device__ inline float bf2f(unsigned short h) {
    union { unsigned u; float f; } v; v.u = ((unsigned)h) << 16; return v.f;
}
__device__ inline float sigmoidf_(float x) { return 1.0f / (1.0f + __expf(-x)); }
__device__ inline float siluf_(float x) { return x / (1.0f + __expf(-x)); }

#define MFMA16(a, b, c) __builtin_amdgcn_mfma_f32_16x16x32_bf16((a), (b), (c), 0, 0, 0)

// async global->LDS, 16B per lane; lds dest = wave-uniform base + lane*16
__device__ inline void load_lds16(const unsigned short* g, unsigned short* l) {
    __builtin_amdgcn_global_load_lds(
        (const __attribute__((address_space(1))) unsigned int*)g,
        (__attribute__((address_space(3))) unsigned int*)l, 16, 0, 0);
}

// ---------------- K1: transpose+convert weights: W (K,N) f32 -> WT (N,K) bf16 ----------------
__global__ __launch_bounds__(256) void k_wT(const float* Wq, const float* Wk, const float* Wv,
                                            const float* Wo, unsigned short* wT)
{
    __shared__ float tile[32][33];
    int z = blockIdx.z;
    const float* W = (z == 0) ? Wq : (z == 1) ? Wk : (z == 2) ? Wv : Wo;
    unsigned short* out = wT + (size_t)z * D * D;
    int kt = blockIdx.x * 32, nt = blockIdx.y * 32;
    int tx = threadIdx.x & 31, ty = threadIdx.x >> 5;
#pragma unroll
    for (int i = 0; i < 4; i++)
        tile[ty + 8 * i][tx] = W[(size_t)(kt + ty + 8 * i) * D + nt + tx];
    __syncthreads();
#pragma unroll
    for (int i = 0; i < 4; i++)
        out[(size_t)(nt + ty + 8 * i) * D + kt + tx] = f2bf(tile[tx][ty + 8 * i]);
}

// ---------------- K2: hidden f32 -> bf16 ----------------
__global__ __launch_bounds__(256) void k_cvt(const float* h, unsigned short* hb, int n4)
{
    int i = blockIdx.x * blockDim.x + threadIdx.x;
    int stride = gridDim.x * blockDim.x;
    const float4* h4 = (const float4*)h;
    for (; i < n4; i += stride) {
        float4 v = h4[i];
        ushort4 o;
        o.x = f2bf(v.x); o.y = f2bf(v.y); o.z = f2bf(v.z); o.w = f2bf(v.w);
        *(ushort4*)(hb + 4 * (size_t)i) = o;
    }
}

// ---------------- K3: LDS-staged 128x128 GEMM (m97 structure) ----------------
// C[M x NTOT] = A[M x 1024] * BT[NTOT x 1024]^T ; output bf16 or f32
template<int NTOT, bool OUT_F32>
__global__ __launch_bounds__(256) void k_gemm_lds(const unsigned short* __restrict__ A,
                                                  const unsigned short* __restrict__ BT,
                                                  void* __restrict__ outp)
{
    __shared__ __align__(16) unsigned short As[128 * 32];   // 8 KB
    __shared__ __align__(16) unsigned short Bs[128 * 32];   // 8 KB
    const int K = 1024;
    int tid = threadIdx.x;
    int w = tid >> 6, lane = tid & 63;
    int r16 = lane & 15, quad = lane >> 4;
    int wm = w & 1, wn = w >> 1;
    int bm = blockIdx.x * 128;
    int bn = blockIdx.y * 128;
    // staging geometry: per wave 2 issues for A, 2 for B; each issue = 16 rows x 32 cols
    int lrow = lane >> 2;            // 0..15
    int lcol = (lane & 3) * 8;       // element col within 32
    f32x4 z4 = {0.f, 0.f, 0.f, 0.f};
    f32x4 acc[4][4];
#pragma unroll
    for (int i = 0; i < 4; i++)
#pragma unroll
        for (int j = 0; j < 4; j++) acc[i][j] = z4;

    for (int kt = 0; kt < K; kt += 32) {
#pragma unroll
        for (int j = 0; j < 2; j++) {
            int r0 = (w * 2 + j) * 16;
            load_lds16(A + (size_t)(bm + r0 + lrow) * K + kt + lcol, &As[r0 * 32]);
            load_lds16(BT + (size_t)(bn + r0 + lrow) * K + kt + lcol, &Bs[r0 * 32]);
        }
        __syncthreads();
        bf16x8 af[4], bf[4];
#pragma unroll
        for (int ms = 0; ms < 4; ms++)
            af[ms] = *(const bf16x8*)&As[(wm * 64 + ms * 16 + r16) * 32 + quad * 8];
#pragma unroll
        for (int ns = 0; ns < 4; ns++)
            bf[ns] = *(const bf16x8*)&Bs[(wn * 64 + ns * 16 + r16) * 32 + quad * 8];
#pragma unroll
        for (int ms = 0; ms < 4; ms++)
#pragma unroll
            for (int ns = 0; ns < 4; ns++)
                acc[ms][ns] = MFMA16(af[ms], bf[ns], acc[ms][ns]);
        __syncthreads();
    }
#pragma unroll
    for (int ms = 0; ms < 4; ms++)
#pragma unroll
        for (int ns = 0; ns < 4; ns++)
#pragma unroll
            for (int r = 0; r < 4; r++) {
                int m = bm + wm * 64 + ms * 16 + quad * 4 + r;
                int n = bn + wn * 64 + ns * 16 + r16;
                if (OUT_F32)
                    ((float*)outp)[(size_t)m * NTOT + n] = acc[ms][ns][r];
                else
                    ((unsigned short*)outp)[(size_t)m * NTOT + n] = f2bf(acc[ms][ns][r]);
            }
}

// ---------------- K4: small projections: beta/gamma (sigmoid), xmix raw ----------------
__global__ __launch_bounds__(256) void k_smallproj(const float* hid, const float* Wb, const float* Wd,
                                                   const float* Wm, float* beta, float* gamma, float* xmix)
{
    int wave = threadIdx.x >> 6, lane = threadIdx.x & 63;
    int row = blockIdx.x * 4 + wave;
    const float* hrow = hid + (size_t)row * D;
    float acc[12];
#pragma unroll
    for (int j = 0; j < 12; j++) acc[j] = 0.f;
    for (int i = 0; i < 16; i++) {
        int k = lane + 64 * i;
        float h = hrow[k];
        float4 wb = ((const float4*)Wb)[k];
        float4 wd = ((const float4*)Wd)[k];
        float4 wm = ((const float4*)Wm)[k];
        acc[0] += h * wb.x; acc[1] += h * wb.y; acc[2] += h * wb.z; acc[3] += h * wb.w;
        acc[4] += h * wd.x; acc[5] += h * wd.y; acc[6] += h * wd.z; acc[7] += h * wd.w;
        acc[8] += h * wm.x; acc[9] += h * wm.y; acc[10] += h * wm.z; acc[11] += h * wm.w;
    }
#pragma unroll
    for (int j = 0; j < 12; j++)
        for (int off = 32; off; off >>= 1) acc[j] += __shfl_xor(acc[j], off, 64);
    if (lane < 4) {
        beta[(size_t)row * 4 + lane] = sigmoidf_(acc[lane]);
        gamma[(size_t)row * 4 + lane] = sigmoidf_(acc[4 + lane]);
        xmix[(size_t)row * 4 + lane] = acc[8 + lane];
    }
}

// ---------------- K5: short conv + silu (q,k double-silu; v single) ----------------
// reads combined xqkv (row stride 3*D), z selects the D-slice
__global__ __launch_bounds__(256) void k_conv(const unsigned short* xqkv,
                                              const float* cq, const float* ck, const float* cv,
                                              float* q, float* k, float* v)
{
    int z = blockIdx.z;
    const float* cw = (z == 0) ? cq : (z == 1) ? ck : cv;
    float* dst = (z == 0) ? q : (z == 1) ? k : v;
    int idx = blockIdx.x * 256 + threadIdx.x;
    int c = idx & (D - 1);
    int t = (idx >> 10) & (L - 1);
    int b = idx >> 21;
    float4 w4 = *(const float4*)(cw + (size_t)c * 4);
    float wv[4] = {w4.x, w4.y, w4.z, w4.w};
    size_t base = ((size_t)(b * L)) * (3 * D) + z * D + c;
    float acc = 0.f;
#pragma unroll
    for (int kk = 0; kk < 4; kk++) {
        int tt = t - 3 + kk;
        if (tt >= 0) acc += wv[kk] * bf2f(xqkv[base + (size_t)tt * (3 * D)]);
    }
    float r = siluf_(acc);
    if (z < 2) r = siluf_(r);
    dst[idx] = r;
}

// ---------------- K6: mix conv + silu (H channels) ----------------
__global__ __launch_bounds__(256) void k_convmix(const float* xmix, const float* cmix, float* mixinp)
{
    int idx = blockIdx.x * 256 + threadIdx.x;   // < B*L*NH
    int h = idx & 3;
    int t = (idx >> 2) & (L - 1);
    int b = idx >> 13;
    float acc = 0.f;
#pragma unroll
    for (int kk = 0; kk < 4; kk++) {
        int tt = t - 3 + kk;
        if (tt >= 0) acc += cmix[h * 4 + kk] * xmix[((size_t)(b * L + tt) << 2) + h];
    }
    mixinp[idx] = siluf_(acc);
}

// ---------------- K7a: l2norm q,k -> bf16 (bh, L, DK) ----------------
__global__ __launch_bounds__(256) void k_l2norm(const float* qbuf, const float* kbuf,
                                                unsigned short* qn, unsigned short* kn)
{
    int wave = threadIdx.x >> 6, lane = threadIdx.x & 63;
    int rid = blockIdx.x * 4 + wave;      // 0..BH*L-1
    int bh = rid >> 11, t = rid & (L - 1);
    int b = bh >> 2, h = bh & 3;
    size_t src = (size_t)(b * L + t) * D + h * DK + lane * 4;
    float4 q4 = *(const float4*)(qbuf + src);
    float4 k4 = *(const float4*)(kbuf + src);
    float sq = q4.x * q4.x + q4.y * q4.y + q4.z * q4.z + q4.w * q4.w;
    float sk = k4.x * k4.x + k4.y * k4.y + k4.z * k4.z + k4.w * k4.w;
    for (int off = 32; off; off >>= 1) { sq += __shfl_xor(sq, off, 64); sk += __shfl_xor(sk, off, 64); }
    float qsc = rsqrtf(sq + 1e-6f);
    float ksc = rsqrtf(sk + 1e-6f);
    uint2 pq, pk;
    pq.x = f2bf(q4.x * qsc) | ((unsigned)f2bf(q4.y * qsc) << 16);
    pq.y = f2bf(q4.z * qsc) | ((unsigned)f2bf(q4.w * qsc) << 16);
    pk.x = f2bf(k4.x * ksc) | ((unsigned)f2bf(k4.y * ksc) << 16);
    pk.y = f2bf(k4.z * ksc) | ((unsigned)f2bf(k4.w * ksc) << 16);
    *(uint2*)(qn + (size_t)rid * DK + lane * 4) = pq;
    *(uint2*)(kn + (size_t)rid * DK + lane * 4) = pk;
}

// ---------------- K7b: per-(bh,chunk) delta-rule precompute ----------------
__global__ __launch_bounds__(256) void k_delta_pre(const unsigned short* qn, const unsigned short* kn,
                                                   const float* vbuf, const float* beta,
                                                   unsigned short* wneg, unsigned short* knT,
                                                   unsigned short* attnb, float* u)
{
    __shared__ __align__(16) float ks[32 * 260];
    __shared__ float Tm[32 * 33];
    __shared__ float betav[32];
    int bx = blockIdx.x;
    int bh = bx >> 6, ch = bx & 63;
    int b = bh >> 2, h = bh & 3;
    int t0 = ch * 32;
    int tid = threadIdx.x;
    int r = tid >> 3, part = tid & 7;

    // stage normalized k (bf16 -> f32) into LDS
    const unsigned short* knrow = kn + (size_t)(bh * L + t0 + r) * DK;
#pragma unroll
    for (int i = 0; i < 8; i++) {
        int c = (part + 8 * i) * 4;
        ushort4 kv = *(const ushort4*)(knrow + c);
        ks[r * 260 + c + 0] = bf2f(kv.x);
        ks[r * 260 + c + 1] = bf2f(kv.y);
        ks[r * 260 + c + 2] = bf2f(kv.z);
        ks[r * 260 + c + 3] = bf2f(kv.w);
    }
    if (tid < 32) betav[tid] = beta[(size_t)(b * L + t0 + tid) * NH + h];
    __syncthreads();

    // G = k.kT, QK = q.kT; init Tm strict-lower = -beta_i*G; write attnb (tril incl) bf16
    {
        int i = tid >> 3, j0 = (tid & 7) * 4;
        const unsigned short* qrow = qn + (size_t)(bh * L + t0 + i) * DK;
        float g[4] = {0.f, 0.f, 0.f, 0.f};
        float a[4] = {0.f, 0.f, 0.f, 0.f};
        for (int c = 0; c < DK; c += 4) {
            ushort4 qv = *(const ushort4*)(qrow + c);
            float q0 = bf2f(qv.x), q1 = bf2f(qv.y), q2 = bf2f(qv.z), q3 = bf2f(qv.w);
            float4 ki = *(const float4*)&ks[i * 260 + c];
#pragma unroll
            for (int jj = 0; jj < 4; jj++) {
                float4 kj = *(const float4*)&ks[(j0 + jj) * 260 + c];
                g[jj] += ki.x * kj.x + ki.y * kj.y + ki.z * kj.z + ki.w * kj.w;
                a[jj] += q0 * kj.x + q1 * kj.y + q2 * kj.z + q3 * kj.w;
            }
        }
#pragma unroll
        for (int jj = 0; jj < 4; jj++) {
            int j = j0 + jj;
            Tm[i * 33 + j] = (j < i) ? (-betav[i] * g[jj]) : 0.0f;
            if (j > i) a[jj] = 0.f;
        }
        uint2 p;
        p.x = f2bf(a[0]) | ((unsigned)f2bf(a[1]) << 16);
        p.y = f2bf(a[2]) | ((unsigned)f2bf(a[3]) << 16);
        *(uint2*)(attnb + (size_t)(bh * 64 + ch) * 1024 + i * 32 + j0) = p;
    }
    __syncthreads();

    // forward substitution
    for (int i = 1; i < 32; i++) {
        float s = 0.f;
        bool act = (tid < i);
        if (act) {
            s = Tm[i * 33 + tid];
            for (int j = tid + 1; j < i; j++) s += Tm[i * 33 + j] * Tm[j * 33 + tid];
        }
        __syncthreads();
        if (act) Tm[i * 33 + tid] = s;
        __syncthreads();
    }
    // T2 = (T + I) * diag(beta)
    for (int idx = tid; idx < 1024; idx += 256) {
        int i = idx >> 5, j = idx & 31;
        float val = (j == i) ? 1.0f : Tm[i * 33 + j]; // j>i slots already 0
        Tm[i * 33 + j] = val * betav[j];
    }
    __syncthreads();

    // u = T2 @ v (raw v), wneg = -(T2 @ k_hat)
    {
        const float* vrow0 = vbuf + (size_t)(b * L + t0) * D + h * DK;
        float* ug = u + (size_t)(bh * L + t0 + r) * DK;
        unsigned short* wg = wneg + (size_t)(bh * L + t0 + r) * DK;
        for (int ccb = 0; ccb < 8; ccb++) {
            int c = part * 4 + 32 * ccb;
            float au0 = 0, au1 = 0, au2 = 0, au3 = 0;
            float aw0 = 0, aw1 = 0, aw2 = 0, aw3 = 0;
            for (int j = 0; j < 32; j++) {
                float t2 = Tm[r * 33 + j];
                float4 vj = *(const float4*)(vrow0 + (size_t)j * D + c);
                float4 kj = *(const float4*)&ks[j * 260 + c];
                au0 += t2 * vj.x; au1 += t2 * vj.y; au2 += t2 * vj.z; au3 += t2 * vj.w;
                aw0 += t2 * kj.x; aw1 += t2 * kj.y; aw2 += t2 * kj.z; aw3 += t2 * kj.w;
            }
            float4 uo; uo.x = au0; uo.y = au1; uo.z = au2; uo.w = au3;
            *(float4*)(ug + c) = uo;
            uint2 p;
            p.x = f2bf(-aw0) | ((unsigned)f2bf(-aw1) << 16);
            p.y = f2bf(-aw2) | ((unsigned)f2bf(-aw3) << 16);
            *(uint2*)(wg + c) = p;
        }
    }
    // knT (bh,ch,DK,32) bf16
    {
        int kk = tid;
        unsigned short* kT = knT + ((size_t)(bh * 64 + ch) * DK + kk) * 32;
#pragma unroll
        for (int r2 = 0; r2 < 32; r2 += 2) {
            unsigned pv = f2bf(ks[r2 * 260 + kk]) | ((unsigned)f2bf(ks[(r2 + 1) * 260 + kk]) << 16);
            *(unsigned*)(kT + r2) = pv;
        }
    }
}

// ---------------- K8a: EMA local scan per (bh, time-chunk of ET) ----------------
__global__ __launch_bounds__(256) void k_ema_local(const float* v, const float* gamma,
                                                   float* ema_local, float* Acum,
                                                   float* s_end, float* Pchunk)
{
    __shared__ float gsh[ET];
    int blk = blockIdx.x;             // bh * ENCH + ch
    int bh = blk >> 5;                // ENCH = 32
    int ch = blk & (ENCH - 1);
    int b = bh >> 2, h = bh & 3;
    int c = threadIdx.x;              // channel within head (0..255)
    int t0 = ch * ET;
    if (c < ET) gsh[c] = gamma[(size_t)(b * L + t0 + c) * NH + h];
    __syncthreads();
    const float* vg = v + (size_t)(b * L + t0) * D + h * DK + c;
    float* eg = ema_local + (size_t)(b * L + t0) * D + h * DK + c;
    float* Ag = Acum + (size_t)bh * L + t0;
    float s = 0.f;
    float A = 1.f;
#pragma unroll 8
    for (int i = 0; i < ET; i++) {
        float g = gsh[i];
        s = g * s + (1.f - g) * vg[(size_t)i * D];
        A *= g;
        eg[(size_t)i * D] = s;
        if (c == 0) Ag[i] = A;
    }
    s_end[((size_t)bh * ENCH + ch) * DK + c] = s;
    if (c == 0) Pchunk[(size_t)bh * ENCH + ch] = A;
}

// ---------------- K8b: EMA carry scan over chunks ----------------
__global__ __launch_bounds__(256) void k_ema_carry(const float* s_end, const float* Pchunk, float* S_in)
{
    int bh = blockIdx.x;
    int c = threadIdx.x;
    float S = 0.f;
    for (int ch = 0; ch < ENCH; ch++) {
        S_in[((size_t)bh * ENCH + ch) * DK + c] = S;
        float P = Pchunk[(size_t)bh * ENCH + ch];
        S = P * S + s_end[((size_t)bh * ENCH + ch) * DK + c];
    }
}

// ---------------- K9: sequential inter-chunk scan (MFMA, S in AGPRs) ----------------
__global__ __launch_bounds__(256) void k_scan(const unsigned short* qn, const unsigned short* wneg,
                                              const unsigned short* knT, const unsigned short* attnb,
                                              const float* u, float* od)
{
    __shared__ __align__(16) unsigned short st[32 * 264];   // S^T bf16: [c][kk]
    __shared__ __align__(16) unsigned short uat[32 * 40];   // u_adj^T bf16: [c][r]
    int tile = blockIdx.x;      // dv tile (0..7), 32 cols
    int bh = blockIdx.y;
    int b = bh >> 2, h = bh & 3;
    int wave = threadIdx.x >> 6, lane = threadIdx.x & 63;
    int r16 = lane & 15, quad = lane >> 4;
    int mo = wave & 1, no = wave >> 1;
    int cbase = tile * 32;
    f32x4 z4 = {0.f, 0.f, 0.f, 0.f};
    f32x4 sacc[4][2];
#pragma unroll
    for (int a = 0; a < 4; a++) { sacc[a][0] = z4; sacc[a][1] = z4; }
    const unsigned short* qb = qn + (size_t)bh * L * DK;
    const unsigned short* wb = wneg + (size_t)bh * L * DK;
    const float* ub = u + (size_t)bh * L * DK;

    for (int ch = 0; ch < NCH; ch++) {
        int t0 = ch * 32;
        // (A) refresh S^T bf16 in LDS from fp32 accumulators
#pragma unroll
        for (int a = 0; a < 4; a++) {
            int kkb = (wave * 4 + a) * 16 + quad * 4;
#pragma unroll
            for (int ni = 0; ni < 2; ni++) {
                int c = ni * 16 + r16;
                unsigned p0 = f2bf(sacc[a][ni][0]) | ((unsigned)f2bf(sacc[a][ni][1]) << 16);
                unsigned p1 = f2bf(sacc[a][ni][2]) | ((unsigned)f2bf(sacc[a][ni][3]) << 16);
                *(unsigned*)&st[c * 264 + kkb] = p0;
                *(unsigned*)&st[c * 264 + kkb + 2] = p1;
            }
        }
        __syncthreads();

        // (C) u_adj = u - w@S  and o_partial = q@S
        f32x4 au, ao = z4;
        {
            const float* up = ub + (size_t)(t0 + 16 * mo + quad * 4) * DK + cbase + no * 16 + r16;
            au[0] = up[0]; au[1] = up[DK]; au[2] = up[2 * DK]; au[3] = up[3 * DK];
        }
        const unsigned short* wrow = wb + (size_t)(t0 + 16 * mo + r16) * DK;
        const unsigned short* qrow = qb + (size_t)(t0 + 16 * mo + r16) * DK;
#pragma unroll
        for (int kt = 0; kt < 8; kt++) {
            bf16x8 bf = *(const bf16x8*)&st[(no * 16 + r16) * 264 + kt * 32 + quad * 8];
            bf16x8 wf = *(const bf16x8*)(wrow + kt * 32 + quad * 8);
            bf16x8 qf = *(const bf16x8*)(qrow + kt * 32 + quad * 8);
            au = MFMA16(wf, bf, au);
            ao = MFMA16(qf, bf, ao);
        }
        // (D) write u_adj^T bf16
        {
            int c = no * 16 + r16;
            int rb = 16 * mo + quad * 4;
            *(unsigned*)&uat[c * 40 + rb] = f2bf(au[0]) | ((unsigned)f2bf(au[1]) << 16);
            *(unsigned*)&uat[c * 40 + rb + 2] = f2bf(au[2]) | ((unsigned)f2bf(au[3]) << 16);
        }
        __syncthreads();

        // (F) o = q@S + attn@u_adj ; store ; S += kT @ u_adj
        {
            bf16x8 af = *(const bf16x8*)(attnb + (size_t)(bh * 64 + ch) * 1024 + (16 * mo + r16) * 32 + quad * 8);
            bf16x8 uf = *(const bf16x8*)&uat[(no * 16 + r16) * 40 + quad * 8];
            ao = MFMA16(af, uf, ao);
            float* op = od + (size_t)(b * L + t0 + 16 * mo + quad * 4) * D + h * DK + cbase + no * 16 + r16;
            op[0] = ao[0]; op[D] = ao[1]; op[2 * D] = ao[2]; op[3 * D] = ao[3];

            bf16x8 u0 = *(const bf16x8*)&uat[(r16) * 40 + quad * 8];
            bf16x8 u1 = *(const bf16x8*)&uat[(16 + r16) * 40 + quad * 8];
            const unsigned short* kTb = knT + (size_t)(bh * 64 + ch) * DK * 32;
#pragma unroll
            for (int a = 0; a < 4; a++) {
                bf16x8 kf = *(const bf16x8*)(kTb + (size_t)((wave * 4 + a) * 16 + r16) * 32 + quad * 8);
                sacc[a][0] = MFMA16(kf, u0, sacc[a][0]);
                sacc[a][1] = MFMA16(kf, u1, sacc[a][1]);
            }
        }
    }
}

// ---------------- K10: mix + EMA fix-up + per-head RMS norm -> bf16 ----------------
__global__ __launch_bounds__(256) void k_mixrms(const float* od, const float* ema_local,
                                                const float* Acum, const float* S_in,
                                                const float* mixinp,
                                                const float* mix_bias, const float* rms_w,
                                                unsigned short* onorm)
{
    int row = blockIdx.x;       // b*L + t
    int tid = threadIdx.x;
    int h = tid >> 6, lane = tid & 63;
    int b = row >> 11, t = row & (L - 1);
    int bh = b * NH + h;
    int ch = t >> 6;            // ET = 64
    float m = sigmoidf_(mixinp[(size_t)row * NH + h] + mix_bias[h]);
    int c = tid * 4;
    float A = Acum[(size_t)bh * L + t];
    float4 sin4 = *(const float4*)(S_in + ((size_t)bh * ENCH + ch) * DK + (c & (DK - 1)));
    float4 o = *(const float4*)(od + (size_t)row * D + c);
    float4 e = *(const float4*)(ema_local + (size_t)row * D + c);
    e.x += A * sin4.x; e.y += A * sin4.y; e.z += A * sin4.z; e.w += A * sin4.w;
    float x0 = o.x + m * (e.x - o.x);
    float x1 = o.y + m * (e.y - o.y);
    float x2 = o.z + m * (e.z - o.z);
    float x3 = o.w + m * (e.w - o.w);
    float ss = x0 * x0 + x1 * x1 + x2 * x2 + x3 * x3;
    for (int off = 32; off; off >>= 1) ss += __shfl_xor(ss, off, 64);
    float scale = rsqrtf(ss * (1.0f / 256.0f) + 1e-5f);
    float4 w = *(const float4*)(rms_w + lane * 4);
    uint2 p;
    p.x = f2bf(x0 * scale * w.x) | ((unsigned)f2bf(x1 * scale * w.y) << 16);
    p.y = f2bf(x2 * scale * w.z) | ((unsigned)f2bf(x3 * scale * w.w) << 16);
    *(uint2*)(onorm + (size_t)row * D + c) = p;
}

extern "C" void kernel_launch(void* const* d_in, const int* in_sizes, int n_in,
                              void* d_out, int out_size, void* d_ws, size_t ws_size,
                              hipStream_t stream)
{
    (void)in_sizes; (void)n_in; (void)out_size; (void)ws_size;
    const float* hidden   = (const float*)d_in[0];
    const float* Wq       = (const float*)d_in[1];
    const float* Wk       = (const float*)d_in[2];
    const float* Wv       = (const float*)d_in[3];
    const float* conv_q   = (const float*)d_in[4];
    const float* conv_k   = (const float*)d_in[5];
    const float* conv_v   = (const float*)d_in[6];
    const float* Wb       = (const float*)d_in[7];
    const float* Wdec     = (const float*)d_in[8];
    const float* Wmix     = (const float*)d_in[9];
    const float* conv_mix = (const float*)d_in[10];
    const float* mix_bias = (const float*)d_in[11];
    const float* rms_w    = (const float*)d_in[12];
    const float* Wo       = (const float*)d_in[13];
    float* out = (float*)d_out;

    char* ws = (char*)d_ws;
    size_t off = 0;
    auto alloc = [&](size_t bytes) -> char* {
        char* p = ws + off;
        off += (bytes + 255) & ~(size_t)255;
        return p;
    };
    unsigned short* wT    = (unsigned short*)alloc((size_t)4 * D * D * 2);
    unsigned short* hidB  = (unsigned short*)alloc((size_t)B * L * D * 2);
    unsigned short* xqkv  = (unsigned short*)alloc((size_t)B * L * 3 * D * 2); // later qn/wneg/knT
    float* beta   = (float*)alloc((size_t)B * L * NH * 4);
    float* gamma  = (float*)alloc((size_t)B * L * NH * 4);
    float* xmix   = (float*)alloc((size_t)B * L * NH * 4);
    float* mixinp = (float*)alloc((size_t)B * L * NH * 4);
    float* qbuf   = (float*)alloc((size_t)B * L * D * 4);   // later ema_local
    float* kbuf   = (float*)alloc((size_t)B * L * D * 4);   // later od
    float* vbuf   = (float*)alloc((size_t)B * L * D * 4);
    float* u      = (float*)alloc((size_t)B * L * D * 4);
    unsigned short* attnb = (unsigned short*)alloc((size_t)BH * NCH * CHUNK * CHUNK * 2);
    unsigned short* onorm = (unsigned short*)alloc((size_t)B * L * D * 2);
    unsigned short* kn    = (unsigned short*)alloc((size_t)B * L * D * 2);
    float* Acum   = (float*)alloc((size_t)BH * L * 4);
    float* s_end  = (float*)alloc((size_t)BH * ENCH * DK * 4);
    float* Pchunk = (float*)alloc((size_t)BH * ENCH * 4);
    float* S_in   = (float*)alloc((size_t)BH * ENCH * DK * 4);

    unsigned short* qn   = xqkv;
    unsigned short* wneg = xqkv + (size_t)B * L * D;
    unsigned short* knT  = xqkv + (size_t)2 * B * L * D;
    float* ema_local = qbuf;
    float* od  = kbuf;

    k_wT<<<dim3(32, 32, 4), 256, 0, stream>>>(Wq, Wk, Wv, Wo, wT);
    k_cvt<<<dim3(2048), 256, 0, stream>>>(hidden, hidB, B * L * D / 4);
    // fused QKV GEMM: M=8192, N=3072 (Wq^T|Wk^T|Wv^T contiguous in wT)
    k_gemm_lds<3 * D, false><<<dim3(64, 24), 256, 0, stream>>>(hidB, wT, xqkv);
    k_smallproj<<<dim3(B * L / 4), 256, 0, stream>>>(hidden, Wb, Wdec, Wmix, beta, gamma, xmix);
    k_conv<<<dim3(B * L * D / 256, 1, 3), 256, 0, stream>>>(xqkv, conv_q, conv_k, conv_v,
                                                            qbuf, kbuf, vbuf);
    k_convmix<<<dim3(B * L * NH / 256), 256, 0, stream>>>(xmix, conv_mix, mixinp);
    k_l2norm<<<dim3(BH * L / 4), 256, 0, stream>>>(qbuf, kbuf, qn, kn);
    k_delta_pre<<<dim3(BH * NCH), 256, 0, stream>>>(qn, kn, vbuf, beta, wneg, knT, attnb, u);
    k_ema_local<<<dim3(BH * ENCH), 256, 0, stream>>>(vbuf, gamma, ema_local, Acum, s_end, Pchunk);
    k_ema_carry<<<dim3(BH), 256, 0, stream>>>(s_end, Pchunk, S_in);
    k_scan<<<dim3(8, 16), 256, 0, stream>>>(qn, wneg, knT, attnb, u, od);
    k_mixrms<<<dim3(B * L), 256, 0, stream>>>(od, ema_local, Acum, S_in, mixinp, mix_bias, rms_w, onorm);
    k_gemm_lds<D, true><<<dim3(64, 8), 256, 0, stream>>>(onorm, wT + (size_t)3 * D * D, out);
}

// Round 4
// 630.120 us; speedup vs baseline: 2.4916x; 1.1877x over previous
//
#include <hip/hip_runtime.h>
#include <hip/hip_bf16.h>

#define B 4
#define L 2048
#define D 1024
#define NH 4
#define DK 256
#define CHUNK 32
#define NCH 64
#define BH (B*NH)
// EMA chunking
#define ET 64
#define ENCH (L/ET)

typedef __attribute__((ext_vector_type(8))) __bf16 bf16x8;
typedef __attribute__((ext_vector_type(4))) __bf16 bf16x4;
typedef __attribute__((ext_vector_type(4))) float f32x4;

__device__ inline unsigned short f2bf(float f) {
    union { float f; unsigned u; } v; v.f = f;
    unsigned r = v.u + 0x7fffu + ((v.u >> 16) & 1u);
    return (unsigned short)(r >> 16);
}
__device__ inline float bf2f(unsigned short h) {
    union { unsigned u; float f; } v; v.u = ((unsigned)h) << 16; return v.f;
}
__device__ inline float sigmoidf_(float x) { return 1.0f / (1.0f + __expf(-x)); }
__device__ inline float siluf_(float x) { return x / (1.0f + __expf(-x)); }

#define MFMA16(a, b, c) __builtin_amdgcn_mfma_f32_16x16x32_bf16((a), (b), (c), 0, 0, 0)

// async global->LDS, 16B per lane; lds dest = wave-uniform base + lane*16
__device__ inline void load_lds16(const unsigned short* g, unsigned short* l) {
    __builtin_amdgcn_global_load_lds(
        (const __attribute__((address_space(1))) unsigned int*)g,
        (__attribute__((address_space(3))) unsigned int*)l, 16, 0, 0);
}

// ---------------- K1: transpose+convert weights: W (K,N) f32 -> WT (N,K) bf16 ----------------
__global__ __launch_bounds__(256) void k_wT(const float* Wq, const float* Wk, const float* Wv,
                                            const float* Wo, unsigned short* wT)
{
    __shared__ float tile[32][33];
    int z = blockIdx.z;
    const float* W = (z == 0) ? Wq : (z == 1) ? Wk : (z == 2) ? Wv : Wo;
    unsigned short* out = wT + (size_t)z * D * D;
    int kt = blockIdx.x * 32, nt = blockIdx.y * 32;
    int tx = threadIdx.x & 31, ty = threadIdx.x >> 5;
#pragma unroll
    for (int i = 0; i < 4; i++)
        tile[ty + 8 * i][tx] = W[(size_t)(kt + ty + 8 * i) * D + nt + tx];
    __syncthreads();
#pragma unroll
    for (int i = 0; i < 4; i++)
        out[(size_t)(nt + ty + 8 * i) * D + kt + tx] = f2bf(tile[tx][ty + 8 * i]);
}

// ---------------- K2: hidden f32 -> bf16 ----------------
__global__ __launch_bounds__(256) void k_cvt(const float* h, unsigned short* hb, int n4)
{
    int i = blockIdx.x * blockDim.x + threadIdx.x;
    int stride = gridDim.x * blockDim.x;
    const float4* h4 = (const float4*)h;
    for (; i < n4; i += stride) {
        float4 v = h4[i];
        ushort4 o;
        o.x = f2bf(v.x); o.y = f2bf(v.y); o.z = f2bf(v.z); o.w = f2bf(v.w);
        *(ushort4*)(hb + 4 * (size_t)i) = o;
    }
}

// ---------------- K3: LDS-staged 128x128 GEMM (m97 structure) ----------------
template<int NTOT, bool OUT_F32>
__global__ __launch_bounds__(256) void k_gemm_lds(const unsigned short* __restrict__ A,
                                                  const unsigned short* __restrict__ BT,
                                                  void* __restrict__ outp)
{
    __shared__ __align__(16) unsigned short As[128 * 32];   // 8 KB
    __shared__ __align__(16) unsigned short Bs[128 * 32];   // 8 KB
    const int K = 1024;
    int tid = threadIdx.x;
    int w = tid >> 6, lane = tid & 63;
    int r16 = lane & 15, quad = lane >> 4;
    int wm = w & 1, wn = w >> 1;
    int bm = blockIdx.x * 128;
    int bn = blockIdx.y * 128;
    int lrow = lane >> 2;            // 0..15
    int lcol = (lane & 3) * 8;       // element col within 32
    f32x4 z4 = {0.f, 0.f, 0.f, 0.f};
    f32x4 acc[4][4];
#pragma unroll
    for (int i = 0; i < 4; i++)
#pragma unroll
        for (int j = 0; j < 4; j++) acc[i][j] = z4;

    for (int kt = 0; kt < K; kt += 32) {
#pragma unroll
        for (int j = 0; j < 2; j++) {
            int r0 = (w * 2 + j) * 16;
            load_lds16(A + (size_t)(bm + r0 + lrow) * K + kt + lcol, &As[r0 * 32]);
            load_lds16(BT + (size_t)(bn + r0 + lrow) * K + kt + lcol, &Bs[r0 * 32]);
        }
        __syncthreads();
        bf16x8 af[4], bf[4];
#pragma unroll
        for (int ms = 0; ms < 4; ms++)
            af[ms] = *(const bf16x8*)&As[(wm * 64 + ms * 16 + r16) * 32 + quad * 8];
#pragma unroll
        for (int ns = 0; ns < 4; ns++)
            bf[ns] = *(const bf16x8*)&Bs[(wn * 64 + ns * 16 + r16) * 32 + quad * 8];
#pragma unroll
        for (int ms = 0; ms < 4; ms++)
#pragma unroll
            for (int ns = 0; ns < 4; ns++)
                acc[ms][ns] = MFMA16(af[ms], bf[ns], acc[ms][ns]);
        __syncthreads();
    }
#pragma unroll
    for (int ms = 0; ms < 4; ms++)
#pragma unroll
        for (int ns = 0; ns < 4; ns++)
#pragma unroll
            for (int r = 0; r < 4; r++) {
                int m = bm + wm * 64 + ms * 16 + quad * 4 + r;
                int n = bn + wn * 64 + ns * 16 + r16;
                if (OUT_F32)
                    ((float*)outp)[(size_t)m * NTOT + n] = acc[ms][ns][r];
                else
                    ((unsigned short*)outp)[(size_t)m * NTOT + n] = f2bf(acc[ms][ns][r]);
            }
}

// ---------------- K4: small projections ----------------
__global__ __launch_bounds__(256) void k_smallproj(const float* hid, const float* Wb, const float* Wd,
                                                   const float* Wm, float* beta, float* gamma, float* xmix)
{
    int wave = threadIdx.x >> 6, lane = threadIdx.x & 63;
    int row = blockIdx.x * 4 + wave;
    const float* hrow = hid + (size_t)row * D;
    float acc[12];
#pragma unroll
    for (int j = 0; j < 12; j++) acc[j] = 0.f;
    for (int i = 0; i < 16; i++) {
        int k = lane + 64 * i;
        float h = hrow[k];
        float4 wb = ((const float4*)Wb)[k];
        float4 wd = ((const float4*)Wd)[k];
        float4 wm = ((const float4*)Wm)[k];
        acc[0] += h * wb.x; acc[1] += h * wb.y; acc[2] += h * wb.z; acc[3] += h * wb.w;
        acc[4] += h * wd.x; acc[5] += h * wd.y; acc[6] += h * wd.z; acc[7] += h * wd.w;
        acc[8] += h * wm.x; acc[9] += h * wm.y; acc[10] += h * wm.z; acc[11] += h * wm.w;
    }
#pragma unroll
    for (int j = 0; j < 12; j++)
        for (int off = 32; off; off >>= 1) acc[j] += __shfl_xor(acc[j], off, 64);
    if (lane < 4) {
        beta[(size_t)row * 4 + lane] = sigmoidf_(acc[lane]);
        gamma[(size_t)row * 4 + lane] = sigmoidf_(acc[4 + lane]);
        xmix[(size_t)row * 4 + lane] = acc[8 + lane];
    }
}

// ---------------- K5: short conv + silu ----------------
__global__ __launch_bounds__(256) void k_conv(const unsigned short* xqkv,
                                              const float* cq, const float* ck, const float* cv,
                                              float* q, float* k, float* v)
{
    int z = blockIdx.z;
    const float* cw = (z == 0) ? cq : (z == 1) ? ck : cv;
    float* dst = (z == 0) ? q : (z == 1) ? k : v;
    int idx = blockIdx.x * 256 + threadIdx.x;
    int c = idx & (D - 1);
    int t = (idx >> 10) & (L - 1);
    int b = idx >> 21;
    float4 w4 = *(const float4*)(cw + (size_t)c * 4);
    float wv[4] = {w4.x, w4.y, w4.z, w4.w};
    size_t base = ((size_t)(b * L)) * (3 * D) + z * D + c;
    float acc = 0.f;
#pragma unroll
    for (int kk = 0; kk < 4; kk++) {
        int tt = t - 3 + kk;
        if (tt >= 0) acc += wv[kk] * bf2f(xqkv[base + (size_t)tt * (3 * D)]);
    }
    float r = siluf_(acc);
    if (z < 2) r = siluf_(r);
    dst[idx] = r;
}

// ---------------- K6: mix conv + silu ----------------
__global__ __launch_bounds__(256) void k_convmix(const float* xmix, const float* cmix, float* mixinp)
{
    int idx = blockIdx.x * 256 + threadIdx.x;   // < B*L*NH
    int h = idx & 3;
    int t = (idx >> 2) & (L - 1);
    int b = idx >> 13;
    float acc = 0.f;
#pragma unroll
    for (int kk = 0; kk < 4; kk++) {
        int tt = t - 3 + kk;
        if (tt >= 0) acc += cmix[h * 4 + kk] * xmix[((size_t)(b * L + tt) << 2) + h];
    }
    mixinp[idx] = siluf_(acc);
}

// ---------------- K7a: l2norm q,k -> bf16 ----------------
__global__ __launch_bounds__(256) void k_l2norm(const float* qbuf, const float* kbuf,
                                                unsigned short* qn, unsigned short* kn)
{
    int wave = threadIdx.x >> 6, lane = threadIdx.x & 63;
    int rid = blockIdx.x * 4 + wave;      // 0..BH*L-1
    int bh = rid >> 11, t = rid & (L - 1);
    int b = bh >> 2, h = bh & 3;
    size_t src = (size_t)(b * L + t) * D + h * DK + lane * 4;
    float4 q4 = *(const float4*)(qbuf + src);
    float4 k4 = *(const float4*)(kbuf + src);
    float sq = q4.x * q4.x + q4.y * q4.y + q4.z * q4.z + q4.w * q4.w;
    float sk = k4.x * k4.x + k4.y * k4.y + k4.z * k4.z + k4.w * k4.w;
    for (int off = 32; off; off >>= 1) { sq += __shfl_xor(sq, off, 64); sk += __shfl_xor(sk, off, 64); }
    float qsc = rsqrtf(sq + 1e-6f);
    float ksc = rsqrtf(sk + 1e-6f);
    uint2 pq, pk;
    pq.x = f2bf(q4.x * qsc) | ((unsigned)f2bf(q4.y * qsc) << 16);
    pq.y = f2bf(q4.z * qsc) | ((unsigned)f2bf(q4.w * qsc) << 16);
    pk.x = f2bf(k4.x * ksc) | ((unsigned)f2bf(k4.y * ksc) << 16);
    pk.y = f2bf(k4.z * ksc) | ((unsigned)f2bf(k4.w * ksc) << 16);
    *(uint2*)(qn + (size_t)rid * DK + lane * 4) = pq;
    *(uint2*)(kn + (size_t)rid * DK + lane * 4) = pk;
}

// ---------------- K7b: per-(bh,chunk) delta-rule precompute ----------------
__global__ __launch_bounds__(256) void k_delta_pre(const unsigned short* qn, const unsigned short* kn,
                                                   const float* vbuf, const float* beta,
                                                   unsigned short* wneg, unsigned short* knT,
                                                   unsigned short* attnb, float* u)
{
    __shared__ __align__(16) float ks[32 * 260];
    __shared__ float Tm[32 * 33];
    __shared__ float betav[32];
    int bx = blockIdx.x;
    int bh = bx >> 6, ch = bx & 63;
    int b = bh >> 2, h = bh & 3;
    int t0 = ch * 32;
    int tid = threadIdx.x;
    int r = tid >> 3, part = tid & 7;

    const unsigned short* knrow = kn + (size_t)(bh * L + t0 + r) * DK;
#pragma unroll
    for (int i = 0; i < 8; i++) {
        int c = (part + 8 * i) * 4;
        ushort4 kv = *(const ushort4*)(knrow + c);
        ks[r * 260 + c + 0] = bf2f(kv.x);
        ks[r * 260 + c + 1] = bf2f(kv.y);
        ks[r * 260 + c + 2] = bf2f(kv.z);
        ks[r * 260 + c + 3] = bf2f(kv.w);
    }
    if (tid < 32) betav[tid] = beta[(size_t)(b * L + t0 + tid) * NH + h];
    __syncthreads();

    {
        int i = tid >> 3, j0 = (tid & 7) * 4;
        const unsigned short* qrow = qn + (size_t)(bh * L + t0 + i) * DK;
        float g[4] = {0.f, 0.f, 0.f, 0.f};
        float a[4] = {0.f, 0.f, 0.f, 0.f};
        for (int c = 0; c < DK; c += 4) {
            ushort4 qv = *(const ushort4*)(qrow + c);
            float q0 = bf2f(qv.x), q1 = bf2f(qv.y), q2 = bf2f(qv.z), q3 = bf2f(qv.w);
            float4 ki = *(const float4*)&ks[i * 260 + c];
#pragma unroll
            for (int jj = 0; jj < 4; jj++) {
                float4 kj = *(const float4*)&ks[(j0 + jj) * 260 + c];
                g[jj] += ki.x * kj.x + ki.y * kj.y + ki.z * kj.z + ki.w * kj.w;
                a[jj] += q0 * kj.x + q1 * kj.y + q2 * kj.z + q3 * kj.w;
            }
        }
#pragma unroll
        for (int jj = 0; jj < 4; jj++) {
            int j = j0 + jj;
            Tm[i * 33 + j] = (j < i) ? (-betav[i] * g[jj]) : 0.0f;
            if (j > i) a[jj] = 0.f;
        }
        uint2 p;
        p.x = f2bf(a[0]) | ((unsigned)f2bf(a[1]) << 16);
        p.y = f2bf(a[2]) | ((unsigned)f2bf(a[3]) << 16);
        *(uint2*)(attnb + (size_t)(bh * 64 + ch) * 1024 + i * 32 + j0) = p;
    }
    __syncthreads();

    for (int i = 1; i < 32; i++) {
        float s = 0.f;
        bool act = (tid < i);
        if (act) {
            s = Tm[i * 33 + tid];
            for (int j = tid + 1; j < i; j++) s += Tm[i * 33 + j] * Tm[j * 33 + tid];
        }
        __syncthreads();
        if (act) Tm[i * 33 + tid] = s;
        __syncthreads();
    }
    for (int idx = tid; idx < 1024; idx += 256) {
        int i = idx >> 5, j = idx & 31;
        float val = (j == i) ? 1.0f : Tm[i * 33 + j];
        Tm[i * 33 + j] = val * betav[j];
    }
    __syncthreads();

    {
        const float* vrow0 = vbuf + (size_t)(b * L + t0) * D + h * DK;
        float* ug = u + (size_t)(bh * L + t0 + r) * DK;
        unsigned short* wg = wneg + (size_t)(bh * L + t0 + r) * DK;
        for (int ccb = 0; ccb < 8; ccb++) {
            int c = part * 4 + 32 * ccb;
            float au0 = 0, au1 = 0, au2 = 0, au3 = 0;
            float aw0 = 0, aw1 = 0, aw2 = 0, aw3 = 0;
            for (int j = 0; j < 32; j++) {
                float t2 = Tm[r * 33 + j];
                float4 vj = *(const float4*)(vrow0 + (size_t)j * D + c);
                float4 kj = *(const float4*)&ks[j * 260 + c];
                au0 += t2 * vj.x; au1 += t2 * vj.y; au2 += t2 * vj.z; au3 += t2 * vj.w;
                aw0 += t2 * kj.x; aw1 += t2 * kj.y; aw2 += t2 * kj.z; aw3 += t2 * kj.w;
            }
            float4 uo; uo.x = au0; uo.y = au1; uo.z = au2; uo.w = au3;
            *(float4*)(ug + c) = uo;
            uint2 p;
            p.x = f2bf(-aw0) | ((unsigned)f2bf(-aw1) << 16);
            p.y = f2bf(-aw2) | ((unsigned)f2bf(-aw3) << 16);
            *(uint2*)(wg + c) = p;
        }
    }
    {
        int kk = tid;
        unsigned short* kT = knT + ((size_t)(bh * 64 + ch) * DK + kk) * 32;
#pragma unroll
        for (int r2 = 0; r2 < 32; r2 += 2) {
            unsigned pv = f2bf(ks[r2 * 260 + kk]) | ((unsigned)f2bf(ks[(r2 + 1) * 260 + kk]) << 16);
            *(unsigned*)(kT + r2) = pv;
        }
    }
}

// ---------------- K8a: EMA local scan ----------------
__global__ __launch_bounds__(256) void k_ema_local(const float* v, const float* gamma,
                                                   float* ema_local, float* Acum,
                                                   float* s_end, float* Pchunk)
{
    __shared__ float gsh[ET];
    int blk = blockIdx.x;
    int bh = blk >> 5;
    int ch = blk & (ENCH - 1);
    int b = bh >> 2, h = bh & 3;
    int c = threadIdx.x;
    int t0 = ch * ET;
    if (c < ET) gsh[c] = gamma[(size_t)(b * L + t0 + c) * NH + h];
    __syncthreads();
    const float* vg = v + (size_t)(b * L + t0) * D + h * DK + c;
    float* eg = ema_local + (size_t)(b * L + t0) * D + h * DK + c;
    float* Ag = Acum + (size_t)bh * L + t0;
    float s = 0.f;
    float A = 1.f;
#pragma unroll 8
    for (int i = 0; i < ET; i++) {
        float g = gsh[i];
        s = g * s + (1.f - g) * vg[(size_t)i * D];
        A *= g;
        eg[(size_t)i * D] = s;
        if (c == 0) Ag[i] = A;
    }
    s_end[((size_t)bh * ENCH + ch) * DK + c] = s;
    if (c == 0) Pchunk[(size_t)bh * ENCH + ch] = A;
}

// ---------------- K8b: EMA carry scan ----------------
__global__ __launch_bounds__(256) void k_ema_carry(const float* s_end, const float* Pchunk, float* S_in)
{
    int bh = blockIdx.x;
    int c = threadIdx.x;
    float S = 0.f;
    for (int ch = 0; ch < ENCH; ch++) {
        S_in[((size_t)bh * ENCH + ch) * DK + c] = S;
        float P = Pchunk[(size_t)bh * ENCH + ch];
        S = P * S + s_end[((size_t)bh * ENCH + ch) * DK + c];
    }
}

// ---------------- K9: sequential inter-chunk scan (MFMA, S in regs, prefetched) ----------------
// grid (bh, tile): linear id = bh + 16*tile -> id%8 = bh%8 -> all 8 tiles of a bh on one XCD
#define STS 260   // st row stride in shorts: 130 dwords = 2 mod 32 -> 2-way (free)
__global__ __launch_bounds__(256, 1) void k_scan(const unsigned short* qn, const unsigned short* wneg,
                                                 const unsigned short* knT, const unsigned short* attnb,
                                                 const float* u, float* od)
{
    __shared__ __align__(16) unsigned short st[32 * STS];   // S^T bf16: [c][kk]
    __shared__ __align__(16) unsigned short uat[32 * 40];   // u_adj^T bf16: [c][r]
    int bh = blockIdx.x;
    int tile = blockIdx.y;      // dv tile (0..7), 32 cols
    int b = bh >> 2, h = bh & 3;
    int wave = threadIdx.x >> 6, lane = threadIdx.x & 63;
    int r16 = lane & 15, quad = lane >> 4;
    int mo = wave & 1, no = wave >> 1;
    int cbase = tile * 32;
    f32x4 z4 = {0.f, 0.f, 0.f, 0.f};
    f32x4 sacc[4][2];
#pragma unroll
    for (int a = 0; a < 4; a++) { sacc[a][0] = z4; sacc[a][1] = z4; }
    const unsigned short* qb = qn + (size_t)bh * L * DK;
    const unsigned short* wb = wneg + (size_t)bh * L * DK;
    const float* ub = u + (size_t)bh * L * DK;
    const unsigned short* kTbase = knT + (size_t)bh * 64 * DK * 32;
    const unsigned short* atbase = attnb + (size_t)bh * 64 * 1024;

    // parity-double-buffered prefetch registers
    bf16x8 qf[2][8], wf[2][8], kf[2][4], af[2];
    f32x4 au0[2];

    auto issue = [&](int ch, int par) {
        int t0 = ch * 32;
        const unsigned short* wrow = wb + (size_t)(t0 + 16 * mo + r16) * DK;
        const unsigned short* qrow = qb + (size_t)(t0 + 16 * mo + r16) * DK;
#pragma unroll
        for (int kt = 0; kt < 8; kt++) {
            qf[par][kt] = *(const bf16x8*)(qrow + kt * 32 + quad * 8);
            wf[par][kt] = *(const bf16x8*)(wrow + kt * 32 + quad * 8);
        }
        const float* up = ub + (size_t)(t0 + 16 * mo + quad * 4) * DK + cbase + no * 16 + r16;
        f32x4 a; a[0] = up[0]; a[1] = up[DK]; a[2] = up[2 * DK]; a[3] = up[3 * DK];
        au0[par] = a;
        af[par] = *(const bf16x8*)(atbase + (size_t)ch * 1024 + (16 * mo + r16) * 32 + quad * 8);
        const unsigned short* kTb = kTbase + (size_t)ch * DK * 32;
#pragma unroll
        for (int a2 = 0; a2 < 4; a2++)
            kf[par][a2] = *(const bf16x8*)(kTb + (size_t)((wave * 4 + a2) * 16 + r16) * 32 + quad * 8);
    };

    issue(0, 0);

    auto body = [&](int ch, int par) {
        int t0 = ch * 32;
        // (A) refresh S^T bf16 in LDS from fp32 accumulators (b64 stores, 2-way banks = free)
#pragma unroll
        for (int a = 0; a < 4; a++) {
            int kkb = (wave * 4 + a) * 16 + quad * 4;
#pragma unroll
            for (int ni = 0; ni < 2; ni++) {
                int c = ni * 16 + r16;
                uint2 p;
                p.x = f2bf(sacc[a][ni][0]) | ((unsigned)f2bf(sacc[a][ni][1]) << 16);
                p.y = f2bf(sacc[a][ni][2]) | ((unsigned)f2bf(sacc[a][ni][3]) << 16);
                *(uint2*)&st[c * STS + kkb] = p;
            }
        }
        // prefetch next chunk while barriers/MFMAs run
        if (ch + 1 < NCH) issue(ch + 1, par ^ 1);
        __syncthreads();

        // (C) u_adj = u - w@S  and o_partial = q@S
        f32x4 au = au0[par], ao = z4;
#pragma unroll
        for (int kt = 0; kt < 8; kt++) {
            union { bf16x8 v8; bf16x4 v4[2]; } bu;
            bu.v4[0] = *(const bf16x4*)&st[(no * 16 + r16) * STS + kt * 32 + quad * 8];
            bu.v4[1] = *(const bf16x4*)&st[(no * 16 + r16) * STS + kt * 32 + quad * 8 + 4];
            au = MFMA16(wf[par][kt], bu.v8, au);
            ao = MFMA16(qf[par][kt], bu.v8, ao);
        }
        // (D) write u_adj^T bf16
        {
            int c = no * 16 + r16;
            int rb = 16 * mo + quad * 4;
            uint2 p;
            p.x = f2bf(au[0]) | ((unsigned)f2bf(au[1]) << 16);
            p.y = f2bf(au[2]) | ((unsigned)f2bf(au[3]) << 16);
            *(uint2*)&uat[c * 40 + rb] = p;
        }
        __syncthreads();

        // (F) o = q@S + attn@u_adj ; store ; S += kT @ u_adj
        {
            bf16x8 uf = *(const bf16x8*)&uat[(no * 16 + r16) * 40 + quad * 8];
            ao = MFMA16(af[par], uf, ao);
            float* op = od + (size_t)(b * L + t0 + 16 * mo + quad * 4) * D + h * DK + cbase + no * 16 + r16;
            op[0] = ao[0]; op[D] = ao[1]; op[2 * D] = ao[2]; op[3 * D] = ao[3];

            bf16x8 u0 = *(const bf16x8*)&uat[(r16) * 40 + quad * 8];
            bf16x8 u1 = *(const bf16x8*)&uat[(16 + r16) * 40 + quad * 8];
#pragma unroll
            for (int a = 0; a < 4; a++) {
                sacc[a][0] = MFMA16(kf[par][a], u0, sacc[a][0]);
                sacc[a][1] = MFMA16(kf[par][a], u1, sacc[a][1]);
            }
        }
    };

    for (int ch2 = 0; ch2 < NCH; ch2 += 2) {
        body(ch2, 0);
        body(ch2 + 1, 1);
    }
}

// ---------------- K10: mix + EMA fix-up + per-head RMS norm -> bf16 ----------------
__global__ __launch_bounds__(256) void k_mixrms(const float* od, const float* ema_local,
                                                const float* Acum, const float* S_in,
                                                const float* mixinp,
                                                const float* mix_bias, const float* rms_w,
                                                unsigned short* onorm)
{
    int row = blockIdx.x;       // b*L + t
    int tid = threadIdx.x;
    int h = tid >> 6, lane = tid & 63;
    int b = row >> 11, t = row & (L - 1);
    int bh = b * NH + h;
    int ch = t >> 6;            // ET = 64
    float m = sigmoidf_(mixinp[(size_t)row * NH + h] + mix_bias[h]);
    int c = tid * 4;
    float A = Acum[(size_t)bh * L + t];
    float4 sin4 = *(const float4*)(S_in + ((size_t)bh * ENCH + ch) * DK + (c & (DK - 1)));
    float4 o = *(const float4*)(od + (size_t)row * D + c);
    float4 e = *(const float4*)(ema_local + (size_t)row * D + c);
    e.x += A * sin4.x; e.y += A * sin4.y; e.z += A * sin4.z; e.w += A * sin4.w;
    float x0 = o.x + m * (e.x - o.x);
    float x1 = o.y + m * (e.y - o.y);
    float x2 = o.z + m * (e.z - o.z);
    float x3 = o.w + m * (e.w - o.w);
    float ss = x0 * x0 + x1 * x1 + x2 * x2 + x3 * x3;
    for (int off = 32; off; off >>= 1) ss += __shfl_xor(ss, off, 64);
    float scale = rsqrtf(ss * (1.0f / 256.0f) + 1e-5f);
    float4 w = *(const float4*)(rms_w + lane * 4);
    uint2 p;
    p.x = f2bf(x0 * scale * w.x) | ((unsigned)f2bf(x1 * scale * w.y) << 16);
    p.y = f2bf(x2 * scale * w.z) | ((unsigned)f2bf(x3 * scale * w.w) << 16);
    *(uint2*)(onorm + (size_t)row * D + c) = p;
}

extern "C" void kernel_launch(void* const* d_in, const int* in_sizes, int n_in,
                              void* d_out, int out_size, void* d_ws, size_t ws_size,
                              hipStream_t stream)
{
    (void)in_sizes; (void)n_in; (void)out_size; (void)ws_size;
    const float* hidden   = (const float*)d_in[0];
    const float* Wq       = (const float*)d_in[1];
    const float* Wk       = (const float*)d_in[2];
    const float* Wv       = (const float*)d_in[3];
    const float* conv_q   = (const float*)d_in[4];
    const float* conv_k   = (const float*)d_in[5];
    const float* conv_v   = (const float*)d_in[6];
    const float* Wb       = (const float*)d_in[7];
    const float* Wdec     = (const float*)d_in[8];
    const float* Wmix     = (const float*)d_in[9];
    const float* conv_mix = (const float*)d_in[10];
    const float* mix_bias = (const float*)d_in[11];
    const float* rms_w    = (const float*)d_in[12];
    const float* Wo       = (const float*)d_in[13];
    float* out = (float*)d_out;

    char* ws = (char*)d_ws;
    size_t off = 0;
    auto alloc = [&](size_t bytes) -> char* {
        char* p = ws + off;
        off += (bytes + 255) & ~(size_t)255;
        return p;
    };
    unsigned short* wT    = (unsigned short*)alloc((size_t)4 * D * D * 2);
    unsigned short* hidB  = (unsigned short*)alloc((size_t)B * L * D * 2);
    unsigned short* xqkv  = (unsigned short*)alloc((size_t)B * L * 3 * D * 2); // later qn/wneg/knT
    float* beta   = (float*)alloc((size_t)B * L * NH * 4);
    float* gamma  = (float*)alloc((size_t)B * L * NH * 4);
    float* xmix   = (float*)alloc((size_t)B * L * NH * 4);
    float* mixinp = (float*)alloc((size_t)B * L * NH * 4);
    float* qbuf   = (float*)alloc((size_t)B * L * D * 4);   // later ema_local
    float* kbuf   = (float*)alloc((size_t)B * L * D * 4);   // later od
    float* vbuf   = (float*)alloc((size_t)B * L * D * 4);
    float* u      = (float*)alloc((size_t)B * L * D * 4);
    unsigned short* attnb = (unsigned short*)alloc((size_t)BH * NCH * CHUNK * CHUNK * 2);
    unsigned short* onorm = (unsigned short*)alloc((size_t)B * L * D * 2);
    unsigned short* kn    = (unsigned short*)alloc((size_t)B * L * D * 2);
    float* Acum   = (float*)alloc((size_t)BH * L * 4);
    float* s_end  = (float*)alloc((size_t)BH * ENCH * DK * 4);
    float* Pchunk = (float*)alloc((size_t)BH * ENCH * 4);
    float* S_in   = (float*)alloc((size_t)BH * ENCH * DK * 4);

    unsigned short* qn   = xqkv;
    unsigned short* wneg = xqkv + (size_t)B * L * D;
    unsigned short* knT  = xqkv + (size_t)2 * B * L * D;
    float* ema_local = qbuf;
    float* od  = kbuf;

    k_wT<<<dim3(32, 32, 4), 256, 0, stream>>>(Wq, Wk, Wv, Wo, wT);
    k_cvt<<<dim3(2048), 256, 0, stream>>>(hidden, hidB, B * L * D / 4);
    k_gemm_lds<3 * D, false><<<dim3(64, 24), 256, 0, stream>>>(hidB, wT, xqkv);
    k_smallproj<<<dim3(B * L / 4), 256, 0, stream>>>(hidden, Wb, Wdec, Wmix, beta, gamma, xmix);
    k_conv<<<dim3(B * L * D / 256, 1, 3), 256, 0, stream>>>(xqkv, conv_q, conv_k, conv_v,
                                                            qbuf, kbuf, vbuf);
    k_convmix<<<dim3(B * L * NH / 256), 256, 0, stream>>>(xmix, conv_mix, mixinp);
    k_l2norm<<<dim3(BH * L / 4), 256, 0, stream>>>(qbuf, kbuf, qn, kn);
    k_delta_pre<<<dim3(BH * NCH), 256, 0, stream>>>(qn, kn, vbuf, beta, wneg, knT, attnb, u);
    k_ema_local<<<dim3(BH * ENCH), 256, 0, stream>>>(vbuf, gamma, ema_local, Acum, s_end, Pchunk);
    k_ema_carry<<<dim3(BH), 256, 0, stream>>>(s_end, Pchunk, S_in);
    k_scan<<<dim3(16, 8), 256, 0, stream>>>(qn, wneg, knT, attnb, u, od);
    k_mixrms<<<dim3(B * L), 256, 0, stream>>>(od, ema_local, Acum, S_in, mixinp, mix_bias, rms_w, onorm);
    k_gemm_lds<D, true><<<dim3(64, 8), 256, 0, stream>>>(onorm, wT + (size_t)3 * D * D, out);
}

// Round 5
// 579.254 us; speedup vs baseline: 2.7104x; 1.0878x over previous
//
#include <hip/hip_runtime.h>
#include <hip/hip_bf16.h>

#define B 4
#define L 2048
#define D 1024
#define NH 4
#define DK 256
#define CHUNK 32
#define NCH 64
#define BH (B*NH)
// EMA chunking
#define ET 64
#define ENCH (L/ET)

typedef __attribute__((ext_vector_type(8))) __bf16 bf16x8;
typedef __attribute__((ext_vector_type(4))) __bf16 bf16x4;
typedef __attribute__((ext_vector_type(4))) float f32x4;

__device__ inline unsigned short f2bf(float f) {
    union { float f; unsigned u; } v; v.f = f;
    unsigned r = v.u + 0x7fffu + ((v.u >> 16) & 1u);
    return (unsigned short)(r >> 16);
}
__device__ inline float bf2f(unsigned short h) {
    union { unsigned u; float f; } v; v.u = ((unsigned)h) << 16; return v.f;
}
__device__ inline float sigmoidf_(float x) { return 1.0f / (1.0f + __expf(-x)); }
__device__ inline float siluf_(float x) { return x / (1.0f + __expf(-x)); }

#define MFMA16(a, b, c) __builtin_amdgcn_mfma_f32_16x16x32_bf16((a), (b), (c), 0, 0, 0)

// raw barrier: wait only LDS (lgkmcnt(0)), leave global loads in flight.
// 0xC07F = vmcnt(63) expcnt(7) lgkmcnt(0)
__device__ inline void bar_lds() {
    __builtin_amdgcn_s_waitcnt(0xC07F);
    __builtin_amdgcn_s_barrier();
}

// async global->LDS, 16B per lane; lds dest = wave-uniform base + lane*16
__device__ inline void load_lds16(const unsigned short* g, unsigned short* l) {
    __builtin_amdgcn_global_load_lds(
        (const __attribute__((address_space(1))) unsigned int*)g,
        (__attribute__((address_space(3))) unsigned int*)l, 16, 0, 0);
}

// ---------------- K1: transpose+convert weights: W (K,N) f32 -> WT (N,K) bf16 ----------------
__global__ __launch_bounds__(256) void k_wT(const float* Wq, const float* Wk, const float* Wv,
                                            const float* Wo, unsigned short* wT)
{
    __shared__ float tile[32][33];
    int z = blockIdx.z;
    const float* W = (z == 0) ? Wq : (z == 1) ? Wk : (z == 2) ? Wv : Wo;
    unsigned short* out = wT + (size_t)z * D * D;
    int kt = blockIdx.x * 32, nt = blockIdx.y * 32;
    int tx = threadIdx.x & 31, ty = threadIdx.x >> 5;
#pragma unroll
    for (int i = 0; i < 4; i++)
        tile[ty + 8 * i][tx] = W[(size_t)(kt + ty + 8 * i) * D + nt + tx];
    __syncthreads();
#pragma unroll
    for (int i = 0; i < 4; i++)
        out[(size_t)(nt + ty + 8 * i) * D + kt + tx] = f2bf(tile[tx][ty + 8 * i]);
}

// ---------------- K2: hidden f32 -> bf16 ----------------
__global__ __launch_bounds__(256) void k_cvt(const float* h, unsigned short* hb, int n4)
{
    int i = blockIdx.x * blockDim.x + threadIdx.x;
    int stride = gridDim.x * blockDim.x;
    const float4* h4 = (const float4*)h;
    for (; i < n4; i += stride) {
        float4 v = h4[i];
        ushort4 o;
        o.x = f2bf(v.x); o.y = f2bf(v.y); o.z = f2bf(v.z); o.w = f2bf(v.w);
        *(ushort4*)(hb + 4 * (size_t)i) = o;
    }
}

// ---------------- K3: LDS-staged 128x128 GEMM (m97 structure) ----------------
template<int NTOT, bool OUT_F32>
__global__ __launch_bounds__(256) void k_gemm_lds(const unsigned short* __restrict__ A,
                                                  const unsigned short* __restrict__ BT,
                                                  void* __restrict__ outp)
{
    __shared__ __align__(16) unsigned short As[128 * 32];   // 8 KB
    __shared__ __align__(16) unsigned short Bs[128 * 32];   // 8 KB
    const int K = 1024;
    int tid = threadIdx.x;
    int w = tid >> 6, lane = tid & 63;
    int r16 = lane & 15, quad = lane >> 4;
    int wm = w & 1, wn = w >> 1;
    int bm = blockIdx.x * 128;
    int bn = blockIdx.y * 128;
    int lrow = lane >> 2;            // 0..15
    int lcol = (lane & 3) * 8;       // element col within 32
    f32x4 z4 = {0.f, 0.f, 0.f, 0.f};
    f32x4 acc[4][4];
#pragma unroll
    for (int i = 0; i < 4; i++)
#pragma unroll
        for (int j = 0; j < 4; j++) acc[i][j] = z4;

    for (int kt = 0; kt < K; kt += 32) {
#pragma unroll
        for (int j = 0; j < 2; j++) {
            int r0 = (w * 2 + j) * 16;
            load_lds16(A + (size_t)(bm + r0 + lrow) * K + kt + lcol, &As[r0 * 32]);
            load_lds16(BT + (size_t)(bn + r0 + lrow) * K + kt + lcol, &Bs[r0 * 32]);
        }
        __syncthreads();
        bf16x8 af[4], bf[4];
#pragma unroll
        for (int ms = 0; ms < 4; ms++)
            af[ms] = *(const bf16x8*)&As[(wm * 64 + ms * 16 + r16) * 32 + quad * 8];
#pragma unroll
        for (int ns = 0; ns < 4; ns++)
            bf[ns] = *(const bf16x8*)&Bs[(wn * 64 + ns * 16 + r16) * 32 + quad * 8];
#pragma unroll
        for (int ms = 0; ms < 4; ms++)
#pragma unroll
            for (int ns = 0; ns < 4; ns++)
                acc[ms][ns] = MFMA16(af[ms], bf[ns], acc[ms][ns]);
        __syncthreads();
    }
#pragma unroll
    for (int ms = 0; ms < 4; ms++)
#pragma unroll
        for (int ns = 0; ns < 4; ns++)
#pragma unroll
            for (int r = 0; r < 4; r++) {
                int m = bm + wm * 64 + ms * 16 + quad * 4 + r;
                int n = bn + wn * 64 + ns * 16 + r16;
                if (OUT_F32)
                    ((float*)outp)[(size_t)m * NTOT + n] = acc[ms][ns][r];
                else
                    ((unsigned short*)outp)[(size_t)m * NTOT + n] = f2bf(acc[ms][ns][r]);
            }
}

// ---------------- K4: small projections ----------------
__global__ __launch_bounds__(256) void k_smallproj(const float* hid, const float* Wb, const float* Wd,
                                                   const float* Wm, float* beta, float* gamma, float* xmix)
{
    int wave = threadIdx.x >> 6, lane = threadIdx.x & 63;
    int row = blockIdx.x * 4 + wave;
    const float* hrow = hid + (size_t)row * D;
    float acc[12];
#pragma unroll
    for (int j = 0; j < 12; j++) acc[j] = 0.f;
    for (int i = 0; i < 16; i++) {
        int k = lane + 64 * i;
        float h = hrow[k];
        float4 wb = ((const float4*)Wb)[k];
        float4 wd = ((const float4*)Wd)[k];
        float4 wm = ((const float4*)Wm)[k];
        acc[0] += h * wb.x; acc[1] += h * wb.y; acc[2] += h * wb.z; acc[3] += h * wb.w;
        acc[4] += h * wd.x; acc[5] += h * wd.y; acc[6] += h * wd.z; acc[7] += h * wd.w;
        acc[8] += h * wm.x; acc[9] += h * wm.y; acc[10] += h * wm.z; acc[11] += h * wm.w;
    }
#pragma unroll
    for (int j = 0; j < 12; j++)
        for (int off = 32; off; off >>= 1) acc[j] += __shfl_xor(acc[j], off, 64);
    if (lane < 4) {
        beta[(size_t)row * 4 + lane] = sigmoidf_(acc[lane]);
        gamma[(size_t)row * 4 + lane] = sigmoidf_(acc[4 + lane]);
        xmix[(size_t)row * 4 + lane] = acc[8 + lane];
    }
}

// ---------------- K5: short conv + silu ----------------
__global__ __launch_bounds__(256) void k_conv(const unsigned short* xqkv,
                                              const float* cq, const float* ck, const float* cv,
                                              float* q, float* k, float* v)
{
    int z = blockIdx.z;
    const float* cw = (z == 0) ? cq : (z == 1) ? ck : cv;
    float* dst = (z == 0) ? q : (z == 1) ? k : v;
    int idx = blockIdx.x * 256 + threadIdx.x;
    int c = idx & (D - 1);
    int t = (idx >> 10) & (L - 1);
    int b = idx >> 21;
    float4 w4 = *(const float4*)(cw + (size_t)c * 4);
    float wv[4] = {w4.x, w4.y, w4.z, w4.w};
    size_t base = ((size_t)(b * L)) * (3 * D) + z * D + c;
    float acc = 0.f;
#pragma unroll
    for (int kk = 0; kk < 4; kk++) {
        int tt = t - 3 + kk;
        if (tt >= 0) acc += wv[kk] * bf2f(xqkv[base + (size_t)tt * (3 * D)]);
    }
    float r = siluf_(acc);
    if (z < 2) r = siluf_(r);
    dst[idx] = r;
}

// ---------------- K6: mix conv + silu ----------------
__global__ __launch_bounds__(256) void k_convmix(const float* xmix, const float* cmix, float* mixinp)
{
    int idx = blockIdx.x * 256 + threadIdx.x;   // < B*L*NH
    int h = idx & 3;
    int t = (idx >> 2) & (L - 1);
    int b = idx >> 13;
    float acc = 0.f;
#pragma unroll
    for (int kk = 0; kk < 4; kk++) {
        int tt = t - 3 + kk;
        if (tt >= 0) acc += cmix[h * 4 + kk] * xmix[((size_t)(b * L + tt) << 2) + h];
    }
    mixinp[idx] = siluf_(acc);
}

// ---------------- K7a: l2norm q,k -> bf16 ----------------
__global__ __launch_bounds__(256) void k_l2norm(const float* qbuf, const float* kbuf,
                                                unsigned short* qn, unsigned short* kn)
{
    int wave = threadIdx.x >> 6, lane = threadIdx.x & 63;
    int rid = blockIdx.x * 4 + wave;      // 0..BH*L-1
    int bh = rid >> 11, t = rid & (L - 1);
    int b = bh >> 2, h = bh & 3;
    size_t src = (size_t)(b * L + t) * D + h * DK + lane * 4;
    float4 q4 = *(const float4*)(qbuf + src);
    float4 k4 = *(const float4*)(kbuf + src);
    float sq = q4.x * q4.x + q4.y * q4.y + q4.z * q4.z + q4.w * q4.w;
    float sk = k4.x * k4.x + k4.y * k4.y + k4.z * k4.z + k4.w * k4.w;
    for (int off = 32; off; off >>= 1) { sq += __shfl_xor(sq, off, 64); sk += __shfl_xor(sk, off, 64); }
    float qsc = rsqrtf(sq + 1e-6f);
    float ksc = rsqrtf(sk + 1e-6f);
    uint2 pq, pk;
    pq.x = f2bf(q4.x * qsc) | ((unsigned)f2bf(q4.y * qsc) << 16);
    pq.y = f2bf(q4.z * qsc) | ((unsigned)f2bf(q4.w * qsc) << 16);
    pk.x = f2bf(k4.x * ksc) | ((unsigned)f2bf(k4.y * ksc) << 16);
    pk.y = f2bf(k4.z * ksc) | ((unsigned)f2bf(k4.w * ksc) << 16);
    *(uint2*)(qn + (size_t)rid * DK + lane * 4) = pq;
    *(uint2*)(kn + (size_t)rid * DK + lane * 4) = pk;
}

// ---------------- K7b: per-(bh,chunk) delta-rule precompute ----------------
__global__ __launch_bounds__(256) void k_delta_pre(const unsigned short* qn, const unsigned short* kn,
                                                   const float* vbuf, const float* beta,
                                                   unsigned short* wneg, unsigned short* knT,
                                                   unsigned short* attnb, float* u)
{
    __shared__ __align__(16) float ks[32 * 260];
    __shared__ float Tm[32 * 33];
    __shared__ float betav[32];
    int bx = blockIdx.x;
    int bh = bx >> 6, ch = bx & 63;
    int b = bh >> 2, h = bh & 3;
    int t0 = ch * 32;
    int tid = threadIdx.x;
    int r = tid >> 3, part = tid & 7;

    const unsigned short* knrow = kn + (size_t)(bh * L + t0 + r) * DK;
#pragma unroll
    for (int i = 0; i < 8; i++) {
        int c = (part + 8 * i) * 4;
        ushort4 kv = *(const ushort4*)(knrow + c);
        ks[r * 260 + c + 0] = bf2f(kv.x);
        ks[r * 260 + c + 1] = bf2f(kv.y);
        ks[r * 260 + c + 2] = bf2f(kv.z);
        ks[r * 260 + c + 3] = bf2f(kv.w);
    }
    if (tid < 32) betav[tid] = beta[(size_t)(b * L + t0 + tid) * NH + h];
    __syncthreads();

    {
        int i = tid >> 3, j0 = (tid & 7) * 4;
        const unsigned short* qrow = qn + (size_t)(bh * L + t0 + i) * DK;
        float g[4] = {0.f, 0.f, 0.f, 0.f};
        float a[4] = {0.f, 0.f, 0.f, 0.f};
        for (int c = 0; c < DK; c += 4) {
            ushort4 qv = *(const ushort4*)(qrow + c);
            float q0 = bf2f(qv.x), q1 = bf2f(qv.y), q2 = bf2f(qv.z), q3 = bf2f(qv.w);
            float4 ki = *(const float4*)&ks[i * 260 + c];
#pragma unroll
            for (int jj = 0; jj < 4; jj++) {
                float4 kj = *(const float4*)&ks[(j0 + jj) * 260 + c];
                g[jj] += ki.x * kj.x + ki.y * kj.y + ki.z * kj.z + ki.w * kj.w;
                a[jj] += q0 * kj.x + q1 * kj.y + q2 * kj.z + q3 * kj.w;
            }
        }
#pragma unroll
        for (int jj = 0; jj < 4; jj++) {
            int j = j0 + jj;
            Tm[i * 33 + j] = (j < i) ? (-betav[i] * g[jj]) : 0.0f;
            if (j > i) a[jj] = 0.f;
        }
        uint2 p;
        p.x = f2bf(a[0]) | ((unsigned)f2bf(a[1]) << 16);
        p.y = f2bf(a[2]) | ((unsigned)f2bf(a[3]) << 16);
        *(uint2*)(attnb + (size_t)(bh * 64 + ch) * 1024 + i * 32 + j0) = p;
    }
    __syncthreads();

    for (int i = 1; i < 32; i++) {
        float s = 0.f;
        bool act = (tid < i);
        if (act) {
            s = Tm[i * 33 + tid];
            for (int j = tid + 1; j < i; j++) s += Tm[i * 33 + j] * Tm[j * 33 + tid];
        }
        __syncthreads();
        if (act) Tm[i * 33 + tid] = s;
        __syncthreads();
    }
    for (int idx = tid; idx < 1024; idx += 256) {
        int i = idx >> 5, j = idx & 31;
        float val = (j == i) ? 1.0f : Tm[i * 33 + j];
        Tm[i * 33 + j] = val * betav[j];
    }
    __syncthreads();

    {
        const float* vrow0 = vbuf + (size_t)(b * L + t0) * D + h * DK;
        float* ug = u + (size_t)(bh * L + t0 + r) * DK;
        unsigned short* wg = wneg + (size_t)(bh * L + t0 + r) * DK;
        for (int ccb = 0; ccb < 8; ccb++) {
            int c = part * 4 + 32 * ccb;
            float au0 = 0, au1 = 0, au2 = 0, au3 = 0;
            float aw0 = 0, aw1 = 0, aw2 = 0, aw3 = 0;
            for (int j = 0; j < 32; j++) {
                float t2 = Tm[r * 33 + j];
                float4 vj = *(const float4*)(vrow0 + (size_t)j * D + c);
                float4 kj = *(const float4*)&ks[j * 260 + c];
                au0 += t2 * vj.x; au1 += t2 * vj.y; au2 += t2 * vj.z; au3 += t2 * vj.w;
                aw0 += t2 * kj.x; aw1 += t2 * kj.y; aw2 += t2 * kj.z; aw3 += t2 * kj.w;
            }
            float4 uo; uo.x = au0; uo.y = au1; uo.z = au2; uo.w = au3;
            *(float4*)(ug + c) = uo;
            uint2 p;
            p.x = f2bf(-aw0) | ((unsigned)f2bf(-aw1) << 16);
            p.y = f2bf(-aw2) | ((unsigned)f2bf(-aw3) << 16);
            *(uint2*)(wg + c) = p;
        }
    }
    {
        int kk = tid;
        unsigned short* kT = knT + ((size_t)(bh * 64 + ch) * DK + kk) * 32;
#pragma unroll
        for (int r2 = 0; r2 < 32; r2 += 2) {
            unsigned pv = f2bf(ks[r2 * 260 + kk]) | ((unsigned)f2bf(ks[(r2 + 1) * 260 + kk]) << 16);
            *(unsigned*)(kT + r2) = pv;
        }
    }
}

// ---------------- K8a: EMA local scan ----------------
__global__ __launch_bounds__(256) void k_ema_local(const float* v, const float* gamma,
                                                   float* ema_local, float* Acum,
                                                   float* s_end, float* Pchunk)
{
    __shared__ float gsh[ET];
    int blk = blockIdx.x;
    int bh = blk >> 5;
    int ch = blk & (ENCH - 1);
    int b = bh >> 2, h = bh & 3;
    int c = threadIdx.x;
    int t0 = ch * ET;
    if (c < ET) gsh[c] = gamma[(size_t)(b * L + t0 + c) * NH + h];
    __syncthreads();
    const float* vg = v + (size_t)(b * L + t0) * D + h * DK + c;
    float* eg = ema_local + (size_t)(b * L + t0) * D + h * DK + c;
    float* Ag = Acum + (size_t)bh * L + t0;
    float s = 0.f;
    float A = 1.f;
#pragma unroll 8
    for (int i = 0; i < ET; i++) {
        float g = gsh[i];
        s = g * s + (1.f - g) * vg[(size_t)i * D];
        A *= g;
        eg[(size_t)i * D] = s;
        if (c == 0) Ag[i] = A;
    }
    s_end[((size_t)bh * ENCH + ch) * DK + c] = s;
    if (c == 0) Pchunk[(size_t)bh * ENCH + ch] = A;
}

// ---------------- K8b: EMA carry scan ----------------
__global__ __launch_bounds__(256) void k_ema_carry(const float* s_end, const float* Pchunk, float* S_in)
{
    int bh = blockIdx.x;
    int c = threadIdx.x;
    float S = 0.f;
    for (int ch = 0; ch < ENCH; ch++) {
        S_in[((size_t)bh * ENCH + ch) * DK + c] = S;
        float P = Pchunk[(size_t)bh * ENCH + ch];
        S = P * S + s_end[((size_t)bh * ENCH + ch) * DK + c];
    }
}

// ---------------- K9: sequential inter-chunk scan ----------------
// 2 waves/block, 16 dv-cols per block; grid (bh=16, tile=16) -> id%8 = bh%8 (XCD locality).
// Each wave: rows 16*mo..16*mo+15 of the chunk; sacc = S^T rows mo*128..mo*128+127 x 16 cols.
// Raw lgkm-only barriers keep prefetched global loads in flight across sync points.
#define STS 280   // st row stride in shorts (dword stride 140 = 12 mod 32 -> ~2-way)
#define USTR 40   // uat row stride in shorts (2-way only)
__global__ __launch_bounds__(128, 1) void k_scan(const unsigned short* qn, const unsigned short* wneg,
                                                 const unsigned short* knT, const unsigned short* attnb,
                                                 const float* u, float* od)
{
    __shared__ __align__(16) unsigned short st[16 * STS];   // S^T bf16: [c][dk]
    __shared__ __align__(16) unsigned short uat[16 * USTR]; // u_adj^T bf16: [c][t]
    int bh = blockIdx.x;
    int tile = blockIdx.y;      // 0..15, 16 cols each
    int b = bh >> 2, h = bh & 3;
    int mo = threadIdx.x >> 6, lane = threadIdx.x & 63;
    int r16 = lane & 15, quad = lane >> 4;
    int cbase = tile * 16;
    f32x4 z4 = {0.f, 0.f, 0.f, 0.f};
    f32x4 sacc[8];
#pragma unroll
    for (int a = 0; a < 8; a++) sacc[a] = z4;
    const unsigned short* qb = qn + (size_t)bh * L * DK;
    const unsigned short* wb = wneg + (size_t)bh * L * DK;
    const float* ub = u + (size_t)bh * L * DK;
    const unsigned short* kTbase = knT + (size_t)bh * 64 * DK * 32;
    const unsigned short* atbase = attnb + (size_t)bh * 64 * 1024;
    int dkb = mo * 128;   // this wave's S^T row base

    // parity-prefetched (one chunk ahead): q/w A-frags + u accumulator init
    bf16x8 qf[2][8], wf[2][8];
    f32x4 au0[2];

    auto issue = [&](int ch, int par) {
        int t0 = ch * 32;
        const unsigned short* wrow = wb + (size_t)(t0 + 16 * mo + r16) * DK;
        const unsigned short* qrow = qb + (size_t)(t0 + 16 * mo + r16) * DK;
#pragma unroll
        for (int kt = 0; kt < 8; kt++) {
            qf[par][kt] = *(const bf16x8*)(qrow + kt * 32 + quad * 8);
            wf[par][kt] = *(const bf16x8*)(wrow + kt * 32 + quad * 8);
        }
        const float* up = ub + (size_t)(t0 + 16 * mo + quad * 4) * DK + cbase + r16;
        f32x4 a; a[0] = up[0]; a[1] = up[DK]; a[2] = up[2 * DK]; a[3] = up[3 * DK];
        au0[par] = a;
    };

    issue(0, 0);

    auto body = [&](int ch, int par) {
        int t0 = ch * 32;
        // (A) write this wave's S^T slab (dk rows dkb..dkb+127, cols r16) to LDS
#pragma unroll
        for (int a = 0; a < 8; a++) {
            uint2 p;
            p.x = f2bf(sacc[a][0]) | ((unsigned)f2bf(sacc[a][1]) << 16);
            p.y = f2bf(sacc[a][2]) | ((unsigned)f2bf(sacc[a][3]) << 16);
            *(uint2*)&st[r16 * STS + dkb + a * 16 + quad * 4] = p;
        }
        // prefetch next chunk (stays in flight across raw barriers)
        if (ch + 1 < NCH) issue(ch + 1, par ^ 1);
        bar_lds();

        // current-chunk late loads (covered by the MFMA chains below)
        bf16x8 af = *(const bf16x8*)(atbase + (size_t)ch * 1024 + (16 * mo + r16) * 32 + quad * 8);
        const unsigned short* kTb = kTbase + (size_t)ch * DK * 32;
        bf16x8 kf[8];
#pragma unroll
        for (int a = 0; a < 8; a++)
            kf[a] = *(const bf16x8*)(kTb + (size_t)(dkb + a * 16 + r16) * 32 + quad * 8);

        // (C) u_adj = u - w@S ; o_partial = q@S   (16 rows x own 16 cols)
        f32x4 au = au0[par], ao = z4;
#pragma unroll
        for (int kt = 0; kt < 8; kt++) {
            bf16x8 sfr = *(const bf16x8*)&st[r16 * STS + kt * 32 + quad * 8];
            au = MFMA16(wf[par][kt], sfr, au);
            ao = MFMA16(qf[par][kt], sfr, ao);
        }
        // (D) write u_adj^T [c][t]
        {
            uint2 p;
            p.x = f2bf(au[0]) | ((unsigned)f2bf(au[1]) << 16);
            p.y = f2bf(au[2]) | ((unsigned)f2bf(au[3]) << 16);
            *(uint2*)&uat[r16 * USTR + 16 * mo + quad * 4] = p;
        }
        bar_lds();

        // (F) o = q@S + attn@u_adj ; store ; S^T += kT @ u_adj
        {
            bf16x8 uf = *(const bf16x8*)&uat[r16 * USTR + quad * 8];
            ao = MFMA16(af, uf, ao);
            float* op = od + (size_t)(b * L + t0 + 16 * mo + quad * 4) * D + h * DK + cbase + r16;
            op[0] = ao[0]; op[D] = ao[1]; op[2 * D] = ao[2]; op[3 * D] = ao[3];
#pragma unroll
            for (int a = 0; a < 8; a++)
                sacc[a] = MFMA16(kf[a], uf, sacc[a]);
        }
    };

    for (int ch2 = 0; ch2 < NCH; ch2 += 2) {
        body(ch2, 0);
        body(ch2 + 1, 1);
    }
}

// ---------------- K10: mix + EMA fix-up + per-head RMS norm -> bf16 ----------------
__global__ __launch_bounds__(256) void k_mixrms(const float* od, const float* ema_local,
                                                const float* Acum, const float* S_in,
                                                const float* mixinp,
                                                const float* mix_bias, const float* rms_w,
                                                unsigned short* onorm)
{
    int row = blockIdx.x;       // b*L + t
    int tid = threadIdx.x;
    int h = tid >> 6, lane = tid & 63;
    int b = row >> 11, t = row & (L - 1);
    int bh = b * NH + h;
    int ch = t >> 6;            // ET = 64
    float m = sigmoidf_(mixinp[(size_t)row * NH + h] + mix_bias[h]);
    int c = tid * 4;
    float A = Acum[(size_t)bh * L + t];
    float4 sin4 = *(const float4*)(S_in + ((size_t)bh * ENCH + ch) * DK + (c & (DK - 1)));
    float4 o = *(const float4*)(od + (size_t)row * D + c);
    float4 e = *(const float4*)(ema_local + (size_t)row * D + c);
    e.x += A * sin4.x; e.y += A * sin4.y; e.z += A * sin4.z; e.w += A * sin4.w;
    float x0 = o.x + m * (e.x - o.x);
    float x1 = o.y + m * (e.y - o.y);
    float x2 = o.z + m * (e.z - o.z);
    float x3 = o.w + m * (e.w - o.w);
    float ss = x0 * x0 + x1 * x1 + x2 * x2 + x3 * x3;
    for (int off = 32; off; off >>= 1) ss += __shfl_xor(ss, off, 64);
    float scale = rsqrtf(ss * (1.0f / 256.0f) + 1e-5f);
    float4 w = *(const float4*)(rms_w + lane * 4);
    uint2 p;
    p.x = f2bf(x0 * scale * w.x) | ((unsigned)f2bf(x1 * scale * w.y) << 16);
    p.y = f2bf(x2 * scale * w.z) | ((unsigned)f2bf(x3 * scale * w.w) << 16);
    *(uint2*)(onorm + (size_t)row * D + c) = p;
}

extern "C" void kernel_launch(void* const* d_in, const int* in_sizes, int n_in,
                              void* d_out, int out_size, void* d_ws, size_t ws_size,
                              hipStream_t stream)
{
    (void)in_sizes; (void)n_in; (void)out_size; (void)ws_size;
    const float* hidden   = (const float*)d_in[0];
    const float* Wq       = (const float*)d_in[1];
    const float* Wk       = (const float*)d_in[2];
    const float* Wv       = (const float*)d_in[3];
    const float* conv_q   = (const float*)d_in[4];
    const float* conv_k   = (const float*)d_in[5];
    const float* conv_v   = (const float*)d_in[6];
    const float* Wb       = (const float*)d_in[7];
    const float* Wdec     = (const float*)d_in[8];
    const float* Wmix     = (const float*)d_in[9];
    const float* conv_mix = (const float*)d_in[10];
    const float* mix_bias = (const float*)d_in[11];
    const float* rms_w    = (const float*)d_in[12];
    const float* Wo       = (const float*)d_in[13];
    float* out = (float*)d_out;

    char* ws = (char*)d_ws;
    size_t off = 0;
    auto alloc = [&](size_t bytes) -> char* {
        char* p = ws + off;
        off += (bytes + 255) & ~(size_t)255;
        return p;
    };
    unsigned short* wT    = (unsigned short*)alloc((size_t)4 * D * D * 2);
    unsigned short* hidB  = (unsigned short*)alloc((size_t)B * L * D * 2);
    unsigned short* xqkv  = (unsigned short*)alloc((size_t)B * L * 3 * D * 2); // later qn/wneg/knT
    float* beta   = (float*)alloc((size_t)B * L * NH * 4);
    float* gamma  = (float*)alloc((size_t)B * L * NH * 4);
    float* xmix   = (float*)alloc((size_t)B * L * NH * 4);
    float* mixinp = (float*)alloc((size_t)B * L * NH * 4);
    float* qbuf   = (float*)alloc((size_t)B * L * D * 4);   // later ema_local
    float* kbuf   = (float*)alloc((size_t)B * L * D * 4);   // later od
    float* vbuf   = (float*)alloc((size_t)B * L * D * 4);
    float* u      = (float*)alloc((size_t)B * L * D * 4);
    unsigned short* attnb = (unsigned short*)alloc((size_t)BH * NCH * CHUNK * CHUNK * 2);
    unsigned short* onorm = (unsigned short*)alloc((size_t)B * L * D * 2);
    unsigned short* kn    = (unsigned short*)alloc((size_t)B * L * D * 2);
    float* Acum   = (float*)alloc((size_t)BH * L * 4);
    float* s_end  = (float*)alloc((size_t)BH * ENCH * DK * 4);
    float* Pchunk = (float*)alloc((size_t)BH * ENCH * 4);
    float* S_in   = (float*)alloc((size_t)BH * ENCH * DK * 4);

    unsigned short* qn   = xqkv;
    unsigned short* wneg = xqkv + (size_t)B * L * D;
    unsigned short* knT  = xqkv + (size_t)2 * B * L * D;
    float* ema_local = qbuf;
    float* od  = kbuf;

    k_wT<<<dim3(32, 32, 4), 256, 0, stream>>>(Wq, Wk, Wv, Wo, wT);
    k_cvt<<<dim3(2048), 256, 0, stream>>>(hidden, hidB, B * L * D / 4);
    k_gemm_lds<3 * D, false><<<dim3(64, 24), 256, 0, stream>>>(hidB, wT, xqkv);
    k_smallproj<<<dim3(B * L / 4), 256, 0, stream>>>(hidden, Wb, Wdec, Wmix, beta, gamma, xmix);
    k_conv<<<dim3(B * L * D / 256, 1, 3), 256, 0, stream>>>(xqkv, conv_q, conv_k, conv_v,
                                                            qbuf, kbuf, vbuf);
    k_convmix<<<dim3(B * L * NH / 256), 256, 0, stream>>>(xmix, conv_mix, mixinp);
    k_l2norm<<<dim3(BH * L / 4), 256, 0, stream>>>(qbuf, kbuf, qn, kn);
    k_delta_pre<<<dim3(BH * NCH), 256, 0, stream>>>(qn, kn, vbuf, beta, wneg, knT, attnb, u);
    k_ema_local<<<dim3(BH * ENCH), 256, 0, stream>>>(vbuf, gamma, ema_local, Acum, s_end, Pchunk);
    k_ema_carry<<<dim3(BH), 256, 0, stream>>>(s_end, Pchunk, S_in);
    k_scan<<<dim3(16, 16), 128, 0, stream>>>(qn, wneg, knT, attnb, u, od);
    k_mixrms<<<dim3(B * L), 256, 0, stream>>>(od, ema_local, Acum, S_in, mixinp, mix_bias, rms_w, onorm);
    k_gemm_lds<D, true><<<dim3(64, 8), 256, 0, stream>>>(onorm, wT + (size_t)3 * D * D, out);
}

// Round 7
// 534.502 us; speedup vs baseline: 2.9374x; 1.0837x over previous
//
#include <hip/hip_runtime.h>
#include <hip/hip_bf16.h>

#define B 4
#define L 2048
#define D 1024
#define NH 4
#define DK 256
#define CHUNK 32
#define NCH 64
#define BH (B*NH)
// EMA chunking
#define ET 64
#define ENCH (L/ET)

typedef __attribute__((ext_vector_type(8))) __bf16 bf16x8;
typedef __attribute__((ext_vector_type(4))) __bf16 bf16x4;
typedef __attribute__((ext_vector_type(4))) float f32x4;

__device__ inline unsigned short f2bf(float f) {
    union { float f; unsigned u; } v; v.f = f;
    unsigned r = v.u + 0x7fffu + ((v.u >> 16) & 1u);
    return (unsigned short)(r >> 16);
}
__device__ inline float bf2f(unsigned short h) {
    union { unsigned u; float f; } v; v.u = ((unsigned)h) << 16; return v.f;
}
__device__ inline float sigmoidf_(float x) { return 1.0f / (1.0f + __expf(-x)); }
__device__ inline float siluf_(float x) { return x / (1.0f + __expf(-x)); }

#define MFMA16(a, b, c) __builtin_amdgcn_mfma_f32_16x16x32_bf16((a), (b), (c), 0, 0, 0)

// raw barrier: wait only LDS (lgkmcnt(0)), leave global loads in flight.
// 0xC07F = vmcnt(63) expcnt(7) lgkmcnt(0)
__device__ inline void bar_lds() {
    __builtin_amdgcn_s_waitcnt(0xC07F);
    __builtin_amdgcn_s_barrier();
}

// async global->LDS, 16B per lane; lds dest = wave-uniform base + lane*16
__device__ inline void load_lds16(const unsigned short* g, unsigned short* l) {
    __builtin_amdgcn_global_load_lds(
        (const __attribute__((address_space(1))) unsigned int*)g,
        (__attribute__((address_space(3))) unsigned int*)l, 16, 0, 0);
}

// ---------------- K1: transpose+convert weights: W (K,N) f32 -> WT (N,K) bf16 ----------------
__global__ __launch_bounds__(256) void k_wT(const float* Wq, const float* Wk, const float* Wv,
                                            const float* Wo, unsigned short* wT)
{
    __shared__ float tile[32][33];
    int z = blockIdx.z;
    const float* W = (z == 0) ? Wq : (z == 1) ? Wk : (z == 2) ? Wv : Wo;
    unsigned short* out = wT + (size_t)z * D * D;
    int kt = blockIdx.x * 32, nt = blockIdx.y * 32;
    int tx = threadIdx.x & 31, ty = threadIdx.x >> 5;
#pragma unroll
    for (int i = 0; i < 4; i++)
        tile[ty + 8 * i][tx] = W[(size_t)(kt + ty + 8 * i) * D + nt + tx];
    __syncthreads();
#pragma unroll
    for (int i = 0; i < 4; i++)
        out[(size_t)(nt + ty + 8 * i) * D + kt + tx] = f2bf(tile[tx][ty + 8 * i]);
}

// ---------------- K2: hidden f32 -> bf16 ----------------
__global__ __launch_bounds__(256) void k_cvt(const float* h, unsigned short* hb, int n4)
{
    int i = blockIdx.x * blockDim.x + threadIdx.x;
    int stride = gridDim.x * blockDim.x;
    const float4* h4 = (const float4*)h;
    for (; i < n4; i += stride) {
        float4 v = h4[i];
        ushort4 o;
        o.x = f2bf(v.x); o.y = f2bf(v.y); o.z = f2bf(v.z); o.w = f2bf(v.w);
        *(ushort4*)(hb + 4 * (size_t)i) = o;
    }
}

// ---------------- K3: LDS-staged 128x128 GEMM (m97 structure) ----------------
template<int NTOT, bool OUT_F32>
__global__ __launch_bounds__(256) void k_gemm_lds(const unsigned short* __restrict__ A,
                                                  const unsigned short* __restrict__ BT,
                                                  void* __restrict__ outp)
{
    __shared__ __align__(16) unsigned short As[128 * 32];   // 8 KB
    __shared__ __align__(16) unsigned short Bs[128 * 32];   // 8 KB
    const int K = 1024;
    int tid = threadIdx.x;
    int w = tid >> 6, lane = tid & 63;
    int r16 = lane & 15, quad = lane >> 4;
    int wm = w & 1, wn = w >> 1;
    int bm = blockIdx.x * 128;
    int bn = blockIdx.y * 128;
    int lrow = lane >> 2;            // 0..15
    int lcol = (lane & 3) * 8;       // element col within 32
    f32x4 z4 = {0.f, 0.f, 0.f, 0.f};
    f32x4 acc[4][4];
#pragma unroll
    for (int i = 0; i < 4; i++)
#pragma unroll
        for (int j = 0; j < 4; j++) acc[i][j] = z4;

    for (int kt = 0; kt < K; kt += 32) {
#pragma unroll
        for (int j = 0; j < 2; j++) {
            int r0 = (w * 2 + j) * 16;
            load_lds16(A + (size_t)(bm + r0 + lrow) * K + kt + lcol, &As[r0 * 32]);
            load_lds16(BT + (size_t)(bn + r0 + lrow) * K + kt + lcol, &Bs[r0 * 32]);
        }
        __syncthreads();
        bf16x8 af[4], bf[4];
#pragma unroll
        for (int ms = 0; ms < 4; ms++)
            af[ms] = *(const bf16x8*)&As[(wm * 64 + ms * 16 + r16) * 32 + quad * 8];
#pragma unroll
        for (int ns = 0; ns < 4; ns++)
            bf[ns] = *(const bf16x8*)&Bs[(wn * 64 + ns * 16 + r16) * 32 + quad * 8];
#pragma unroll
        for (int ms = 0; ms < 4; ms++)
#pragma unroll
            for (int ns = 0; ns < 4; ns++)
                acc[ms][ns] = MFMA16(af[ms], bf[ns], acc[ms][ns]);
        __syncthreads();
    }
#pragma unroll
    for (int ms = 0; ms < 4; ms++)
#pragma unroll
        for (int ns = 0; ns < 4; ns++)
#pragma unroll
            for (int r = 0; r < 4; r++) {
                int m = bm + wm * 64 + ms * 16 + quad * 4 + r;
                int n = bn + wn * 64 + ns * 16 + r16;
                if (OUT_F32)
                    ((float*)outp)[(size_t)m * NTOT + n] = acc[ms][ns][r];
                else
                    ((unsigned short*)outp)[(size_t)m * NTOT + n] = f2bf(acc[ms][ns][r]);
            }
}

// ---------------- K4: small projections ----------------
__global__ __launch_bounds__(256) void k_smallproj(const float* hid, const float* Wb, const float* Wd,
                                                   const float* Wm, float* beta, float* gamma, float* xmix)
{
    int wave = threadIdx.x >> 6, lane = threadIdx.x & 63;
    int row = blockIdx.x * 4 + wave;
    const float* hrow = hid + (size_t)row * D;
    float acc[12];
#pragma unroll
    for (int j = 0; j < 12; j++) acc[j] = 0.f;
    for (int i = 0; i < 16; i++) {
        int k = lane + 64 * i;
        float h = hrow[k];
        float4 wb = ((const float4*)Wb)[k];
        float4 wd = ((const float4*)Wd)[k];
        float4 wm = ((const float4*)Wm)[k];
        acc[0] += h * wb.x; acc[1] += h * wb.y; acc[2] += h * wb.z; acc[3] += h * wb.w;
        acc[4] += h * wd.x; acc[5] += h * wd.y; acc[6] += h * wd.z; acc[7] += h * wd.w;
        acc[8] += h * wm.x; acc[9] += h * wm.y; acc[10] += h * wm.z; acc[11] += h * wm.w;
    }
#pragma unroll
    for (int j = 0; j < 12; j++)
        for (int off = 32; off; off >>= 1) acc[j] += __shfl_xor(acc[j], off, 64);
    if (lane < 4) {
        beta[(size_t)row * 4 + lane] = sigmoidf_(acc[lane]);
        gamma[(size_t)row * 4 + lane] = sigmoidf_(acc[4 + lane]);
        xmix[(size_t)row * 4 + lane] = acc[8 + lane];
    }
}

// ---------------- K5: short conv + silu ----------------
__global__ __launch_bounds__(256) void k_conv(const unsigned short* xqkv,
                                              const float* cq, const float* ck, const float* cv,
                                              float* q, float* k, float* v)
{
    int z = blockIdx.z;
    const float* cw = (z == 0) ? cq : (z == 1) ? ck : cv;
    float* dst = (z == 0) ? q : (z == 1) ? k : v;
    int idx = blockIdx.x * 256 + threadIdx.x;
    int c = idx & (D - 1);
    int t = (idx >> 10) & (L - 1);
    int b = idx >> 21;
    float4 w4 = *(const float4*)(cw + (size_t)c * 4);
    float wv[4] = {w4.x, w4.y, w4.z, w4.w};
    size_t base = ((size_t)(b * L)) * (3 * D) + z * D + c;
    float acc = 0.f;
#pragma unroll
    for (int kk = 0; kk < 4; kk++) {
        int tt = t - 3 + kk;
        if (tt >= 0) acc += wv[kk] * bf2f(xqkv[base + (size_t)tt * (3 * D)]);
    }
    float r = siluf_(acc);
    if (z < 2) r = siluf_(r);
    dst[idx] = r;
}

// ---------------- K6: mix conv + silu ----------------
__global__ __launch_bounds__(256) void k_convmix(const float* xmix, const float* cmix, float* mixinp)
{
    int idx = blockIdx.x * 256 + threadIdx.x;   // < B*L*NH
    int h = idx & 3;
    int t = (idx >> 2) & (L - 1);
    int b = idx >> 13;
    float acc = 0.f;
#pragma unroll
    for (int kk = 0; kk < 4; kk++) {
        int tt = t - 3 + kk;
        if (tt >= 0) acc += cmix[h * 4 + kk] * xmix[((size_t)(b * L + tt) << 2) + h];
    }
    mixinp[idx] = siluf_(acc);
}

// ---------------- K7a: l2norm q,k -> bf16 ----------------
__global__ __launch_bounds__(256) void k_l2norm(const float* qbuf, const float* kbuf,
                                                unsigned short* qn, unsigned short* kn)
{
    int wave = threadIdx.x >> 6, lane = threadIdx.x & 63;
    int rid = blockIdx.x * 4 + wave;      // 0..BH*L-1
    int bh = rid >> 11, t = rid & (L - 1);
    int b = bh >> 2, h = bh & 3;
    size_t src = (size_t)(b * L + t) * D + h * DK + lane * 4;
    float4 q4 = *(const float4*)(qbuf + src);
    float4 k4 = *(const float4*)(kbuf + src);
    float sq = q4.x * q4.x + q4.y * q4.y + q4.z * q4.z + q4.w * q4.w;
    float sk = k4.x * k4.x + k4.y * k4.y + k4.z * k4.z + k4.w * k4.w;
    for (int off = 32; off; off >>= 1) { sq += __shfl_xor(sq, off, 64); sk += __shfl_xor(sk, off, 64); }
    float qsc = rsqrtf(sq + 1e-6f);
    float ksc = rsqrtf(sk + 1e-6f);
    uint2 pq, pk;
    pq.x = f2bf(q4.x * qsc) | ((unsigned)f2bf(q4.y * qsc) << 16);
    pq.y = f2bf(q4.z * qsc) | ((unsigned)f2bf(q4.w * qsc) << 16);
    pk.x = f2bf(k4.x * ksc) | ((unsigned)f2bf(k4.y * ksc) << 16);
    pk.y = f2bf(k4.z * ksc) | ((unsigned)f2bf(k4.w * ksc) << 16);
    *(uint2*)(qn + (size_t)rid * DK + lane * 4) = pq;
    *(uint2*)(kn + (size_t)rid * DK + lane * 4) = pk;
}

// ---------------- K7b: per-(bh,chunk) delta-rule precompute (MFMA version) ----------------
// Phase A: G=k.kT, QK=q.kT via MFMA (waves 0-2); all threads transpose k,v into LDS bf16.
// Phase B: wave 0 does forward substitution in registers (shfl broadcasts, no barriers);
//          waves 1-3 dump kT -> knT global.
// Phase C: u = T2@v (f32), wneg = -(T2@k) (bf16) via MFMA.
#define KTS 40   // LDS row stride in shorts: 80B (16B-aligned), dword stride 20 -> 2-way banks (free)
__global__ __launch_bounds__(256) void k_delta_pre(const unsigned short* qn, const unsigned short* kn,
                                                   const float* vbuf, const float* beta,
                                                   unsigned short* wneg, unsigned short* knT,
                                                   unsigned short* attnb, float* u)
{
    __shared__ __align__(16) unsigned short kTl[256 * KTS]; // k^T bf16 [dk][t]
    __shared__ __align__(16) unsigned short vTl[256 * KTS]; // v^T bf16 [dk][t]
    __shared__ __align__(16) unsigned short T2b[32 * KTS];  // T2 bf16 [t][t']
    __shared__ float Gs[32 * 33];
    int bx = blockIdx.x;
    int bh = bx >> 6, ch = bx & 63;
    int b = bh >> 2, h = bh & 3;
    int t0 = ch * 32;
    int tid = threadIdx.x;
    int w = tid >> 6, lane = tid & 63;
    int r16 = lane & 15, quad = lane >> 4;
    size_t rowbase = (size_t)(bh * L + t0);
    f32x4 z4 = {0.f, 0.f, 0.f, 0.f};

    // ---- phase A: MFMA G/QK tiles
    if (w < 3) {
        int mi = (w == 0) ? 0 : 1;
        int ni = (w == 2) ? 1 : 0;
        const unsigned short* krm = kn + (rowbase + mi * 16 + r16) * DK;
        const unsigned short* krn = kn + (rowbase + ni * 16 + r16) * DK;
        const unsigned short* qrm = qn + (rowbase + mi * 16 + r16) * DK;
        f32x4 g = z4, qk = z4;
#pragma unroll
        for (int kt = 0; kt < 8; kt++) {
            bf16x8 a  = *(const bf16x8*)(krm + kt * 32 + quad * 8);
            bf16x8 bb = *(const bf16x8*)(krn + kt * 32 + quad * 8);
            bf16x8 qa = *(const bf16x8*)(qrm + kt * 32 + quad * 8);
            g  = MFMA16(a, bb, g);
            qk = MFMA16(qa, bb, qk);
        }
#pragma unroll
        for (int r = 0; r < 4; r++) {
            int i = mi * 16 + quad * 4 + r, j = ni * 16 + r16;
            Gs[i * 33 + j] = g[r];
            attnb[(size_t)(bh * 64 + ch) * 1024 + i * 32 + j] =
                (j <= i) ? f2bf(qk[r]) : (unsigned short)0;
        }
    } else {
        // strictly-upper QK tile (0,1) is all zero
#pragma unroll
        for (int r = 0; r < 4; r++) {
            int i = quad * 4 + r, j = 16 + r16;
            attnb[(size_t)(bh * 64 + ch) * 1024 + i * 32 + j] = 0;
        }
    }
    // ---- phase A2 (all threads): transpose k (bf16) and v (f32->bf16) into LDS
    {
        int t = tid & 31, c0 = (tid >> 5) * 32;
        const unsigned short* krow = kn + (rowbase + t) * DK + c0;
        const float* vrow = vbuf + ((size_t)(b * L + t0 + t)) * D + h * DK + c0;
#pragma unroll
        for (int j = 0; j < 32; j += 4) {
            ushort4 kv = *(const ushort4*)(krow + j);
            float4 vv = *(const float4*)(vrow + j);
            kTl[(c0 + j + 0) * KTS + t] = kv.x;
            kTl[(c0 + j + 1) * KTS + t] = kv.y;
            kTl[(c0 + j + 2) * KTS + t] = kv.z;
            kTl[(c0 + j + 3) * KTS + t] = kv.w;
            vTl[(c0 + j + 0) * KTS + t] = f2bf(vv.x);
            vTl[(c0 + j + 1) * KTS + t] = f2bf(vv.y);
            vTl[(c0 + j + 2) * KTS + t] = f2bf(vv.z);
            vTl[(c0 + j + 3) * KTS + t] = f2bf(vv.w);
        }
    }
    __syncthreads();

    // ---- phase B
    if (w == 0) {
        int c = lane & 31;
        float rr[32];
#pragma unroll
        for (int j = 0; j < 32; j++) rr[j] = Gs[j * 33 + c];
        // Row 0 of the strict-lower T is empty: must be zero (BUGFIX vs R6 —
        // rr[0] is never processed by the i-loop, and is only read at the final
        // T2 write, so zero it up front).
        rr[0] = 0.f;
        float bc = beta[(size_t)(b * L + t0 + c) * NH + h];
        // T[i] = A[i] + sum_{j<i} A[i,j]*T[j], A[i,j] = -beta_i*G[i,j] (strict lower)
#pragma unroll
        for (int i = 1; i < 32; i++) {
            float bi = __shfl(bc, i, 64);
            float s = -bi * rr[i];
#pragma unroll
            for (int j = 1; j < i; j++) {
                float aij = -bi * __shfl(rr[i], j, 64);
                s += aij * ((c < j) ? rr[j] : 0.f);
            }
            rr[i] = (c < i) ? s : 0.f;
        }
        // T2 = (T+I) diag(beta)
        if (lane < 32) {
#pragma unroll
            for (int i = 0; i < 32; i++) {
                float val = (rr[i] + ((i == c) ? 1.f : 0.f)) * bc;
                T2b[i * KTS + c] = f2bf(val);
            }
        }
    } else {
        int idx = tid - 64;
        for (int rowc = idx; rowc < 256; rowc += 192) {
            unsigned short* kT = knT + ((size_t)(bh * 64 + ch) * DK + rowc) * 32;
#pragma unroll
            for (int seg = 0; seg < 4; seg++) {
                uint4 d = *(const uint4*)&kTl[rowc * KTS + seg * 8];
                *(uint4*)(kT + seg * 8) = d;
            }
        }
    }
    __syncthreads();

    // ---- phase C: u = T2@v (f32 out), wneg = -(T2@k) (bf16 out); wave w owns dk cols w*64..w*64+63
#pragma unroll
    for (int mt = 0; mt < 2; mt++) {
        bf16x8 ta = *(const bf16x8*)&T2b[(mt * 16 + r16) * KTS + quad * 8];
#pragma unroll
        for (int nt2 = 0; nt2 < 4; nt2++) {
            int nt = w * 4 + nt2;
            bf16x8 vb = *(const bf16x8*)&vTl[(nt * 16 + r16) * KTS + quad * 8];
            bf16x8 kb = *(const bf16x8*)&kTl[(nt * 16 + r16) * KTS + quad * 8];
            f32x4 uu = MFMA16(ta, vb, z4);
            f32x4 ww = MFMA16(ta, kb, z4);
            float* ug = u + (rowbase + mt * 16 + quad * 4) * DK + nt * 16 + r16;
            unsigned short* wg = wneg + (rowbase + mt * 16 + quad * 4) * DK + nt * 16 + r16;
#pragma unroll
            for (int r = 0; r < 4; r++) {
                ug[(size_t)r * DK] = uu[r];
                wg[(size_t)r * DK] = f2bf(-ww[r]);
            }
        }
    }
}

// ---------------- K8a: EMA local scan ----------------
__global__ __launch_bounds__(256) void k_ema_local(const float* v, const float* gamma,
                                                   float* ema_local, float* Acum,
                                                   float* s_end, float* Pchunk)
{
    __shared__ float gsh[ET];
    int blk = blockIdx.x;
    int bh = blk >> 5;
    int ch = blk & (ENCH - 1);
    int b = bh >> 2, h = bh & 3;
    int c = threadIdx.x;
    int t0 = ch * ET;
    if (c < ET) gsh[c] = gamma[(size_t)(b * L + t0 + c) * NH + h];
    __syncthreads();
    const float* vg = v + (size_t)(b * L + t0) * D + h * DK + c;
    float* eg = ema_local + (size_t)(b * L + t0) * D + h * DK + c;
    float* Ag = Acum + (size_t)bh * L + t0;
    float s = 0.f;
    float A = 1.f;
#pragma unroll 8
    for (int i = 0; i < ET; i++) {
        float g = gsh[i];
        s = g * s + (1.f - g) * vg[(size_t)i * D];
        A *= g;
        eg[(size_t)i * D] = s;
        if (c == 0) Ag[i] = A;
    }
    s_end[((size_t)bh * ENCH + ch) * DK + c] = s;
    if (c == 0) Pchunk[(size_t)bh * ENCH + ch] = A;
}

// ---------------- K8b: EMA carry scan ----------------
__global__ __launch_bounds__(256) void k_ema_carry(const float* s_end, const float* Pchunk, float* S_in)
{
    int bh = blockIdx.x;
    int c = threadIdx.x;
    float S = 0.f;
    for (int ch = 0; ch < ENCH; ch++) {
        S_in[((size_t)bh * ENCH + ch) * DK + c] = S;
        float P = Pchunk[(size_t)bh * ENCH + ch];
        S = P * S + s_end[((size_t)bh * ENCH + ch) * DK + c];
    }
}

// ---------------- K9: sequential inter-chunk scan ----------------
#define STS 280   // st row stride in shorts (dword stride 140 = 12 mod 32 -> ~2-way)
#define USTR 40   // uat row stride in shorts (2-way only)
__global__ __launch_bounds__(128, 1) void k_scan(const unsigned short* qn, const unsigned short* wneg,
                                                 const unsigned short* knT, const unsigned short* attnb,
                                                 const float* u, float* od)
{
    __shared__ __align__(16) unsigned short st[16 * STS];   // S^T bf16: [c][dk]
    __shared__ __align__(16) unsigned short uat[16 * USTR]; // u_adj^T bf16: [c][t]
    int bh = blockIdx.x;
    int tile = blockIdx.y;      // 0..15, 16 cols each
    int b = bh >> 2, h = bh & 3;
    int mo = threadIdx.x >> 6, lane = threadIdx.x & 63;
    int r16 = lane & 15, quad = lane >> 4;
    int cbase = tile * 16;
    f32x4 z4 = {0.f, 0.f, 0.f, 0.f};
    f32x4 sacc[8];
#pragma unroll
    for (int a = 0; a < 8; a++) sacc[a] = z4;
    const unsigned short* qb = qn + (size_t)bh * L * DK;
    const unsigned short* wb = wneg + (size_t)bh * L * DK;
    const float* ub = u + (size_t)bh * L * DK;
    const unsigned short* kTbase = knT + (size_t)bh * 64 * DK * 32;
    const unsigned short* atbase = attnb + (size_t)bh * 64 * 1024;
    int dkb = mo * 128;   // this wave's S^T row base

    bf16x8 qf[2][8], wf[2][8];
    f32x4 au0[2];

    auto issue = [&](int ch, int par) {
        int t0 = ch * 32;
        const unsigned short* wrow = wb + (size_t)(t0 + 16 * mo + r16) * DK;
        const unsigned short* qrow = qb + (size_t)(t0 + 16 * mo + r16) * DK;
#pragma unroll
        for (int kt = 0; kt < 8; kt++) {
            qf[par][kt] = *(const bf16x8*)(qrow + kt * 32 + quad * 8);
            wf[par][kt] = *(const bf16x8*)(wrow + kt * 32 + quad * 8);
        }
        const float* up = ub + (size_t)(t0 + 16 * mo + quad * 4) * DK + cbase + r16;
        f32x4 a; a[0] = up[0]; a[1] = up[DK]; a[2] = up[2 * DK]; a[3] = up[3 * DK];
        au0[par] = a;
    };

    issue(0, 0);

    auto body = [&](int ch, int par) {
        int t0 = ch * 32;
#pragma unroll
        for (int a = 0; a < 8; a++) {
            uint2 p;
            p.x = f2bf(sacc[a][0]) | ((unsigned)f2bf(sacc[a][1]) << 16);
            p.y = f2bf(sacc[a][2]) | ((unsigned)f2bf(sacc[a][3]) << 16);
            *(uint2*)&st[r16 * STS + dkb + a * 16 + quad * 4] = p;
        }
        if (ch + 1 < NCH) issue(ch + 1, par ^ 1);
        bar_lds();

        bf16x8 af = *(const bf16x8*)(atbase + (size_t)ch * 1024 + (16 * mo + r16) * 32 + quad * 8);
        const unsigned short* kTb = kTbase + (size_t)ch * DK * 32;
        bf16x8 kf[8];
#pragma unroll
        for (int a = 0; a < 8; a++)
            kf[a] = *(const bf16x8*)(kTb + (size_t)(dkb + a * 16 + r16) * 32 + quad * 8);

        f32x4 au = au0[par], ao = z4;
#pragma unroll
        for (int kt = 0; kt < 8; kt++) {
            bf16x8 sfr = *(const bf16x8*)&st[r16 * STS + kt * 32 + quad * 8];
            au = MFMA16(wf[par][kt], sfr, au);
            ao = MFMA16(qf[par][kt], sfr, ao);
        }
        {
            uint2 p;
            p.x = f2bf(au[0]) | ((unsigned)f2bf(au[1]) << 16);
            p.y = f2bf(au[2]) | ((unsigned)f2bf(au[3]) << 16);
            *(uint2*)&uat[r16 * USTR + 16 * mo + quad * 4] = p;
        }
        bar_lds();

        {
            bf16x8 uf = *(const bf16x8*)&uat[r16 * USTR + quad * 8];
            ao = MFMA16(af, uf, ao);
            float* op = od + (size_t)(b * L + t0 + 16 * mo + quad * 4) * D + h * DK + cbase + r16;
            op[0] = ao[0]; op[D] = ao[1]; op[2 * D] = ao[2]; op[3 * D] = ao[3];
#pragma unroll
            for (int a = 0; a < 8; a++)
                sacc[a] = MFMA16(kf[a], uf, sacc[a]);
        }
    };

    for (int ch2 = 0; ch2 < NCH; ch2 += 2) {
        body(ch2, 0);
        body(ch2 + 1, 1);
    }
}

// ---------------- K10: mix + EMA fix-up + per-head RMS norm -> bf16 ----------------
__global__ __launch_bounds__(256) void k_mixrms(const float* od, const float* ema_local,
                                                const float* Acum, const float* S_in,
                                                const float* mixinp,
                                                const float* mix_bias, const float* rms_w,
                                                unsigned short* onorm)
{
    int row = blockIdx.x;       // b*L + t
    int tid = threadIdx.x;
    int h = tid >> 6, lane = tid & 63;
    int b = row >> 11, t = row & (L - 1);
    int bh = b * NH + h;
    int ch = t >> 6;            // ET = 64
    float m = sigmoidf_(mixinp[(size_t)row * NH + h] + mix_bias[h]);
    int c = tid * 4;
    float A = Acum[(size_t)bh * L + t];
    float4 sin4 = *(const float4*)(S_in + ((size_t)bh * ENCH + ch) * DK + (c & (DK - 1)));
    float4 o = *(const float4*)(od + (size_t)row * D + c);
    float4 e = *(const float4*)(ema_local + (size_t)row * D + c);
    e.x += A * sin4.x; e.y += A * sin4.y; e.z += A * sin4.z; e.w += A * sin4.w;
    float x0 = o.x + m * (e.x - o.x);
    float x1 = o.y + m * (e.y - o.y);
    float x2 = o.z + m * (e.z - o.z);
    float x3 = o.w + m * (e.w - o.w);
    float ss = x0 * x0 + x1 * x1 + x2 * x2 + x3 * x3;
    for (int off = 32; off; off >>= 1) ss += __shfl_xor(ss, off, 64);
    float scale = rsqrtf(ss * (1.0f / 256.0f) + 1e-5f);
    float4 w = *(const float4*)(rms_w + lane * 4);
    uint2 p;
    p.x = f2bf(x0 * scale * w.x) | ((unsigned)f2bf(x1 * scale * w.y) << 16);
    p.y = f2bf(x2 * scale * w.z) | ((unsigned)f2bf(x3 * scale * w.w) << 16);
    *(uint2*)(onorm + (size_t)row * D + c) = p;
}

extern "C" void kernel_launch(void* const* d_in, const int* in_sizes, int n_in,
                              void* d_out, int out_size, void* d_ws, size_t ws_size,
                              hipStream_t stream)
{
    (void)in_sizes; (void)n_in; (void)out_size; (void)ws_size;
    const float* hidden   = (const float*)d_in[0];
    const float* Wq       = (const float*)d_in[1];
    const float* Wk       = (const float*)d_in[2];
    const float* Wv       = (const float*)d_in[3];
    const float* conv_q   = (const float*)d_in[4];
    const float* conv_k   = (const float*)d_in[5];
    const float* conv_v   = (const float*)d_in[6];
    const float* Wb       = (const float*)d_in[7];
    const float* Wdec     = (const float*)d_in[8];
    const float* Wmix     = (const float*)d_in[9];
    const float* conv_mix = (const float*)d_in[10];
    const float* mix_bias = (const float*)d_in[11];
    const float* rms_w    = (const float*)d_in[12];
    const float* Wo       = (const float*)d_in[13];
    float* out = (float*)d_out;

    char* ws = (char*)d_ws;
    size_t off = 0;
    auto alloc = [&](size_t bytes) -> char* {
        char* p = ws + off;
        off += (bytes + 255) & ~(size_t)255;
        return p;
    };
    unsigned short* wT    = (unsigned short*)alloc((size_t)4 * D * D * 2);
    unsigned short* hidB  = (unsigned short*)alloc((size_t)B * L * D * 2);
    unsigned short* xqkv  = (unsigned short*)alloc((size_t)B * L * 3 * D * 2); // later qn/wneg/knT
    float* beta   = (float*)alloc((size_t)B * L * NH * 4);
    float* gamma  = (float*)alloc((size_t)B * L * NH * 4);
    float* xmix   = (float*)alloc((size_t)B * L * NH * 4);
    float* mixinp = (float*)alloc((size_t)B * L * NH * 4);
    float* qbuf   = (float*)alloc((size_t)B * L * D * 4);   // later ema_local
    float* kbuf   = (float*)alloc((size_t)B * L * D * 4);   // later od
    float* vbuf   = (float*)alloc((size_t)B * L * D * 4);
    float* u      = (float*)alloc((size_t)B * L * D * 4);
    unsigned short* attnb = (unsigned short*)alloc((size_t)BH * NCH * CHUNK * CHUNK * 2);
    unsigned short* onorm = (unsigned short*)alloc((size_t)B * L * D * 2);
    unsigned short* kn    = (unsigned short*)alloc((size_t)B * L * D * 2);
    float* Acum   = (float*)alloc((size_t)BH * L * 4);
    float* s_end  = (float*)alloc((size_t)BH * ENCH * DK * 4);
    float* Pchunk = (float*)alloc((size_t)BH * ENCH * 4);
    float* S_in   = (float*)alloc((size_t)BH * ENCH * DK * 4);

    unsigned short* qn   = xqkv;
    unsigned short* wneg = xqkv + (size_t)B * L * D;
    unsigned short* knT  = xqkv + (size_t)2 * B * L * D;
    float* ema_local = qbuf;
    float* od  = kbuf;

    k_wT<<<dim3(32, 32, 4), 256, 0, stream>>>(Wq, Wk, Wv, Wo, wT);
    k_cvt<<<dim3(2048), 256, 0, stream>>>(hidden, hidB, B * L * D / 4);
    k_gemm_lds<3 * D, false><<<dim3(64, 24), 256, 0, stream>>>(hidB, wT, xqkv);
    k_smallproj<<<dim3(B * L / 4), 256, 0, stream>>>(hidden, Wb, Wdec, Wmix, beta, gamma, xmix);
    k_conv<<<dim3(B * L * D / 256, 1, 3), 256, 0, stream>>>(xqkv, conv_q, conv_k, conv_v,
                                                            qbuf, kbuf, vbuf);
    k_convmix<<<dim3(B * L * NH / 256), 256, 0, stream>>>(xmix, conv_mix, mixinp);
    k_l2norm<<<dim3(BH * L / 4), 256, 0, stream>>>(qbuf, kbuf, qn, kn);
    k_delta_pre<<<dim3(BH * NCH), 256, 0, stream>>>(qn, kn, vbuf, beta, wneg, knT, attnb, u);
    k_ema_local<<<dim3(BH * ENCH), 256, 0, stream>>>(vbuf, gamma, ema_local, Acum, s_end, Pchunk);
    k_ema_carry<<<dim3(BH), 256, 0, stream>>>(s_end, Pchunk, S_in);
    k_scan<<<dim3(16, 16), 128, 0, stream>>>(qn, wneg, knT, attnb, u, od);
    k_mixrms<<<dim3(B * L), 256, 0, stream>>>(od, ema_local, Acum, S_in, mixinp, mix_bias, rms_w, onorm);
    k_gemm_lds<D, true><<<dim3(64, 8), 256, 0, stream>>>(onorm, wT + (size_t)3 * D * D, out);
}

// Round 8
// 517.003 us; speedup vs baseline: 3.0368x; 1.0338x over previous
//
#include <hip/hip_runtime.h>
#include <hip/hip_bf16.h>

#define B 4
#define L 2048
#define D 1024
#define NH 4
#define DK 256
#define CHUNK 32
#define NCH 64
#define BH (B*NH)
// EMA chunking
#define ET 64
#define ENCH (L/ET)

typedef __attribute__((ext_vector_type(8))) __bf16 bf16x8;
typedef __attribute__((ext_vector_type(4))) __bf16 bf16x4;
typedef __attribute__((ext_vector_type(4))) float f32x4;

__device__ inline unsigned short f2bf(float f) {
    union { float f; unsigned u; } v; v.f = f;
    unsigned r = v.u + 0x7fffu + ((v.u >> 16) & 1u);
    return (unsigned short)(r >> 16);
}
__device__ inline float bf2f(unsigned short h) {
    union { unsigned u; float f; } v; v.u = ((unsigned)h) << 16; return v.f;
}
__device__ inline float sigmoidf_(float x) { return 1.0f / (1.0f + __expf(-x)); }
__device__ inline float siluf_(float x) { return x / (1.0f + __expf(-x)); }

#define MFMA16(a, b, c) __builtin_amdgcn_mfma_f32_16x16x32_bf16((a), (b), (c), 0, 0, 0)

// raw barrier: wait only LDS (lgkmcnt(0)), leave global loads in flight.
// 0xC07F = vmcnt(63) expcnt(7) lgkmcnt(0)
__device__ inline void bar_lds() {
    __builtin_amdgcn_s_waitcnt(0xC07F);
    __builtin_amdgcn_s_barrier();
}

// async global->LDS, 16B per lane; lds dest = wave-uniform base + lane*16
__device__ inline void load_lds16(const unsigned short* g, unsigned short* l) {
    __builtin_amdgcn_global_load_lds(
        (const __attribute__((address_space(1))) unsigned int*)g,
        (__attribute__((address_space(3))) unsigned int*)l, 16, 0, 0);
}

// ---------------- K1: transpose+convert weights: W (K,N) f32 -> WT (N,K) bf16 ----------------
__global__ __launch_bounds__(256) void k_wT(const float* Wq, const float* Wk, const float* Wv,
                                            const float* Wo, unsigned short* wT)
{
    __shared__ float tile[32][33];
    int z = blockIdx.z;
    const float* W = (z == 0) ? Wq : (z == 1) ? Wk : (z == 2) ? Wv : Wo;
    unsigned short* out = wT + (size_t)z * D * D;
    int kt = blockIdx.x * 32, nt = blockIdx.y * 32;
    int tx = threadIdx.x & 31, ty = threadIdx.x >> 5;
#pragma unroll
    for (int i = 0; i < 4; i++)
        tile[ty + 8 * i][tx] = W[(size_t)(kt + ty + 8 * i) * D + nt + tx];
    __syncthreads();
#pragma unroll
    for (int i = 0; i < 4; i++)
        out[(size_t)(nt + ty + 8 * i) * D + kt + tx] = f2bf(tile[tx][ty + 8 * i]);
}

// ---------------- K2: hidden f32 -> bf16 ----------------
__global__ __launch_bounds__(256) void k_cvt(const float* h, unsigned short* hb, int n4)
{
    int i = blockIdx.x * blockDim.x + threadIdx.x;
    int stride = gridDim.x * blockDim.x;
    const float4* h4 = (const float4*)h;
    for (; i < n4; i += stride) {
        float4 v = h4[i];
        ushort4 o;
        o.x = f2bf(v.x); o.y = f2bf(v.y); o.z = f2bf(v.z); o.w = f2bf(v.w);
        *(ushort4*)(hb + 4 * (size_t)i) = o;
    }
}

// ---------------- K3: LDS-staged 128x128 GEMM (m97 structure) ----------------
template<int NTOT, bool OUT_F32>
__global__ __launch_bounds__(256) void k_gemm_lds(const unsigned short* __restrict__ A,
                                                  const unsigned short* __restrict__ BT,
                                                  void* __restrict__ outp)
{
    __shared__ __align__(16) unsigned short As[128 * 32];   // 8 KB
    __shared__ __align__(16) unsigned short Bs[128 * 32];   // 8 KB
    const int K = 1024;
    int tid = threadIdx.x;
    int w = tid >> 6, lane = tid & 63;
    int r16 = lane & 15, quad = lane >> 4;
    int wm = w & 1, wn = w >> 1;
    int bm = blockIdx.x * 128;
    int bn = blockIdx.y * 128;
    int lrow = lane >> 2;            // 0..15
    int lcol = (lane & 3) * 8;       // element col within 32
    f32x4 z4 = {0.f, 0.f, 0.f, 0.f};
    f32x4 acc[4][4];
#pragma unroll
    for (int i = 0; i < 4; i++)
#pragma unroll
        for (int j = 0; j < 4; j++) acc[i][j] = z4;

    for (int kt = 0; kt < K; kt += 32) {
#pragma unroll
        for (int j = 0; j < 2; j++) {
            int r0 = (w * 2 + j) * 16;
            load_lds16(A + (size_t)(bm + r0 + lrow) * K + kt + lcol, &As[r0 * 32]);
            load_lds16(BT + (size_t)(bn + r0 + lrow) * K + kt + lcol, &Bs[r0 * 32]);
        }
        __syncthreads();
        bf16x8 af[4], bf[4];
#pragma unroll
        for (int ms = 0; ms < 4; ms++)
            af[ms] = *(const bf16x8*)&As[(wm * 64 + ms * 16 + r16) * 32 + quad * 8];
#pragma unroll
        for (int ns = 0; ns < 4; ns++)
            bf[ns] = *(const bf16x8*)&Bs[(wn * 64 + ns * 16 + r16) * 32 + quad * 8];
#pragma unroll
        for (int ms = 0; ms < 4; ms++)
#pragma unroll
            for (int ns = 0; ns < 4; ns++)
                acc[ms][ns] = MFMA16(af[ms], bf[ns], acc[ms][ns]);
        __syncthreads();
    }
#pragma unroll
    for (int ms = 0; ms < 4; ms++)
#pragma unroll
        for (int ns = 0; ns < 4; ns++)
#pragma unroll
            for (int r = 0; r < 4; r++) {
                int m = bm + wm * 64 + ms * 16 + quad * 4 + r;
                int n = bn + wn * 64 + ns * 16 + r16;
                if (OUT_F32)
                    ((float*)outp)[(size_t)m * NTOT + n] = acc[ms][ns][r];
                else
                    ((unsigned short*)outp)[(size_t)m * NTOT + n] = f2bf(acc[ms][ns][r]);
            }
}

// ---------------- K4: small projections ----------------
__global__ __launch_bounds__(256) void k_smallproj(const float* hid, const float* Wb, const float* Wd,
                                                   const float* Wm, float* beta, float* gamma, float* xmix)
{
    int wave = threadIdx.x >> 6, lane = threadIdx.x & 63;
    int row = blockIdx.x * 4 + wave;
    const float* hrow = hid + (size_t)row * D;
    float acc[12];
#pragma unroll
    for (int j = 0; j < 12; j++) acc[j] = 0.f;
    for (int i = 0; i < 16; i++) {
        int k = lane + 64 * i;
        float h = hrow[k];
        float4 wb = ((const float4*)Wb)[k];
        float4 wd = ((const float4*)Wd)[k];
        float4 wm = ((const float4*)Wm)[k];
        acc[0] += h * wb.x; acc[1] += h * wb.y; acc[2] += h * wb.z; acc[3] += h * wb.w;
        acc[4] += h * wd.x; acc[5] += h * wd.y; acc[6] += h * wd.z; acc[7] += h * wd.w;
        acc[8] += h * wm.x; acc[9] += h * wm.y; acc[10] += h * wm.z; acc[11] += h * wm.w;
    }
#pragma unroll
    for (int j = 0; j < 12; j++)
        for (int off = 32; off; off >>= 1) acc[j] += __shfl_xor(acc[j], off, 64);
    if (lane < 4) {
        beta[(size_t)row * 4 + lane] = sigmoidf_(acc[lane]);
        gamma[(size_t)row * 4 + lane] = sigmoidf_(acc[4 + lane]);
        xmix[(size_t)row * 4 + lane] = acc[8 + lane];
    }
}

// ---------------- K5: short conv + silu ----------------
__global__ __launch_bounds__(256) void k_conv(const unsigned short* xqkv,
                                              const float* cq, const float* ck, const float* cv,
                                              float* q, float* k, float* v)
{
    int z = blockIdx.z;
    const float* cw = (z == 0) ? cq : (z == 1) ? ck : cv;
    float* dst = (z == 0) ? q : (z == 1) ? k : v;
    int idx = blockIdx.x * 256 + threadIdx.x;
    int c = idx & (D - 1);
    int t = (idx >> 10) & (L - 1);
    int b = idx >> 21;
    float4 w4 = *(const float4*)(cw + (size_t)c * 4);
    float wv[4] = {w4.x, w4.y, w4.z, w4.w};
    size_t base = ((size_t)(b * L)) * (3 * D) + z * D + c;
    float acc = 0.f;
#pragma unroll
    for (int kk = 0; kk < 4; kk++) {
        int tt = t - 3 + kk;
        if (tt >= 0) acc += wv[kk] * bf2f(xqkv[base + (size_t)tt * (3 * D)]);
    }
    float r = siluf_(acc);
    if (z < 2) r = siluf_(r);
    dst[idx] = r;
}

// ---------------- K6: mix conv + silu ----------------
__global__ __launch_bounds__(256) void k_convmix(const float* xmix, const float* cmix, float* mixinp)
{
    int idx = blockIdx.x * 256 + threadIdx.x;   // < B*L*NH
    int h = idx & 3;
    int t = (idx >> 2) & (L - 1);
    int b = idx >> 13;
    float acc = 0.f;
#pragma unroll
    for (int kk = 0; kk < 4; kk++) {
        int tt = t - 3 + kk;
        if (tt >= 0) acc += cmix[h * 4 + kk] * xmix[((size_t)(b * L + tt) << 2) + h];
    }
    mixinp[idx] = siluf_(acc);
}

// ---------------- K7a: l2norm q,k -> bf16 ----------------
__global__ __launch_bounds__(256) void k_l2norm(const float* qbuf, const float* kbuf,
                                                unsigned short* qn, unsigned short* kn)
{
    int wave = threadIdx.x >> 6, lane = threadIdx.x & 63;
    int rid = blockIdx.x * 4 + wave;      // 0..BH*L-1
    int bh = rid >> 11, t = rid & (L - 1);
    int b = bh >> 2, h = bh & 3;
    size_t src = (size_t)(b * L + t) * D + h * DK + lane * 4;
    float4 q4 = *(const float4*)(qbuf + src);
    float4 k4 = *(const float4*)(kbuf + src);
    float sq = q4.x * q4.x + q4.y * q4.y + q4.z * q4.z + q4.w * q4.w;
    float sk = k4.x * k4.x + k4.y * k4.y + k4.z * k4.z + k4.w * k4.w;
    for (int off = 32; off; off >>= 1) { sq += __shfl_xor(sq, off, 64); sk += __shfl_xor(sk, off, 64); }
    float qsc = rsqrtf(sq + 1e-6f);
    float ksc = rsqrtf(sk + 1e-6f);
    uint2 pq, pk;
    pq.x = f2bf(q4.x * qsc) | ((unsigned)f2bf(q4.y * qsc) << 16);
    pq.y = f2bf(q4.z * qsc) | ((unsigned)f2bf(q4.w * qsc) << 16);
    pk.x = f2bf(k4.x * ksc) | ((unsigned)f2bf(k4.y * ksc) << 16);
    pk.y = f2bf(k4.z * ksc) | ((unsigned)f2bf(k4.w * ksc) << 16);
    *(uint2*)(qn + (size_t)rid * DK + lane * 4) = pq;
    *(uint2*)(kn + (size_t)rid * DK + lane * 4) = pk;
}

// ---------------- K7b: per-(bh,chunk) delta-rule precompute (MFMA version) ----------------
#define KTS 40   // LDS row stride in shorts: 80B (16B-aligned), dword stride 20 -> 2-way banks (free)
__global__ __launch_bounds__(256) void k_delta_pre(const unsigned short* qn, const unsigned short* kn,
                                                   const float* vbuf, const float* beta,
                                                   unsigned short* wneg, unsigned short* knT,
                                                   unsigned short* attnb, float* u)
{
    __shared__ __align__(16) unsigned short kTl[256 * KTS]; // k^T bf16 [dk][t]
    __shared__ __align__(16) unsigned short vTl[256 * KTS]; // v^T bf16 [dk][t]
    __shared__ __align__(16) unsigned short T2b[32 * KTS];  // T2 bf16 [t][t']
    __shared__ float Gs[32 * 33];
    int bx = blockIdx.x;
    int bh = bx >> 6, ch = bx & 63;
    int b = bh >> 2, h = bh & 3;
    int t0 = ch * 32;
    int tid = threadIdx.x;
    int w = tid >> 6, lane = tid & 63;
    int r16 = lane & 15, quad = lane >> 4;
    size_t rowbase = (size_t)(bh * L + t0);
    f32x4 z4 = {0.f, 0.f, 0.f, 0.f};

    // ---- phase A: MFMA G/QK tiles
    if (w < 3) {
        int mi = (w == 0) ? 0 : 1;
        int ni = (w == 2) ? 1 : 0;
        const unsigned short* krm = kn + (rowbase + mi * 16 + r16) * DK;
        const unsigned short* krn = kn + (rowbase + ni * 16 + r16) * DK;
        const unsigned short* qrm = qn + (rowbase + mi * 16 + r16) * DK;
        f32x4 g = z4, qk = z4;
#pragma unroll
        for (int kt = 0; kt < 8; kt++) {
            bf16x8 a  = *(const bf16x8*)(krm + kt * 32 + quad * 8);
            bf16x8 bb = *(const bf16x8*)(krn + kt * 32 + quad * 8);
            bf16x8 qa = *(const bf16x8*)(qrm + kt * 32 + quad * 8);
            g  = MFMA16(a, bb, g);
            qk = MFMA16(qa, bb, qk);
        }
#pragma unroll
        for (int r = 0; r < 4; r++) {
            int i = mi * 16 + quad * 4 + r, j = ni * 16 + r16;
            Gs[i * 33 + j] = g[r];
            attnb[(size_t)(bh * 64 + ch) * 1024 + i * 32 + j] =
                (j <= i) ? f2bf(qk[r]) : (unsigned short)0;
        }
    } else {
        // strictly-upper QK tile (0,1) is all zero
#pragma unroll
        for (int r = 0; r < 4; r++) {
            int i = quad * 4 + r, j = 16 + r16;
            attnb[(size_t)(bh * 64 + ch) * 1024 + i * 32 + j] = 0;
        }
    }
    // ---- phase A2 (all threads): transpose k (bf16) and v (f32->bf16) into LDS
    {
        int t = tid & 31, c0 = (tid >> 5) * 32;
        const unsigned short* krow = kn + (rowbase + t) * DK + c0;
        const float* vrow = vbuf + ((size_t)(b * L + t0 + t)) * D + h * DK + c0;
#pragma unroll
        for (int j = 0; j < 32; j += 4) {
            ushort4 kv = *(const ushort4*)(krow + j);
            float4 vv = *(const float4*)(vrow + j);
            kTl[(c0 + j + 0) * KTS + t] = kv.x;
            kTl[(c0 + j + 1) * KTS + t] = kv.y;
            kTl[(c0 + j + 2) * KTS + t] = kv.z;
            kTl[(c0 + j + 3) * KTS + t] = kv.w;
            vTl[(c0 + j + 0) * KTS + t] = f2bf(vv.x);
            vTl[(c0 + j + 1) * KTS + t] = f2bf(vv.y);
            vTl[(c0 + j + 2) * KTS + t] = f2bf(vv.z);
            vTl[(c0 + j + 3) * KTS + t] = f2bf(vv.w);
        }
    }
    __syncthreads();

    // ---- phase B
    if (w == 0) {
        int c = lane & 31;
        float rr[32];
#pragma unroll
        for (int j = 0; j < 32; j++) rr[j] = Gs[j * 33 + c];
        // Row 0 of the strict-lower T is empty: must be zero.
        rr[0] = 0.f;
        float bc = beta[(size_t)(b * L + t0 + c) * NH + h];
#pragma unroll
        for (int i = 1; i < 32; i++) {
            float bi = __shfl(bc, i, 64);
            float s = -bi * rr[i];
#pragma unroll
            for (int j = 1; j < i; j++) {
                float aij = -bi * __shfl(rr[i], j, 64);
                s += aij * ((c < j) ? rr[j] : 0.f);
            }
            rr[i] = (c < i) ? s : 0.f;
        }
        if (lane < 32) {
#pragma unroll
            for (int i = 0; i < 32; i++) {
                float val = (rr[i] + ((i == c) ? 1.f : 0.f)) * bc;
                T2b[i * KTS + c] = f2bf(val);
            }
        }
    } else {
        int idx = tid - 64;
        for (int rowc = idx; rowc < 256; rowc += 192) {
            unsigned short* kT = knT + ((size_t)(bh * 64 + ch) * DK + rowc) * 32;
#pragma unroll
            for (int seg = 0; seg < 4; seg++) {
                uint4 d = *(const uint4*)&kTl[rowc * KTS + seg * 8];
                *(uint4*)(kT + seg * 8) = d;
            }
        }
    }
    __syncthreads();

    // ---- phase C: u = T2@v (f32 out), wneg = -(T2@k) (bf16 out)
#pragma unroll
    for (int mt = 0; mt < 2; mt++) {
        bf16x8 ta = *(const bf16x8*)&T2b[(mt * 16 + r16) * KTS + quad * 8];
#pragma unroll
        for (int nt2 = 0; nt2 < 4; nt2++) {
            int nt = w * 4 + nt2;
            bf16x8 vb = *(const bf16x8*)&vTl[(nt * 16 + r16) * KTS + quad * 8];
            bf16x8 kb = *(const bf16x8*)&kTl[(nt * 16 + r16) * KTS + quad * 8];
            f32x4 uu = MFMA16(ta, vb, z4);
            f32x4 ww = MFMA16(ta, kb, z4);
            float* ug = u + (rowbase + mt * 16 + quad * 4) * DK + nt * 16 + r16;
            unsigned short* wg = wneg + (rowbase + mt * 16 + quad * 4) * DK + nt * 16 + r16;
#pragma unroll
            for (int r = 0; r < 4; r++) {
                ug[(size_t)r * DK] = uu[r];
                wg[(size_t)r * DK] = f2bf(-ww[r]);
            }
        }
    }
}

// ---------------- K8a: EMA local scan ----------------
__global__ __launch_bounds__(256) void k_ema_local(const float* v, const float* gamma,
                                                   float* ema_local, float* Acum,
                                                   float* s_end, float* Pchunk)
{
    __shared__ float gsh[ET];
    int blk = blockIdx.x;
    int bh = blk >> 5;
    int ch = blk & (ENCH - 1);
    int b = bh >> 2, h = bh & 3;
    int c = threadIdx.x;
    int t0 = ch * ET;
    if (c < ET) gsh[c] = gamma[(size_t)(b * L + t0 + c) * NH + h];
    __syncthreads();
    const float* vg = v + (size_t)(b * L + t0) * D + h * DK + c;
    float* eg = ema_local + (size_t)(b * L + t0) * D + h * DK + c;
    float* Ag = Acum + (size_t)bh * L + t0;
    float s = 0.f;
    float A = 1.f;
#pragma unroll 8
    for (int i = 0; i < ET; i++) {
        float g = gsh[i];
        s = g * s + (1.f - g) * vg[(size_t)i * D];
        A *= g;
        eg[(size_t)i * D] = s;
        if (c == 0) Ag[i] = A;
    }
    s_end[((size_t)bh * ENCH + ch) * DK + c] = s;
    if (c == 0) Pchunk[(size_t)bh * ENCH + ch] = A;
}

// ---------------- K8b: EMA carry scan ----------------
__global__ __launch_bounds__(256) void k_ema_carry(const float* s_end, const float* Pchunk, float* S_in)
{
    int bh = blockIdx.x;
    int c = threadIdx.x;
    float S = 0.f;
    for (int ch = 0; ch < ENCH; ch++) {
        S_in[((size_t)bh * ENCH + ch) * DK + c] = S;
        float P = Pchunk[(size_t)bh * ENCH + ch];
        S = P * S + s_end[((size_t)bh * ENCH + ch) * DK + c];
    }
}

// ---------------- K9: sequential inter-chunk scan ----------------
// 2 waves/block, 16 dv-cols per block; grid (bh=16, tile=16) -> id%8 = bh%8 (XCD locality).
// qf/wf/au0 prefetched one full chunk ahead (parity regs); kf/af issued at body top
// (used only at step F, ~600+ cycles later). Raw lgkm-only barriers keep all global
// loads in flight across sync points.
#define STS 280   // st row stride in shorts (dword stride 140 = 12 mod 32 -> 2-way)
#define USTR 40   // uat row stride in shorts (2-way only)
__global__ __launch_bounds__(128, 1) void k_scan(const unsigned short* qn, const unsigned short* wneg,
                                                 const unsigned short* knT, const unsigned short* attnb,
                                                 const float* u, float* od)
{
    __shared__ __align__(16) unsigned short st[16 * STS];   // S^T bf16: [c][dk]
    __shared__ __align__(16) unsigned short uat[16 * USTR]; // u_adj^T bf16: [c][t]
    int bh = blockIdx.x;
    int tile = blockIdx.y;      // 0..15, 16 cols each
    int b = bh >> 2, h = bh & 3;
    int mo = threadIdx.x >> 6, lane = threadIdx.x & 63;
    int r16 = lane & 15, quad = lane >> 4;
    int cbase = tile * 16;
    f32x4 z4 = {0.f, 0.f, 0.f, 0.f};
    f32x4 sacc[8];
#pragma unroll
    for (int a = 0; a < 8; a++) sacc[a] = z4;
    const unsigned short* qb = qn + (size_t)bh * L * DK;
    const unsigned short* wb = wneg + (size_t)bh * L * DK;
    const float* ub = u + (size_t)bh * L * DK;
    const unsigned short* kTbase = knT + (size_t)bh * 64 * DK * 32;
    const unsigned short* atbase = attnb + (size_t)bh * 64 * 1024;
    int dkb = mo * 128;   // this wave's S^T row base

    bf16x8 qf[2][8], wf[2][8];
    f32x4 au0[2];

    auto issue = [&](int ch, int par) {
        int t0 = ch * 32;
        const unsigned short* wrow = wb + (size_t)(t0 + 16 * mo + r16) * DK;
        const unsigned short* qrow = qb + (size_t)(t0 + 16 * mo + r16) * DK;
#pragma unroll
        for (int kt = 0; kt < 8; kt++) {
            qf[par][kt] = *(const bf16x8*)(qrow + kt * 32 + quad * 8);
            wf[par][kt] = *(const bf16x8*)(wrow + kt * 32 + quad * 8);
        }
        const float* up = ub + (size_t)(t0 + 16 * mo + quad * 4) * DK + cbase + r16;
        f32x4 a; a[0] = up[0]; a[1] = up[DK]; a[2] = up[2 * DK]; a[3] = up[3 * DK];
        au0[par] = a;
    };

    issue(0, 0);

    auto body = [&](int ch, int par) {
        int t0 = ch * 32;
        // (0) issue current-chunk kf/af early — consumed only at (F), so the
        //     st-store + barrier + MFMA chain below covers their L2/L3 latency
        bf16x8 af = *(const bf16x8*)(atbase + (size_t)ch * 1024 + (16 * mo + r16) * 32 + quad * 8);
        const unsigned short* kTb = kTbase + (size_t)ch * DK * 32;
        bf16x8 kf[8];
#pragma unroll
        for (int a = 0; a < 8; a++)
            kf[a] = *(const bf16x8*)(kTb + (size_t)(dkb + a * 16 + r16) * 32 + quad * 8);

        // (A) write this wave's S^T slab to LDS
#pragma unroll
        for (int a = 0; a < 8; a++) {
            uint2 p;
            p.x = f2bf(sacc[a][0]) | ((unsigned)f2bf(sacc[a][1]) << 16);
            p.y = f2bf(sacc[a][2]) | ((unsigned)f2bf(sacc[a][3]) << 16);
            *(uint2*)&st[r16 * STS + dkb + a * 16 + quad * 4] = p;
        }
        // (B) prefetch next chunk's qf/wf/au0
        if (ch + 1 < NCH) issue(ch + 1, par ^ 1);
        bar_lds();

        // (C) u_adj = u - w@S ; o_partial = q@S
        f32x4 au = au0[par], ao = z4;
#pragma unroll
        for (int kt = 0; kt < 8; kt++) {
            bf16x8 sfr = *(const bf16x8*)&st[r16 * STS + kt * 32 + quad * 8];
            au = MFMA16(wf[par][kt], sfr, au);
            ao = MFMA16(qf[par][kt], sfr, ao);
        }
        // (D) write u_adj^T
        {
            uint2 p;
            p.x = f2bf(au[0]) | ((unsigned)f2bf(au[1]) << 16);
            p.y = f2bf(au[2]) | ((unsigned)f2bf(au[3]) << 16);
            *(uint2*)&uat[r16 * USTR + 16 * mo + quad * 4] = p;
        }
        bar_lds();

        // (F) o = q@S + attn@u_adj ; store ; S^T += kT @ u_adj
        {
            bf16x8 uf = *(const bf16x8*)&uat[r16 * USTR + quad * 8];
            ao = MFMA16(af, uf, ao);
            float* op = od + (size_t)(b * L + t0 + 16 * mo + quad * 4) * D + h * DK + cbase + r16;
            op[0] = ao[0]; op[D] = ao[1]; op[2 * D] = ao[2]; op[3 * D] = ao[3];
#pragma unroll
            for (int a = 0; a < 8; a++)
                sacc[a] = MFMA16(kf[a], uf, sacc[a]);
        }
    };

    for (int ch2 = 0; ch2 < NCH; ch2 += 2) {
        body(ch2, 0);
        body(ch2 + 1, 1);
    }
}

// ---------------- K10: mix + EMA fix-up + per-head RMS norm -> bf16 ----------------
__global__ __launch_bounds__(256) void k_mixrms(const float* od, const float* ema_local,
                                                const float* Acum, const float* S_in,
                                                const float* mixinp,
                                                const float* mix_bias, const float* rms_w,
                                                unsigned short* onorm)
{
    int row = blockIdx.x;       // b*L + t
    int tid = threadIdx.x;
    int h = tid >> 6, lane = tid & 63;
    int b = row >> 11, t = row & (L - 1);
    int bh = b * NH + h;
    int ch = t >> 6;            // ET = 64
    float m = sigmoidf_(mixinp[(size_t)row * NH + h] + mix_bias[h]);
    int c = tid * 4;
    float A = Acum[(size_t)bh * L + t];
    float4 sin4 = *(const float4*)(S_in + ((size_t)bh * ENCH + ch) * DK + (c & (DK - 1)));
    float4 o = *(const float4*)(od + (size_t)row * D + c);
    float4 e = *(const float4*)(ema_local + (size_t)row * D + c);
    e.x += A * sin4.x; e.y += A * sin4.y; e.z += A * sin4.z; e.w += A * sin4.w;
    float x0 = o.x + m * (e.x - o.x);
    float x1 = o.y + m * (e.y - o.y);
    float x2 = o.z + m * (e.z - o.z);
    float x3 = o.w + m * (e.w - o.w);
    float ss = x0 * x0 + x1 * x1 + x2 * x2 + x3 * x3;
    for (int off = 32; off; off >>= 1) ss += __shfl_xor(ss, off, 64);
    float scale = rsqrtf(ss * (1.0f / 256.0f) + 1e-5f);
    float4 w = *(const float4*)(rms_w + lane * 4);
    uint2 p;
    p.x = f2bf(x0 * scale * w.x) | ((unsigned)f2bf(x1 * scale * w.y) << 16);
    p.y = f2bf(x2 * scale * w.z) | ((unsigned)f2bf(x3 * scale * w.w) << 16);
    *(uint2*)(onorm + (size_t)row * D + c) = p;
}

extern "C" void kernel_launch(void* const* d_in, const int* in_sizes, int n_in,
                              void* d_out, int out_size, void* d_ws, size_t ws_size,
                              hipStream_t stream)
{
    (void)in_sizes; (void)n_in; (void)out_size; (void)ws_size;
    const float* hidden   = (const float*)d_in[0];
    const float* Wq       = (const float*)d_in[1];
    const float* Wk       = (const float*)d_in[2];
    const float* Wv       = (const float*)d_in[3];
    const float* conv_q   = (const float*)d_in[4];
    const float* conv_k   = (const float*)d_in[5];
    const float* conv_v   = (const float*)d_in[6];
    const float* Wb       = (const float*)d_in[7];
    const float* Wdec     = (const float*)d_in[8];
    const float* Wmix     = (const float*)d_in[9];
    const float* conv_mix = (const float*)d_in[10];
    const float* mix_bias = (const float*)d_in[11];
    const float* rms_w    = (const float*)d_in[12];
    const float* Wo       = (const float*)d_in[13];
    float* out = (float*)d_out;

    char* ws = (char*)d_ws;
    size_t off = 0;
    auto alloc = [&](size_t bytes) -> char* {
        char* p = ws + off;
        off += (bytes + 255) & ~(size_t)255;
        return p;
    };
    unsigned short* wT    = (unsigned short*)alloc((size_t)4 * D * D * 2);
    unsigned short* hidB  = (unsigned short*)alloc((size_t)B * L * D * 2);
    unsigned short* xqkv  = (unsigned short*)alloc((size_t)B * L * 3 * D * 2); // later qn/wneg/knT
    float* beta   = (float*)alloc((size_t)B * L * NH * 4);
    float* gamma  = (float*)alloc((size_t)B * L * NH * 4);
    float* xmix   = (float*)alloc((size_t)B * L * NH * 4);
    float* mixinp = (float*)alloc((size_t)B * L * NH * 4);
    float* qbuf   = (float*)alloc((size_t)B * L * D * 4);   // later ema_local
    float* kbuf   = (float*)alloc((size_t)B * L * D * 4);   // later od
    float* vbuf   = (float*)alloc((size_t)B * L * D * 4);
    float* u      = (float*)alloc((size_t)B * L * D * 4);
    unsigned short* attnb = (unsigned short*)alloc((size_t)BH * NCH * CHUNK * CHUNK * 2);
    unsigned short* onorm = (unsigned short*)alloc((size_t)B * L * D * 2);
    unsigned short* kn    = (unsigned short*)alloc((size_t)B * L * D * 2);
    float* Acum   = (float*)alloc((size_t)BH * L * 4);
    float* s_end  = (float*)alloc((size_t)BH * ENCH * DK * 4);
    float* Pchunk = (float*)alloc((size_t)BH * ENCH * 4);
    float* S_in   = (float*)alloc((size_t)BH * ENCH * DK * 4);

    unsigned short* qn   = xqkv;
    unsigned short* wneg = xqkv + (size_t)B * L * D;
    unsigned short* knT  = xqkv + (size_t)2 * B * L * D;
    float* ema_local = qbuf;
    float* od  = kbuf;

    k_wT<<<dim3(32, 32, 4), 256, 0, stream>>>(Wq, Wk, Wv, Wo, wT);
    k_cvt<<<dim3(2048), 256, 0, stream>>>(hidden, hidB, B * L * D / 4);
    k_gemm_lds<3 * D, false><<<dim3(64, 24), 256, 0, stream>>>(hidB, wT, xqkv);
    k_smallproj<<<dim3(B * L / 4), 256, 0, stream>>>(hidden, Wb, Wdec, Wmix, beta, gamma, xmix);
    k_conv<<<dim3(B * L * D / 256, 1, 3), 256, 0, stream>>>(xqkv, conv_q, conv_k, conv_v,
                                                            qbuf, kbuf, vbuf);
    k_convmix<<<dim3(B * L * NH / 256), 256, 0, stream>>>(xmix, conv_mix, mixinp);
    k_l2norm<<<dim3(BH * L / 4), 256, 0, stream>>>(qbuf, kbuf, qn, kn);
    k_delta_pre<<<dim3(BH * NCH), 256, 0, stream>>>(qn, kn, vbuf, beta, wneg, knT, attnb, u);
    k_ema_local<<<dim3(BH * ENCH), 256, 0, stream>>>(vbuf, gamma, ema_local, Acum, s_end, Pchunk);
    k_ema_carry<<<dim3(BH), 256, 0, stream>>>(s_end, Pchunk, S_in);
    k_scan<<<dim3(16, 16), 128, 0, stream>>>(qn, wneg, knT, attnb, u, od);
    k_mixrms<<<dim3(B * L), 256, 0, stream>>>(od, ema_local, Acum, S_in, mixinp, mix_bias, rms_w, onorm);
    k_gemm_lds<D, true><<<dim3(64, 8), 256, 0, stream>>>(onorm, wT + (size_t)3 * D * D, out);
}

// Round 9
// 496.507 us; speedup vs baseline: 3.1621x; 1.0413x over previous
//
#include <hip/hip_runtime.h>
#include <hip/hip_bf16.h>

#define B 4
#define L 2048
#define D 1024
#define NH 4
#define DK 256
#define CHUNK 32
#define NCH 64
#define BH (B*NH)
// EMA chunking
#define ET 64
#define ENCH (L/ET)

typedef __attribute__((ext_vector_type(8))) __bf16 bf16x8;
typedef __attribute__((ext_vector_type(4))) __bf16 bf16x4;
typedef __attribute__((ext_vector_type(4))) float f32x4;

__device__ inline unsigned short f2bf(float f) {
    union { float f; unsigned u; } v; v.f = f;
    unsigned r = v.u + 0x7fffu + ((v.u >> 16) & 1u);
    return (unsigned short)(r >> 16);
}
__device__ inline float bf2f(unsigned short h) {
    union { unsigned u; float f; } v; v.u = ((unsigned)h) << 16; return v.f;
}
__device__ inline float sigmoidf_(float x) { return 1.0f / (1.0f + __expf(-x)); }
__device__ inline float siluf_(float x) { return x / (1.0f + __expf(-x)); }

#define MFMA16(a, b, c) __builtin_amdgcn_mfma_f32_16x16x32_bf16((a), (b), (c), 0, 0, 0)

// raw barrier: wait only LDS (lgkmcnt(0)), leave global loads in flight.
// 0xC07F = vmcnt(63) expcnt(7) lgkmcnt(0)
__device__ inline void bar_lds() {
    __builtin_amdgcn_s_waitcnt(0xC07F);
    __builtin_amdgcn_s_barrier();
}

// async global->LDS, 16B per lane; lds dest = wave-uniform base + lane*16
__device__ inline void load_lds16(const unsigned short* g, unsigned short* l) {
    __builtin_amdgcn_global_load_lds(
        (const __attribute__((address_space(1))) unsigned int*)g,
        (__attribute__((address_space(3))) unsigned int*)l, 16, 0, 0);
}

// ---------------- K1: transpose+convert weights: W (K,N) f32 -> WT (N,K) bf16 ----------------
__global__ __launch_bounds__(256) void k_wT(const float* Wq, const float* Wk, const float* Wv,
                                            const float* Wo, unsigned short* wT)
{
    __shared__ float tile[32][33];
    int z = blockIdx.z;
    const float* W = (z == 0) ? Wq : (z == 1) ? Wk : (z == 2) ? Wv : Wo;
    unsigned short* out = wT + (size_t)z * D * D;
    int kt = blockIdx.x * 32, nt = blockIdx.y * 32;
    int tx = threadIdx.x & 31, ty = threadIdx.x >> 5;
#pragma unroll
    for (int i = 0; i < 4; i++)
        tile[ty + 8 * i][tx] = W[(size_t)(kt + ty + 8 * i) * D + nt + tx];
    __syncthreads();
#pragma unroll
    for (int i = 0; i < 4; i++)
        out[(size_t)(nt + ty + 8 * i) * D + kt + tx] = f2bf(tile[tx][ty + 8 * i]);
}

// ---------------- K2: hidden f32 -> bf16 ----------------
__global__ __launch_bounds__(256) void k_cvt(const float* h, unsigned short* hb, int n4)
{
    int i = blockIdx.x * blockDim.x + threadIdx.x;
    int stride = gridDim.x * blockDim.x;
    const float4* h4 = (const float4*)h;
    for (; i < n4; i += stride) {
        float4 v = h4[i];
        ushort4 o;
        o.x = f2bf(v.x); o.y = f2bf(v.y); o.z = f2bf(v.z); o.w = f2bf(v.w);
        *(ushort4*)(hb + 4 * (size_t)i) = o;
    }
}

// ---------------- K3: LDS-staged 128x128 GEMM (m97 structure) ----------------
template<int NTOT, bool OUT_F32>
__global__ __launch_bounds__(256) void k_gemm_lds(const unsigned short* __restrict__ A,
                                                  const unsigned short* __restrict__ BT,
                                                  void* __restrict__ outp)
{
    __shared__ __align__(16) unsigned short As[128 * 32];   // 8 KB
    __shared__ __align__(16) unsigned short Bs[128 * 32];   // 8 KB
    const int K = 1024;
    int tid = threadIdx.x;
    int w = tid >> 6, lane = tid & 63;
    int r16 = lane & 15, quad = lane >> 4;
    int wm = w & 1, wn = w >> 1;
    int bm = blockIdx.x * 128;
    int bn = blockIdx.y * 128;
    int lrow = lane >> 2;            // 0..15
    int lcol = (lane & 3) * 8;       // element col within 32
    f32x4 z4 = {0.f, 0.f, 0.f, 0.f};
    f32x4 acc[4][4];
#pragma unroll
    for (int i = 0; i < 4; i++)
#pragma unroll
        for (int j = 0; j < 4; j++) acc[i][j] = z4;

    for (int kt = 0; kt < K; kt += 32) {
#pragma unroll
        for (int j = 0; j < 2; j++) {
            int r0 = (w * 2 + j) * 16;
            load_lds16(A + (size_t)(bm + r0 + lrow) * K + kt + lcol, &As[r0 * 32]);
            load_lds16(BT + (size_t)(bn + r0 + lrow) * K + kt + lcol, &Bs[r0 * 32]);
        }
        __syncthreads();
        bf16x8 af[4], bf[4];
#pragma unroll
        for (int ms = 0; ms < 4; ms++)
            af[ms] = *(const bf16x8*)&As[(wm * 64 + ms * 16 + r16) * 32 + quad * 8];
#pragma unroll
        for (int ns = 0; ns < 4; ns++)
            bf[ns] = *(const bf16x8*)&Bs[(wn * 64 + ns * 16 + r16) * 32 + quad * 8];
#pragma unroll
        for (int ms = 0; ms < 4; ms++)
#pragma unroll
            for (int ns = 0; ns < 4; ns++)
                acc[ms][ns] = MFMA16(af[ms], bf[ns], acc[ms][ns]);
        __syncthreads();
    }
#pragma unroll
    for (int ms = 0; ms < 4; ms++)
#pragma unroll
        for (int ns = 0; ns < 4; ns++)
#pragma unroll
            for (int r = 0; r < 4; r++) {
                int m = bm + wm * 64 + ms * 16 + quad * 4 + r;
                int n = bn + wn * 64 + ns * 16 + r16;
                if (OUT_F32)
                    ((float*)outp)[(size_t)m * NTOT + n] = acc[ms][ns][r];
                else
                    ((unsigned short*)outp)[(size_t)m * NTOT + n] = f2bf(acc[ms][ns][r]);
            }
}

// ---------------- K4: small projections ----------------
__global__ __launch_bounds__(256) void k_smallproj(const float* hid, const float* Wb, const float* Wd,
                                                   const float* Wm, float* beta, float* gamma, float* xmix)
{
    int wave = threadIdx.x >> 6, lane = threadIdx.x & 63;
    int row = blockIdx.x * 4 + wave;
    const float* hrow = hid + (size_t)row * D;
    float acc[12];
#pragma unroll
    for (int j = 0; j < 12; j++) acc[j] = 0.f;
    for (int i = 0; i < 16; i++) {
        int k = lane + 64 * i;
        float h = hrow[k];
        float4 wb = ((const float4*)Wb)[k];
        float4 wd = ((const float4*)Wd)[k];
        float4 wm = ((const float4*)Wm)[k];
        acc[0] += h * wb.x; acc[1] += h * wb.y; acc[2] += h * wb.z; acc[3] += h * wb.w;
        acc[4] += h * wd.x; acc[5] += h * wd.y; acc[6] += h * wd.z; acc[7] += h * wd.w;
        acc[8] += h * wm.x; acc[9] += h * wm.y; acc[10] += h * wm.z; acc[11] += h * wm.w;
    }
#pragma unroll
    for (int j = 0; j < 12; j++)
        for (int off = 32; off; off >>= 1) acc[j] += __shfl_xor(acc[j], off, 64);
    if (lane < 4) {
        beta[(size_t)row * 4 + lane] = sigmoidf_(acc[lane]);
        gamma[(size_t)row * 4 + lane] = sigmoidf_(acc[4 + lane]);
        xmix[(size_t)row * 4 + lane] = acc[8 + lane];
    }
}

// ---------------- K5 (fused): conv + silu(+silu) + per-head l2norm -> qn/kn bf16; v -> bf16 ----------------
// One block per (b,t) row. Thread tid handles channels c=tid*4..+3; head h=tid>>6, lane=tid&63.
__global__ __launch_bounds__(256) void k_convnorm(const unsigned short* __restrict__ xqkv,
                                                  const float* __restrict__ cq,
                                                  const float* __restrict__ ck,
                                                  const float* __restrict__ cv,
                                                  unsigned short* __restrict__ qn,
                                                  unsigned short* __restrict__ kn,
                                                  unsigned short* __restrict__ vb)
{
    int row = blockIdx.x;          // b*L + t
    int t = row & (L - 1);
    int b = row >> 11;
    int tid = threadIdx.x;
    int h = tid >> 6, lane = tid & 63;
    int c = tid * 4;
    float wq[4][4], wk[4][4], wv[4][4];
#pragma unroll
    for (int j = 0; j < 4; j++) {
        float4 a = *(const float4*)(cq + (size_t)(c + j) * 4);
        wq[j][0] = a.x; wq[j][1] = a.y; wq[j][2] = a.z; wq[j][3] = a.w;
        float4 d = *(const float4*)(ck + (size_t)(c + j) * 4);
        wk[j][0] = d.x; wk[j][1] = d.y; wk[j][2] = d.z; wk[j][3] = d.w;
        float4 e = *(const float4*)(cv + (size_t)(c + j) * 4);
        wv[j][0] = e.x; wv[j][1] = e.y; wv[j][2] = e.z; wv[j][3] = e.w;
    }
    float aq[4] = {0, 0, 0, 0}, ak[4] = {0, 0, 0, 0}, av[4] = {0, 0, 0, 0};
#pragma unroll
    for (int kk = 0; kk < 4; kk++) {
        int tt = t - 3 + kk;
        if (tt < 0) continue;
        const unsigned short* p = xqkv + (size_t)(row - 3 + kk) * (3 * D) + c;
        ushort4 xq = *(const ushort4*)(p);
        ushort4 xk = *(const ushort4*)(p + D);
        ushort4 xv = *(const ushort4*)(p + 2 * D);
        aq[0] += wq[0][kk] * bf2f(xq.x); aq[1] += wq[1][kk] * bf2f(xq.y);
        aq[2] += wq[2][kk] * bf2f(xq.z); aq[3] += wq[3][kk] * bf2f(xq.w);
        ak[0] += wk[0][kk] * bf2f(xk.x); ak[1] += wk[1][kk] * bf2f(xk.y);
        ak[2] += wk[2][kk] * bf2f(xk.z); ak[3] += wk[3][kk] * bf2f(xk.w);
        av[0] += wv[0][kk] * bf2f(xv.x); av[1] += wv[1][kk] * bf2f(xv.y);
        av[2] += wv[2][kk] * bf2f(xv.z); av[3] += wv[3][kk] * bf2f(xv.w);
    }
    float rq[4], rk[4], rv[4];
#pragma unroll
    for (int j = 0; j < 4; j++) {
        rq[j] = siluf_(siluf_(aq[j]));
        rk[j] = siluf_(siluf_(ak[j]));
        rv[j] = siluf_(av[j]);
    }
    float sq = rq[0] * rq[0] + rq[1] * rq[1] + rq[2] * rq[2] + rq[3] * rq[3];
    float sk = rk[0] * rk[0] + rk[1] * rk[1] + rk[2] * rk[2] + rk[3] * rk[3];
    for (int off = 32; off; off >>= 1) { sq += __shfl_xor(sq, off, 64); sk += __shfl_xor(sk, off, 64); }
    float qs = rsqrtf(sq + 1e-6f), ks = rsqrtf(sk + 1e-6f);
    size_t oidx = ((size_t)(b * NH + h) * L + t) * DK + lane * 4;
    ushort4 oq, ok, ov;
    oq.x = f2bf(rq[0] * qs); oq.y = f2bf(rq[1] * qs); oq.z = f2bf(rq[2] * qs); oq.w = f2bf(rq[3] * qs);
    ok.x = f2bf(rk[0] * ks); ok.y = f2bf(rk[1] * ks); ok.z = f2bf(rk[2] * ks); ok.w = f2bf(rk[3] * ks);
    ov.x = f2bf(rv[0]); ov.y = f2bf(rv[1]); ov.z = f2bf(rv[2]); ov.w = f2bf(rv[3]);
    *(ushort4*)(qn + oidx) = oq;
    *(ushort4*)(kn + oidx) = ok;
    *(ushort4*)(vb + (size_t)row * D + c) = ov;
}

// ---------------- K6: mix conv + silu ----------------
__global__ __launch_bounds__(256) void k_convmix(const float* xmix, const float* cmix, float* mixinp)
{
    int idx = blockIdx.x * 256 + threadIdx.x;   // < B*L*NH
    int h = idx & 3;
    int t = (idx >> 2) & (L - 1);
    int b = idx >> 13;
    float acc = 0.f;
#pragma unroll
    for (int kk = 0; kk < 4; kk++) {
        int tt = t - 3 + kk;
        if (tt >= 0) acc += cmix[h * 4 + kk] * xmix[((size_t)(b * L + tt) << 2) + h];
    }
    mixinp[idx] = siluf_(acc);
}

// ---------------- K7b: per-(bh,chunk) delta-rule precompute (MFMA version) ----------------
#define KTS 40   // LDS row stride in shorts: 80B (16B-aligned), dword stride 20 -> 2-way banks (free)
__global__ __launch_bounds__(256) void k_delta_pre(const unsigned short* qn, const unsigned short* kn,
                                                   const unsigned short* vb, const float* beta,
                                                   unsigned short* wneg, unsigned short* knT,
                                                   unsigned short* attnb, float* u)
{
    __shared__ __align__(16) unsigned short kTl[256 * KTS]; // k^T bf16 [dk][t]
    __shared__ __align__(16) unsigned short vTl[256 * KTS]; // v^T bf16 [dk][t]
    __shared__ __align__(16) unsigned short T2b[32 * KTS];  // T2 bf16 [t][t']
    __shared__ float Gs[32 * 33];
    int bx = blockIdx.x;
    int bh = bx >> 6, ch = bx & 63;
    int b = bh >> 2, h = bh & 3;
    int t0 = ch * 32;
    int tid = threadIdx.x;
    int w = tid >> 6, lane = tid & 63;
    int r16 = lane & 15, quad = lane >> 4;
    size_t rowbase = (size_t)(bh * L + t0);
    f32x4 z4 = {0.f, 0.f, 0.f, 0.f};

    // ---- phase A: MFMA G/QK tiles
    if (w < 3) {
        int mi = (w == 0) ? 0 : 1;
        int ni = (w == 2) ? 1 : 0;
        const unsigned short* krm = kn + (rowbase + mi * 16 + r16) * DK;
        const unsigned short* krn = kn + (rowbase + ni * 16 + r16) * DK;
        const unsigned short* qrm = qn + (rowbase + mi * 16 + r16) * DK;
        f32x4 g = z4, qk = z4;
#pragma unroll
        for (int kt = 0; kt < 8; kt++) {
            bf16x8 a  = *(const bf16x8*)(krm + kt * 32 + quad * 8);
            bf16x8 bb = *(const bf16x8*)(krn + kt * 32 + quad * 8);
            bf16x8 qa = *(const bf16x8*)(qrm + kt * 32 + quad * 8);
            g  = MFMA16(a, bb, g);
            qk = MFMA16(qa, bb, qk);
        }
#pragma unroll
        for (int r = 0; r < 4; r++) {
            int i = mi * 16 + quad * 4 + r, j = ni * 16 + r16;
            Gs[i * 33 + j] = g[r];
            attnb[(size_t)(bh * 64 + ch) * 1024 + i * 32 + j] =
                (j <= i) ? f2bf(qk[r]) : (unsigned short)0;
        }
    } else {
        // strictly-upper QK tile (0,1) is all zero
#pragma unroll
        for (int r = 0; r < 4; r++) {
            int i = quad * 4 + r, j = 16 + r16;
            attnb[(size_t)(bh * 64 + ch) * 1024 + i * 32 + j] = 0;
        }
    }
    // ---- phase A2 (all threads): transpose k, v (both bf16) into LDS
    {
        int t = tid & 31, c0 = (tid >> 5) * 32;
        const unsigned short* krow = kn + (rowbase + t) * DK + c0;
        const unsigned short* vrow = vb + ((size_t)(b * L + t0 + t)) * D + h * DK + c0;
#pragma unroll
        for (int j = 0; j < 32; j += 4) {
            ushort4 kv = *(const ushort4*)(krow + j);
            ushort4 vv = *(const ushort4*)(vrow + j);
            kTl[(c0 + j + 0) * KTS + t] = kv.x;
            kTl[(c0 + j + 1) * KTS + t] = kv.y;
            kTl[(c0 + j + 2) * KTS + t] = kv.z;
            kTl[(c0 + j + 3) * KTS + t] = kv.w;
            vTl[(c0 + j + 0) * KTS + t] = vv.x;
            vTl[(c0 + j + 1) * KTS + t] = vv.y;
            vTl[(c0 + j + 2) * KTS + t] = vv.z;
            vTl[(c0 + j + 3) * KTS + t] = vv.w;
        }
    }
    __syncthreads();

    // ---- phase B
    if (w == 0) {
        int c = lane & 31;
        float rr[32];
#pragma unroll
        for (int j = 0; j < 32; j++) rr[j] = Gs[j * 33 + c];
        // Row 0 of the strict-lower T is empty: must be zero.
        rr[0] = 0.f;
        float bc = beta[(size_t)(b * L + t0 + c) * NH + h];
#pragma unroll
        for (int i = 1; i < 32; i++) {
            float bi = __shfl(bc, i, 64);
            float s = -bi * rr[i];
#pragma unroll
            for (int j = 1; j < i; j++) {
                float aij = -bi * __shfl(rr[i], j, 64);
                s += aij * ((c < j) ? rr[j] : 0.f);
            }
            rr[i] = (c < i) ? s : 0.f;
        }
        if (lane < 32) {
#pragma unroll
            for (int i = 0; i < 32; i++) {
                float val = (rr[i] + ((i == c) ? 1.f : 0.f)) * bc;
                T2b[i * KTS + c] = f2bf(val);
            }
        }
    } else {
        int idx = tid - 64;
        for (int rowc = idx; rowc < 256; rowc += 192) {
            unsigned short* kT = knT + ((size_t)(bh * 64 + ch) * DK + rowc) * 32;
#pragma unroll
            for (int seg = 0; seg < 4; seg++) {
                uint4 d = *(const uint4*)&kTl[rowc * KTS + seg * 8];
                *(uint4*)(kT + seg * 8) = d;
            }
        }
    }
    __syncthreads();

    // ---- phase C: u = T2@v (f32 out), wneg = -(T2@k) (bf16 out)
#pragma unroll
    for (int mt = 0; mt < 2; mt++) {
        bf16x8 ta = *(const bf16x8*)&T2b[(mt * 16 + r16) * KTS + quad * 8];
#pragma unroll
        for (int nt2 = 0; nt2 < 4; nt2++) {
            int nt = w * 4 + nt2;
            bf16x8 vb2 = *(const bf16x8*)&vTl[(nt * 16 + r16) * KTS + quad * 8];
            bf16x8 kb = *(const bf16x8*)&kTl[(nt * 16 + r16) * KTS + quad * 8];
            f32x4 uu = MFMA16(ta, vb2, z4);
            f32x4 ww = MFMA16(ta, kb, z4);
            float* ug = u + (rowbase + mt * 16 + quad * 4) * DK + nt * 16 + r16;
            unsigned short* wg = wneg + (rowbase + mt * 16 + quad * 4) * DK + nt * 16 + r16;
#pragma unroll
            for (int r = 0; r < 4; r++) {
                ug[(size_t)r * DK] = uu[r];
                wg[(size_t)r * DK] = f2bf(-ww[r]);
            }
        }
    }
}

// ---------------- K8a: EMA local scan (bf16 v input) ----------------
__global__ __launch_bounds__(256) void k_ema_local(const unsigned short* v, const float* gamma,
                                                   float* ema_local, float* Acum,
                                                   float* s_end, float* Pchunk)
{
    __shared__ float gsh[ET];
    int blk = blockIdx.x;
    int bh = blk >> 5;
    int ch = blk & (ENCH - 1);
    int b = bh >> 2, h = bh & 3;
    int c = threadIdx.x;
    int t0 = ch * ET;
    if (c < ET) gsh[c] = gamma[(size_t)(b * L + t0 + c) * NH + h];
    __syncthreads();
    const unsigned short* vg = v + (size_t)(b * L + t0) * D + h * DK + c;
    float* eg = ema_local + (size_t)(b * L + t0) * D + h * DK + c;
    float* Ag = Acum + (size_t)bh * L + t0;
    float s = 0.f;
    float A = 1.f;
#pragma unroll 8
    for (int i = 0; i < ET; i++) {
        float g = gsh[i];
        s = g * s + (1.f - g) * bf2f(vg[(size_t)i * D]);
        A *= g;
        eg[(size_t)i * D] = s;
        if (c == 0) Ag[i] = A;
    }
    s_end[((size_t)bh * ENCH + ch) * DK + c] = s;
    if (c == 0) Pchunk[(size_t)bh * ENCH + ch] = A;
}

// ---------------- K8b: EMA carry scan ----------------
__global__ __launch_bounds__(256) void k_ema_carry(const float* s_end, const float* Pchunk, float* S_in)
{
    int bh = blockIdx.x;
    int c = threadIdx.x;
    float S = 0.f;
    for (int ch = 0; ch < ENCH; ch++) {
        S_in[((size_t)bh * ENCH + ch) * DK + c] = S;
        float P = Pchunk[(size_t)bh * ENCH + ch];
        S = P * S + s_end[((size_t)bh * ENCH + ch) * DK + c];
    }
}

// ---------------- K9: sequential inter-chunk scan ----------------
#define STS 280   // st row stride in shorts (dword stride 140 = 12 mod 32 -> 2-way)
#define USTR 40   // uat row stride in shorts (2-way only)
__global__ __launch_bounds__(128, 1) void k_scan(const unsigned short* qn, const unsigned short* wneg,
                                                 const unsigned short* knT, const unsigned short* attnb,
                                                 const float* u, float* od)
{
    __shared__ __align__(16) unsigned short st[16 * STS];   // S^T bf16: [c][dk]
    __shared__ __align__(16) unsigned short uat[16 * USTR]; // u_adj^T bf16: [c][t]
    int bh = blockIdx.x;
    int tile = blockIdx.y;      // 0..15, 16 cols each
    int b = bh >> 2, h = bh & 3;
    int mo = threadIdx.x >> 6, lane = threadIdx.x & 63;
    int r16 = lane & 15, quad = lane >> 4;
    int cbase = tile * 16;
    f32x4 z4 = {0.f, 0.f, 0.f, 0.f};
    f32x4 sacc[8];
#pragma unroll
    for (int a = 0; a < 8; a++) sacc[a] = z4;
    const unsigned short* qb = qn + (size_t)bh * L * DK;
    const unsigned short* wb = wneg + (size_t)bh * L * DK;
    const float* ub = u + (size_t)bh * L * DK;
    const unsigned short* kTbase = knT + (size_t)bh * 64 * DK * 32;
    const unsigned short* atbase = attnb + (size_t)bh * 64 * 1024;
    int dkb = mo * 128;   // this wave's S^T row base

    bf16x8 qf[2][8], wf[2][8];
    f32x4 au0[2];

    auto issue = [&](int ch, int par) {
        int t0 = ch * 32;
        const unsigned short* wrow = wb + (size_t)(t0 + 16 * mo + r16) * DK;
        const unsigned short* qrow = qb + (size_t)(t0 + 16 * mo + r16) * DK;
#pragma unroll
        for (int kt = 0; kt < 8; kt++) {
            qf[par][kt] = *(const bf16x8*)(qrow + kt * 32 + quad * 8);
            wf[par][kt] = *(const bf16x8*)(wrow + kt * 32 + quad * 8);
        }
        const float* up = ub + (size_t)(t0 + 16 * mo + quad * 4) * DK + cbase + r16;
        f32x4 a; a[0] = up[0]; a[1] = up[DK]; a[2] = up[2 * DK]; a[3] = up[3 * DK];
        au0[par] = a;
    };

    issue(0, 0);

    auto body = [&](int ch, int par) {
        int t0 = ch * 32;
        // (0) issue current-chunk kf/af early — consumed only at (F)
        bf16x8 af = *(const bf16x8*)(atbase + (size_t)ch * 1024 + (16 * mo + r16) * 32 + quad * 8);
        const unsigned short* kTb = kTbase + (size_t)ch * DK * 32;
        bf16x8 kf[8];
#pragma unroll
        for (int a = 0; a < 8; a++)
            kf[a] = *(const bf16x8*)(kTb + (size_t)(dkb + a * 16 + r16) * 32 + quad * 8);

        // (A) write this wave's S^T slab to LDS
#pragma unroll
        for (int a = 0; a < 8; a++) {
            uint2 p;
            p.x = f2bf(sacc[a][0]) | ((unsigned)f2bf(sacc[a][1]) << 16);
            p.y = f2bf(sacc[a][2]) | ((unsigned)f2bf(sacc[a][3]) << 16);
            *(uint2*)&st[r16 * STS + dkb + a * 16 + quad * 4] = p;
        }
        // (B) prefetch next chunk's qf/wf/au0
        if (ch + 1 < NCH) issue(ch + 1, par ^ 1);
        bar_lds();

        // (C) u_adj = u - w@S ; o_partial = q@S
        f32x4 au = au0[par], ao = z4;
#pragma unroll
        for (int kt = 0; kt < 8; kt++) {
            bf16x8 sfr = *(const bf16x8*)&st[r16 * STS + kt * 32 + quad * 8];
            au = MFMA16(wf[par][kt], sfr, au);
            ao = MFMA16(qf[par][kt], sfr, ao);
        }
        // (D) write u_adj^T
        {
            uint2 p;
            p.x = f2bf(au[0]) | ((unsigned)f2bf(au[1]) << 16);
            p.y = f2bf(au[2]) | ((unsigned)f2bf(au[3]) << 16);
            *(uint2*)&uat[r16 * USTR + 16 * mo + quad * 4] = p;
        }
        bar_lds();

        // (F) o = q@S + attn@u_adj ; store ; S^T += kT @ u_adj
        {
            bf16x8 uf = *(const bf16x8*)&uat[r16 * USTR + quad * 8];
            ao = MFMA16(af, uf, ao);
            float* op = od + (size_t)(b * L + t0 + 16 * mo + quad * 4) * D + h * DK + cbase + r16;
            op[0] = ao[0]; op[D] = ao[1]; op[2 * D] = ao[2]; op[3 * D] = ao[3];
#pragma unroll
            for (int a = 0; a < 8; a++)
                sacc[a] = MFMA16(kf[a], uf, sacc[a]);
        }
    };

    for (int ch2 = 0; ch2 < NCH; ch2 += 2) {
        body(ch2, 0);
        body(ch2 + 1, 1);
    }
}

// ---------------- K10: mix + EMA fix-up + per-head RMS norm -> bf16 ----------------
__global__ __launch_bounds__(256) void k_mixrms(const float* od, const float* ema_local,
                                                const float* Acum, const float* S_in,
                                                const float* mixinp,
                                                const float* mix_bias, const float* rms_w,
                                                unsigned short* onorm)
{
    int row = blockIdx.x;       // b*L + t
    int tid = threadIdx.x;
    int h = tid >> 6, lane = tid & 63;
    int b = row >> 11, t = row & (L - 1);
    int bh = b * NH + h;
    int ch = t >> 6;            // ET = 64
    float m = sigmoidf_(mixinp[(size_t)row * NH + h] + mix_bias[h]);
    int c = tid * 4;
    float A = Acum[(size_t)bh * L + t];
    float4 sin4 = *(const float4*)(S_in + ((size_t)bh * ENCH + ch) * DK + (c & (DK - 1)));
    float4 o = *(const float4*)(od + (size_t)row * D + c);
    float4 e = *(const float4*)(ema_local + (size_t)row * D + c);
    e.x += A * sin4.x; e.y += A * sin4.y; e.z += A * sin4.z; e.w += A * sin4.w;
    float x0 = o.x + m * (e.x - o.x);
    float x1 = o.y + m * (e.y - o.y);
    float x2 = o.z + m * (e.z - o.z);
    float x3 = o.w + m * (e.w - o.w);
    float ss = x0 * x0 + x1 * x1 + x2 * x2 + x3 * x3;
    for (int off = 32; off; off >>= 1) ss += __shfl_xor(ss, off, 64);
    float scale = rsqrtf(ss * (1.0f / 256.0f) + 1e-5f);
    float4 w = *(const float4*)(rms_w + lane * 4);
    uint2 p;
    p.x = f2bf(x0 * scale * w.x) | ((unsigned)f2bf(x1 * scale * w.y) << 16);
    p.y = f2bf(x2 * scale * w.z) | ((unsigned)f2bf(x3 * scale * w.w) << 16);
    *(uint2*)(onorm + (size_t)row * D + c) = p;
}

extern "C" void kernel_launch(void* const* d_in, const int* in_sizes, int n_in,
                              void* d_out, int out_size, void* d_ws, size_t ws_size,
                              hipStream_t stream)
{
    (void)in_sizes; (void)n_in; (void)out_size; (void)ws_size;
    const float* hidden   = (const float*)d_in[0];
    const float* Wq       = (const float*)d_in[1];
    const float* Wk       = (const float*)d_in[2];
    const float* Wv       = (const float*)d_in[3];
    const float* conv_q   = (const float*)d_in[4];
    const float* conv_k   = (const float*)d_in[5];
    const float* conv_v   = (const float*)d_in[6];
    const float* Wb       = (const float*)d_in[7];
    const float* Wdec     = (const float*)d_in[8];
    const float* Wmix     = (const float*)d_in[9];
    const float* conv_mix = (const float*)d_in[10];
    const float* mix_bias = (const float*)d_in[11];
    const float* rms_w    = (const float*)d_in[12];
    const float* Wo       = (const float*)d_in[13];
    float* out = (float*)d_out;

    char* ws = (char*)d_ws;
    size_t off = 0;
    auto alloc = [&](size_t bytes) -> char* {
        char* p = ws + off;
        off += (bytes + 255) & ~(size_t)255;
        return p;
    };
    unsigned short* wT    = (unsigned short*)alloc((size_t)4 * D * D * 2);
    unsigned short* hidB  = (unsigned short*)alloc((size_t)B * L * D * 2);
    unsigned short* xqkv  = (unsigned short*)alloc((size_t)B * L * 3 * D * 2); // slices 1,2 reused as wneg/knT
    float* beta   = (float*)alloc((size_t)B * L * NH * 4);
    float* gamma  = (float*)alloc((size_t)B * L * NH * 4);
    float* xmix   = (float*)alloc((size_t)B * L * NH * 4);
    float* mixinp = (float*)alloc((size_t)B * L * NH * 4);
    float* qbuf   = (float*)alloc((size_t)B * L * D * 4);   // ema_local
    float* kbuf   = (float*)alloc((size_t)B * L * D * 4);   // od
    unsigned short* vb = (unsigned short*)alloc((size_t)B * L * D * 2);  // v bf16
    float* u      = (float*)alloc((size_t)B * L * D * 4);
    unsigned short* attnb = (unsigned short*)alloc((size_t)BH * NCH * CHUNK * CHUNK * 2);
    unsigned short* onorm = (unsigned short*)alloc((size_t)B * L * D * 2);
    unsigned short* kn    = (unsigned short*)alloc((size_t)B * L * D * 2);
    unsigned short* qn    = (unsigned short*)alloc((size_t)B * L * D * 2);
    float* Acum   = (float*)alloc((size_t)BH * L * 4);
    float* s_end  = (float*)alloc((size_t)BH * ENCH * DK * 4);
    float* Pchunk = (float*)alloc((size_t)BH * ENCH * 4);
    float* S_in   = (float*)alloc((size_t)BH * ENCH * DK * 4);

    unsigned short* wneg = xqkv + (size_t)B * L * D;       // xqkv dead after k_convnorm
    unsigned short* knT  = xqkv + (size_t)2 * B * L * D;
    float* ema_local = qbuf;
    float* od  = kbuf;

    k_wT<<<dim3(32, 32, 4), 256, 0, stream>>>(Wq, Wk, Wv, Wo, wT);
    k_cvt<<<dim3(2048), 256, 0, stream>>>(hidden, hidB, B * L * D / 4);
    k_gemm_lds<3 * D, false><<<dim3(64, 24), 256, 0, stream>>>(hidB, wT, xqkv);
    k_smallproj<<<dim3(B * L / 4), 256, 0, stream>>>(hidden, Wb, Wdec, Wmix, beta, gamma, xmix);
    k_convnorm<<<dim3(B * L), 256, 0, stream>>>(xqkv, conv_q, conv_k, conv_v, qn, kn, vb);
    k_convmix<<<dim3(B * L * NH / 256), 256, 0, stream>>>(xmix, conv_mix, mixinp);
    k_delta_pre<<<dim3(BH * NCH), 256, 0, stream>>>(qn, kn, vb, beta, wneg, knT, attnb, u);
    k_ema_local<<<dim3(BH * ENCH), 256, 0, stream>>>(vb, gamma, ema_local, Acum, s_end, Pchunk);
    k_ema_carry<<<dim3(BH), 256, 0, stream>>>(s_end, Pchunk, S_in);
    k_scan<<<dim3(16, 16), 128, 0, stream>>>(qn, wneg, knT, attnb, u, od);
    k_mixrms<<<dim3(B * L), 256, 0, stream>>>(od, ema_local, Acum, S_in, mixinp, mix_bias, rms_w, onorm);
    k_gemm_lds<D, true><<<dim3(64, 8), 256, 0, stream>>>(onorm, wT + (size_t)3 * D * D, out);
}